// Round 1
// baseline (2667.376 us; speedup 1.0000x reference)
//
#include <hip/hip_runtime.h>
#include <math.h>

#define BB 512
#define NT 128
#define NREL 201
#define NNODE (BB*NT)
#define NEDGE (NNODE*16)

// ---------------------------------------------------------------- k_rel
// r1,r2,r3 = rel_emb @ Wrel chain; WoT = transpose(Wo_W)
__global__ void k_rel(const float* __restrict__ rel_emb, const float* __restrict__ W_rel,
                      const float* __restrict__ Wo_W, float* __restrict__ r123,
                      float* __restrict__ WoT) {
  __shared__ float rcur[NREL*32];
  __shared__ float rnext[NREL*32];
  int tid = threadIdx.x;
  for (int i = tid; i < NREL*32; i += 256) rcur[i] = rel_emb[i];
  __syncthreads();
  for (int l = 0; l < 3; ++l) {
    const float* w = W_rel + l*32*32;
    for (int i = tid; i < NREL*32; i += 256) {
      int row = i >> 5, col = i & 31;
      float s = 0.f;
      #pragma unroll
      for (int d = 0; d < 32; ++d) s += rcur[row*32 + d] * w[d*32 + col];
      rnext[i] = s;
    }
    __syncthreads();
    for (int i = tid; i < NREL*32; i += 256) {
      float v = rnext[i];
      rcur[i] = v;
      r123[l*NREL*32 + i] = v;
    }
    __syncthreads();
  }
  for (int i = tid; i < 96*192; i += 256) {
    int jj = i / 192, dd = i - jj*192;
    WoT[i] = Wo_W[dd*96 + jj];
  }
}

// ---------------------------------------------------------------- k_deg
__global__ void k_deg(const int* __restrict__ dst, int* __restrict__ deg) {
  int e = blockIdx.x*256 + threadIdx.x;
  if (e < NEDGE) atomicAdd(&deg[dst[e]], 1);
}

// ---------------------------------------------------------------- k_sem
__device__ __forceinline__ void sem_att(const float* __restrict__ rel_emb,
                                        const int rels[8], const float tgt[32],
                                        float out[32]) {
  float dots[8]; float mx = -1e30f;
  #pragma unroll
  for (int k = 0; k < 8; ++k) {
    const float4* er = (const float4*)(rel_emb + rels[k]*32);
    float s = 0.f;
    #pragma unroll
    for (int q = 0; q < 8; ++q) {
      float4 v = er[q];
      s += v.x*tgt[4*q+0] + v.y*tgt[4*q+1] + v.z*tgt[4*q+2] + v.w*tgt[4*q+3];
    }
    dots[k] = s; mx = fmaxf(mx, s);
  }
  float den = 0.f;
  #pragma unroll
  for (int k = 0; k < 8; ++k) { float e = __expf(dots[k]-mx); dots[k] = e; den += e; }
  float inv = 1.f/den;
  #pragma unroll
  for (int d = 0; d < 32; ++d) out[d] = 0.f;
  #pragma unroll
  for (int k = 0; k < 8; ++k) {
    const float4* er = (const float4*)(rel_emb + rels[k]*32);
    float a = dots[k]*inv;
    #pragma unroll
    for (int q = 0; q < 8; ++q) {
      float4 v = er[q];
      out[4*q+0] += a*v.x; out[4*q+1] += a*v.y; out[4*q+2] += a*v.z; out[4*q+3] += a*v.w;
    }
  }
}

__global__ __launch_bounds__(256) void k_sem(
    const float* __restrict__ feat, const int* __restrict__ out_rels,
    const int* __restrict__ in_rels, const int* __restrict__ r_label_node,
    const float* __restrict__ rel_emb, const float* __restrict__ W,
    const float* __restrict__ bias, float* __restrict__ hin) {
  int n = blockIdx.x*256 + threadIdx.x;
  float tgt[32];
  {
    const float4* tr = (const float4*)(rel_emb + r_label_node[n]*32);
    #pragma unroll
    for (int q = 0; q < 8; ++q) {
      float4 v = tr[q];
      tgt[4*q+0]=v.x; tgt[4*q+1]=v.y; tgt[4*q+2]=v.z; tgt[4*q+3]=v.w;
    }
  }
  int ro[8], ri[8];
  #pragma unroll
  for (int k = 0; k < 8; ++k) { ro[k] = out_rels[n*8+k]; ri[k] = in_rels[n*8+k]; }
  float osem[32], isem[32];
  sem_att(rel_emb, ro, tgt, osem);
  sem_att(rel_emb, ri, tgt, isem);
  const float4* fr = (const float4*)(feat + (size_t)n*16);
  float4* ho = (float4*)(hin + (size_t)n*32);
  #pragma unroll
  for (int q = 0; q < 4; ++q) ho[q] = fr[q];
  #pragma unroll
  for (int j = 0; j < 16; ++j) {
    float s = bias[j];
    #pragma unroll
    for (int d = 0; d < 32; ++d) s += osem[d]*W[d*16+j] + isem[d]*W[(32+d)*16+j];
    hin[(size_t)n*32 + 16 + j] = 1.f/(1.f + __expf(-s));
  }
}

// ---------------------------------------------------------------- k_gnn (one block per graph)
__global__ __launch_bounds__(256) void k_gnn(
    const float* __restrict__ hsrc, int hstride, const float* __restrict__ r_l,
    const int* __restrict__ src, const int* __restrict__ dst, const int* __restrict__ etype,
    const int* __restrict__ deg, const float* __restrict__ Wm, const float* __restrict__ Ws,
    const float* __restrict__ bl, float* __restrict__ repr_out, int ofs) {
  __shared__ __align__(16) float hl[NT*32];
  __shared__ __align__(16) float agg[NT*32];
  __shared__ float WmT[32*33];
  __shared__ float WsT[32*33];
  int g = blockIdx.x;
  int tid = threadIdx.x;
  for (int i = tid; i < NT*32; i += 256) {
    int row = i >> 5, col = i & 31;
    hl[i] = hsrc[(size_t)(g*NT + row)*hstride + col];
    agg[i] = 0.f;
  }
  for (int i = tid; i < 1024; i += 256) {
    int d = i >> 5, j = i & 31;
    WmT[j*33 + d] = Wm[i];
    WsT[j*33 + d] = Ws[i];
  }
  __syncthreads();
  {
    int d = tid & 31, grp = tid >> 5;
    int ebase = g*2048;
    for (int i = grp; i < 2048; i += 8) {
      int e = ebase + i;
      int sl = src[e] - g*NT;
      int dl = dst[e] - g*NT;
      float m = hl[sl*32 + d] * r_l[etype[e]*32 + d];
      atomicAdd(&agg[dl*32 + d], m);
    }
  }
  __syncthreads();
  int j = tid & 31;
  float wm[32], ws[32];
  #pragma unroll
  for (int dd = 0; dd < 32; ++dd) { wm[dd] = WmT[j*33+dd]; ws[dd] = WsT[j*33+dd]; }
  float bj = bl[j];
  int nbase = tid >> 5;
  for (int k2 = 0; k2 < 16; ++k2) {
    int n = nbase + k2*8;
    int dv = deg[g*NT + n];
    float invd = 1.f / (float)(dv > 0 ? dv : 1);
    const float4* a4 = (const float4*)&agg[n*32];
    const float4* h4 = (const float4*)&hl[n*32];
    float sa = 0.f, sh = 0.f;
    #pragma unroll
    for (int q = 0; q < 8; ++q) {
      float4 av = a4[q], hv = h4[q];
      sa += av.x*wm[4*q+0] + av.y*wm[4*q+1] + av.z*wm[4*q+2] + av.w*wm[4*q+3];
      sh += hv.x*ws[4*q+0] + hv.y*ws[4*q+1] + hv.z*ws[4*q+2] + hv.w*ws[4*q+3];
    }
    float res = bj + invd*sa + sh;
    repr_out[(size_t)(g*NT + n)*96 + ofs + j] = fmaxf(res, 0.f);
  }
}

// ---------------------------------------------------------------- k_h0max
__global__ __launch_bounds__(128) void k_h0max(const float* __restrict__ repr,
                                               float* __restrict__ ghid0) {
  int b = blockIdx.x, j = threadIdx.x;
  if (j >= 96) return;
  float m = -1e30f;
  for (int n2 = 0; n2 < NT; ++n2) m = fmaxf(m, repr[(size_t)(b*NT + n2)*96 + j]);
  ghid0[b*96 + j] = m;
}

// ---------------------------------------------------------------- k_gi : GI = relu(repr+bias) @ Wih^T + bih
__global__ __launch_bounds__(128) void k_gi(
    const float* __restrict__ repr, const float* __restrict__ gbias,
    const float* __restrict__ Wih_f, const float* __restrict__ bih_f,
    const float* __restrict__ Wih_b, const float* __restrict__ bih_b,
    float* __restrict__ GIF, float* __restrict__ GIB) {
  __shared__ float a[NT*97];
  int g = blockIdx.x, c = blockIdx.y;
  int dir = c / 3, cc = c - dir*3;
  const float* W = dir ? Wih_b : Wih_f;
  const float* bi = dir ? bih_b : bih_f;
  float* GO = dir ? GIB : GIF;
  int tid = threadIdx.x;
  const float* rbase = repr + (size_t)g*NT*96;
  for (int i = tid; i < NT*96; i += 128) {
    int row = i / 96, col = i - row*96;
    a[row*97 + col] = fmaxf(rbase[i] + gbias[col], 0.f);
  }
  __syncthreads();
  int n = tid;
  const float* arow = &a[n*97];
  size_t nodeoff = (size_t)(g*NT + n)*288;
  for (int pp = 0; pp < 4; ++pp) {
    int jbase = cc*96 + pp*24;
    float acc[24];
    #pragma unroll
    for (int jj = 0; jj < 24; ++jj) acc[jj] = bi[jbase+jj];
    for (int blk = 0; blk < 6; ++blk) {
      float a16[16];
      #pragma unroll
      for (int dd = 0; dd < 16; ++dd) a16[dd] = arow[blk*16 + dd];
      #pragma unroll
      for (int jj = 0; jj < 24; ++jj) {
        const float4* w4 = (const float4*)(W + (size_t)(jbase+jj)*96 + blk*16);
        float4 w0 = w4[0], w1 = w4[1], w2 = w4[2], w3 = w4[3];
        acc[jj] += a16[0]*w0.x + a16[1]*w0.y + a16[2]*w0.z + a16[3]*w0.w
                 + a16[4]*w1.x + a16[5]*w1.y + a16[6]*w1.z + a16[7]*w1.w
                 + a16[8]*w2.x + a16[9]*w2.y + a16[10]*w2.z + a16[11]*w2.w
                 + a16[12]*w3.x + a16[13]*w3.y + a16[14]*w3.z + a16[15]*w3.w;
      }
    }
    float* go = GO + nodeoff + jbase;
    #pragma unroll
    for (int q = 0; q < 6; ++q)
      ((float4*)go)[q] = make_float4(acc[4*q], acc[4*q+1], acc[4*q+2], acc[4*q+3]);
  }
}

// ---------------------------------------------------------------- k_gru : sequential 128 steps, 1 block per (dir, graph)
__global__ __launch_bounds__(288) void k_gru(
    const float* __restrict__ Whh_f, const float* __restrict__ bhh_f,
    const float* __restrict__ Whh_b, const float* __restrict__ bhh_b,
    const float* __restrict__ GIF, const float* __restrict__ GIB,
    const float* __restrict__ ghid0, float* __restrict__ gruout) {
  __shared__ __align__(16) float h_lds[96];
  __shared__ float gh_lds[288];
  int bx = blockIdx.x;
  int dir = bx >> 9;
  int b = bx & 511;
  int j = threadIdx.x;
  const float* Whh = dir ? Whh_b : Whh_f;
  const float* bhh = dir ? bhh_b : bhh_f;
  const float* GI = dir ? GIB : GIF;
  float4 w4[24];
  const float4* wr = (const float4*)(Whh + (size_t)j*96);
  #pragma unroll
  for (int q = 0; q < 24; ++q) w4[q] = wr[q];
  float bj = bhh[j];
  if (j < 96) h_lds[j] = ghid0[b*96 + j];
  __syncthreads();
  for (int t = 0; t < 128; ++t) {
    int pos = dir ? (127 - t) : t;
    size_t node = (size_t)b*128 + pos;
    float gir = 0.f, giz = 0.f, gin = 0.f;
    if (j < 96) {
      const float* gp = GI + node*288;
      gir = gp[j]; giz = gp[96+j]; gin = gp[192+j];
    }
    float acc = bj;
    #pragma unroll
    for (int q = 0; q < 24; ++q) {
      float4 h4 = *(const float4*)&h_lds[4*q];
      acc += w4[q].x*h4.x + w4[q].y*h4.y + w4[q].z*h4.z + w4[q].w*h4.w;
    }
    gh_lds[j] = acc;
    __syncthreads();
    if (j < 96) {
      float r = 1.f/(1.f + __expf(-(gir + gh_lds[j])));
      float z = 1.f/(1.f + __expf(-(giz + gh_lds[96+j])));
      float nn2 = tanhf(gin + r*gh_lds[192+j]);
      float hn = (1.f - z)*nn2 + z*h_lds[j];
      h_lds[j] = hn;
      gruout[node*192 + (size_t)dir*96 + j] = hn;
    }
    __syncthreads();
  }
}

// ---------------------------------------------------------------- k_pool : relu(gruout) @ Wo + b, fused mean/head/tail
__global__ __launch_bounds__(128) void k_pool(
    const float* __restrict__ gruout, const float* __restrict__ WoT,
    const float* __restrict__ Wo_b, float* __restrict__ goutb,
    float* __restrict__ headb, float* __restrict__ tailb) {
  __shared__ float a[NT*193];
  __shared__ float nh[NT*25];
  int g = blockIdx.x, tid = threadIdx.x;
  const float* rb = gruout + (size_t)g*NT*192;
  for (int i = tid; i < NT*192; i += 128) {
    int row = i / 192, col = i - row*192;
    a[row*193 + col] = fmaxf(rb[i], 0.f);
  }
  __syncthreads();
  int n = tid;
  const float* arow = &a[n*193];
  for (int pp = 0; pp < 4; ++pp) {
    int jbase = pp*24;
    float acc[24];
    #pragma unroll
    for (int jj = 0; jj < 24; ++jj) acc[jj] = Wo_b[jbase+jj];
    for (int blk = 0; blk < 12; ++blk) {
      float a16[16];
      #pragma unroll
      for (int dd = 0; dd < 16; ++dd) a16[dd] = arow[blk*16 + dd];
      #pragma unroll
      for (int jj = 0; jj < 24; ++jj) {
        const float4* w4 = (const float4*)(WoT + (size_t)(jbase+jj)*192 + blk*16);
        float4 w0 = w4[0], w1 = w4[1], w2 = w4[2], w3 = w4[3];
        acc[jj] += a16[0]*w0.x + a16[1]*w0.y + a16[2]*w0.z + a16[3]*w0.w
                 + a16[4]*w1.x + a16[5]*w1.y + a16[6]*w1.z + a16[7]*w1.w
                 + a16[8]*w2.x + a16[9]*w2.y + a16[10]*w2.z + a16[11]*w2.w
                 + a16[12]*w3.x + a16[13]*w3.y + a16[14]*w3.z + a16[15]*w3.w;
      }
    }
    #pragma unroll
    for (int jj = 0; jj < 24; ++jj) nh[n*25 + jj] = fmaxf(acc[jj], 0.f);
    __syncthreads();
    if (tid < 24) {
      float s = 0.f;
      for (int n2 = 0; n2 < NT; ++n2) s += nh[n2*25 + tid];
      int jg = jbase + tid;
      goutb[g*96 + jg] = s * (1.f/128.f);
      headb[g*96 + jg] = nh[0*25 + tid];
      tailb[g*96 + jg] = nh[1*25 + tid];
    }
    __syncthreads();
  }
}

// ---------------------------------------------------------------- k_path : 3-step GRU per path, 1 thread per path
__global__ __launch_bounds__(64) void k_path(
    const float* __restrict__ r3, const int* __restrict__ in_rels,
    const int* __restrict__ labels, const float* __restrict__ pWih,
    const float* __restrict__ pWhh, const float* __restrict__ pbih,
    const float* __restrict__ pbhh, float* __restrict__ last) {
  __shared__ float hbuf[64*33];
  int tid = threadIdx.x;
  int p = blockIdx.x*64 + tid;
  int b = p >> 6, pp = p & 63;
  int rids[3];
  rids[0] = in_rels[b*1024 + (pp >> 3)];
  rids[1] = labels[b];
  rids[2] = in_rels[b*1024 + 8 + (pp & 7)];
  float* hs = &hbuf[tid*33];
  float4 h4[8];
  #pragma unroll
  for (int q = 0; q < 8; ++q) h4[q] = make_float4(0.f,0.f,0.f,0.f);
  #pragma unroll
  for (int d = 0; d < 32; ++d) hs[d] = 0.f;
  for (int s = 0; s < 3; ++s) {
    float4 x4[8];
    const float4* xr = (const float4*)(r3 + rids[s]*32);
    #pragma unroll
    for (int q = 0; q < 8; ++q) x4[q] = xr[q];
    for (int gg = 0; gg < 32; ++gg) {
      float air = pbih[gg],    ahr = pbhh[gg];
      float aiz = pbih[32+gg], ahz = pbhh[32+gg];
      float ain = pbih[64+gg], ahn = pbhh[64+gg];
      const float4* wir = (const float4*)(pWih + gg*32);
      const float4* whr = (const float4*)(pWhh + gg*32);
      const float4* wiz = (const float4*)(pWih + (32+gg)*32);
      const float4* whz = (const float4*)(pWhh + (32+gg)*32);
      const float4* win = (const float4*)(pWih + (64+gg)*32);
      const float4* whn = (const float4*)(pWhh + (64+gg)*32);
      #pragma unroll
      for (int q = 0; q < 8; ++q) {
        float4 xv = x4[q], hv = h4[q]; float4 w;
        w = wir[q]; air += xv.x*w.x + xv.y*w.y + xv.z*w.z + xv.w*w.w;
        w = whr[q]; ahr += hv.x*w.x + hv.y*w.y + hv.z*w.z + hv.w*w.w;
        w = wiz[q]; aiz += xv.x*w.x + xv.y*w.y + xv.z*w.z + xv.w*w.w;
        w = whz[q]; ahz += hv.x*w.x + hv.y*w.y + hv.z*w.z + hv.w*w.w;
        w = win[q]; ain += xv.x*w.x + xv.y*w.y + xv.z*w.z + xv.w*w.w;
        w = whn[q]; ahn += hv.x*w.x + hv.y*w.y + hv.z*w.z + hv.w*w.w;
      }
      float r = 1.f/(1.f + __expf(-(air + ahr)));
      float z = 1.f/(1.f + __expf(-(aiz + ahz)));
      float nn2 = tanhf(ain + r*ahn);
      float hold = hs[gg];
      hs[gg] = (1.f - z)*nn2 + z*hold;
    }
    #pragma unroll
    for (int q = 0; q < 8; ++q)
      h4[q] = make_float4(hs[4*q], hs[4*q+1], hs[4*q+2], hs[4*q+3]);
  }
  float* lp = last + (size_t)p*32;
  #pragma unroll
  for (int d = 0; d < 32; ++d) lp[d] = hs[d];
}

// ---------------------------------------------------------------- k_final : path attention + concat + fc
__global__ __launch_bounds__(64) void k_final(
    const float* __restrict__ last, const float* __restrict__ r3,
    const int* __restrict__ labels, const float* __restrict__ goutb,
    const float* __restrict__ headb, const float* __restrict__ tailb,
    const float* __restrict__ fcW, const float* __restrict__ fcb,
    float* __restrict__ out) {
  __shared__ float red[64*33];
  __shared__ float gpl[32];
  int b = blockIdx.x, lane = threadIdx.x;
  const float* rl = r3 + labels[b]*32;
  float l32[32];
  {
    const float4* lr = (const float4*)(last + (size_t)(b*64 + lane)*32);
    #pragma unroll
    for (int q = 0; q < 8; ++q) {
      float4 v = lr[q];
      l32[4*q+0]=v.x; l32[4*q+1]=v.y; l32[4*q+2]=v.z; l32[4*q+3]=v.w;
    }
  }
  float s = 0.f;
  #pragma unroll
  for (int d = 0; d < 32; ++d) s += l32[d]*rl[d];
  float mx = s;
  #pragma unroll
  for (int off = 32; off > 0; off >>= 1) mx = fmaxf(mx, __shfl_xor(mx, off));
  float e = __expf(s - mx);
  float den = e;
  #pragma unroll
  for (int off = 32; off > 0; off >>= 1) den += __shfl_xor(den, off);
  float att = e / den;
  #pragma unroll
  for (int d = 0; d < 32; ++d) red[lane*33 + d] = att*l32[d];
  __syncthreads();
  if (lane < 32) {
    float gp = 0.f;
    for (int p2 = 0; p2 < 64; ++p2) gp += red[p2*33 + lane];
    gpl[lane] = gp;
  }
  __syncthreads();
  float acc = 0.f;
  for (int i = lane; i < 352; i += 64) {
    float v;
    if (i < 96)      v = goutb[b*96 + i];
    else if (i < 192) v = headb[b*96 + (i-96)];
    else if (i < 288) v = tailb[b*96 + (i-192)];
    else if (i < 320) v = rl[i-288];
    else              v = gpl[i-320];
    acc += v*fcW[i];
  }
  #pragma unroll
  for (int off = 32; off > 0; off >>= 1) acc += __shfl_xor(acc, off);
  if (lane == 0) out[b] = acc + fcb[0];
}

// ---------------------------------------------------------------- launch
extern "C" void kernel_launch(void* const* d_in, const int* in_sizes, int n_in,
                              void* d_out, int out_size, void* d_ws, size_t ws_size,
                              hipStream_t stream) {
  const float* feat       = (const float*)d_in[0];
  const int*   out_rels   = (const int*)d_in[1];
  const int*   in_rels    = (const int*)d_in[2];
  const int*   r_label_nd = (const int*)d_in[3];
  const int*   src        = (const int*)d_in[4];
  const int*   dst        = (const int*)d_in[5];
  const int*   etype      = (const int*)d_in[6];
  const int*   rel_labels = (const int*)d_in[7];
  const float* rel_emb    = (const float*)d_in[8];
  const float* w2e_W      = (const float*)d_in[9];
  const float* w2e_b      = (const float*)d_in[10];
  const float* W_msg      = (const float*)d_in[11];
  const float* W_self     = (const float*)d_in[12];
  const float* b_gnn      = (const float*)d_in[13];
  const float* W_rel      = (const float*)d_in[14];
  const float* gru_bias   = (const float*)d_in[15];
  const float* Wih_f      = (const float*)d_in[16];
  const float* Whh_f      = (const float*)d_in[17];
  const float* bih_f      = (const float*)d_in[18];
  const float* bhh_f      = (const float*)d_in[19];
  const float* Wih_b      = (const float*)d_in[20];
  const float* Whh_b      = (const float*)d_in[21];
  const float* bih_b      = (const float*)d_in[22];
  const float* bhh_b      = (const float*)d_in[23];
  const float* Wo_W       = (const float*)d_in[24];
  const float* Wo_b       = (const float*)d_in[25];
  const float* pWih       = (const float*)d_in[26];
  const float* pWhh       = (const float*)d_in[27];
  const float* pbih       = (const float*)d_in[28];
  const float* pbhh       = (const float*)d_in[29];
  const float* fcW        = (const float*)d_in[30];
  const float* fcb        = (const float*)d_in[31];
  float* out = (float*)d_out;

  float* p = (float*)d_ws;
  float* hin   = p; p += (size_t)NNODE*32;
  float* repr  = p; p += (size_t)NNODE*96;
  int*   deg   = (int*)p; p += NNODE;
  float* r123  = p; p += 3*NREL*32;
  float* WoT   = p; p += 96*192;
  float* ghid0 = p; p += BB*96;
  float* GIF   = p; p += (size_t)NNODE*288;
  float* GIB   = p; p += (size_t)NNODE*288;
  float* gruo  = p; p += (size_t)NNODE*192;
  float* goutb = p; p += BB*96;
  float* headb = p; p += BB*96;
  float* tailb = p; p += BB*96;
  float* lastb = p; p += (size_t)BB*64*32;

  hipMemsetAsync(deg, 0, NNODE*sizeof(int), stream);
  k_rel<<<1, 256, 0, stream>>>(rel_emb, W_rel, Wo_W, r123, WoT);
  k_deg<<<NEDGE/256, 256, 0, stream>>>(dst, deg);
  k_sem<<<NNODE/256, 256, 0, stream>>>(feat, out_rels, in_rels, r_label_nd,
                                       rel_emb, w2e_W, w2e_b, hin);
  for (int l = 0; l < 3; ++l) {
    const float* hsrc = (l == 0) ? hin : (repr + (l-1)*32);
    int hstride = (l == 0) ? 32 : 96;
    const float* r_l = (l == 0) ? rel_emb : (r123 + (l-1)*NREL*32);
    k_gnn<<<BB, 256, 0, stream>>>(hsrc, hstride, r_l, src, dst, etype, deg,
                                  W_msg + l*1024, W_self + l*1024, b_gnn + l*32,
                                  repr, l*32);
  }
  k_h0max<<<BB, 128, 0, stream>>>(repr, ghid0);
  k_gi<<<dim3(BB, 6), 128, 0, stream>>>(repr, gru_bias, Wih_f, bih_f, Wih_b, bih_b,
                                        GIF, GIB);
  k_gru<<<1024, 288, 0, stream>>>(Whh_f, bhh_f, Whh_b, bhh_b, GIF, GIB, ghid0, gruo);
  k_pool<<<BB, 128, 0, stream>>>(gruo, WoT, Wo_b, goutb, headb, tailb);
  k_path<<<BB, 64, 0, stream>>>(r123 + 2*NREL*32, in_rels, rel_labels,
                                pWih, pWhh, pbih, pbhh, lastb);
  k_final<<<BB, 64, 0, stream>>>(lastb, r123 + 2*NREL*32, rel_labels,
                                 goutb, headb, tailb, fcW, fcb, out);
}

// Round 2
// 1393.559 us; speedup vs baseline: 1.9141x; 1.9141x over previous
//
#include <hip/hip_runtime.h>
#include <math.h>

#define BB 512
#define NT 128
#define NREL 201
#define NNODE (BB*NT)
#define NEDGE (NNODE*16)

__device__ __forceinline__ float sigm(float x) { return 1.f/(1.f + __expf(-x)); }

// ---------------------------------------------------------------- k_rel
// rel chain r123; WT1[96][576] = [Wih_f;Wih_b]^T; bcat[576]; XI[201][96] = r3 @ pWih^T + pbih
__global__ void k_rel(const float* __restrict__ rel_emb, const float* __restrict__ W_rel,
                      const float* __restrict__ Wih_f, const float* __restrict__ Wih_b,
                      const float* __restrict__ bih_f, const float* __restrict__ bih_b,
                      const float* __restrict__ pWih, const float* __restrict__ pbih,
                      float* __restrict__ r123, float* __restrict__ WT1,
                      float* __restrict__ bcat, float* __restrict__ XI) {
  __shared__ float rcur[NREL*32];
  __shared__ float rnext[NREL*32];
  int tid = threadIdx.x;
  for (int i = tid; i < NREL*32; i += 256) rcur[i] = rel_emb[i];
  __syncthreads();
  for (int l = 0; l < 3; ++l) {
    const float* w = W_rel + l*1024;
    for (int i = tid; i < NREL*32; i += 256) {
      int row = i >> 5, col = i & 31;
      float s = 0.f;
      #pragma unroll
      for (int d = 0; d < 32; ++d) s += rcur[row*32 + d] * w[d*32 + col];
      rnext[i] = s;
    }
    __syncthreads();
    for (int i = tid; i < NREL*32; i += 256) { float v = rnext[i]; rcur[i] = v; r123[l*NREL*32 + i] = v; }
    __syncthreads();
  }
  for (int i = tid; i < 96*576; i += 256) {
    int k = i / 576, j = i - k*576;
    WT1[i] = (j < 288) ? Wih_f[j*96 + k] : Wih_b[(j-288)*96 + k];
  }
  for (int i = tid; i < 576; i += 256) bcat[i] = (i < 288) ? bih_f[i] : bih_b[i-288];
  for (int i = tid; i < NREL*96; i += 256) {
    int r = i / 96, j = i - r*96;
    float s = pbih[j];
    #pragma unroll
    for (int d = 0; d < 32; ++d) s += rcur[r*32 + d]*pWih[j*32 + d];
    XI[i] = s;
  }
}

// ---------------------------------------------------------------- k_deg
__global__ void k_deg(const int* __restrict__ dst, int* __restrict__ deg) {
  int e = blockIdx.x*256 + threadIdx.x;
  if (e < NEDGE) atomicAdd(&deg[dst[e]], 1);
}

// ---------------------------------------------------------------- k_sem
__device__ __forceinline__ void sem_att(const float* __restrict__ rel_emb,
                                        const int rels[8], const float tgt[32],
                                        float out[32]) {
  float dots[8]; float mx = -1e30f;
  #pragma unroll
  for (int k = 0; k < 8; ++k) {
    const float4* er = (const float4*)(rel_emb + rels[k]*32);
    float s = 0.f;
    #pragma unroll
    for (int q = 0; q < 8; ++q) {
      float4 v = er[q];
      s += v.x*tgt[4*q+0] + v.y*tgt[4*q+1] + v.z*tgt[4*q+2] + v.w*tgt[4*q+3];
    }
    dots[k] = s; mx = fmaxf(mx, s);
  }
  float den = 0.f;
  #pragma unroll
  for (int k = 0; k < 8; ++k) { float e = __expf(dots[k]-mx); dots[k] = e; den += e; }
  float inv = 1.f/den;
  #pragma unroll
  for (int d = 0; d < 32; ++d) out[d] = 0.f;
  #pragma unroll
  for (int k = 0; k < 8; ++k) {
    const float4* er = (const float4*)(rel_emb + rels[k]*32);
    float a = dots[k]*inv;
    #pragma unroll
    for (int q = 0; q < 8; ++q) {
      float4 v = er[q];
      out[4*q+0] += a*v.x; out[4*q+1] += a*v.y; out[4*q+2] += a*v.z; out[4*q+3] += a*v.w;
    }
  }
}

__global__ __launch_bounds__(256) void k_sem(
    const float* __restrict__ feat, const int* __restrict__ out_rels,
    const int* __restrict__ in_rels, const int* __restrict__ r_label_node,
    const float* __restrict__ rel_emb, const float* __restrict__ W,
    const float* __restrict__ bias, float* __restrict__ hin) {
  int n = blockIdx.x*256 + threadIdx.x;
  float tgt[32];
  {
    const float4* tr = (const float4*)(rel_emb + r_label_node[n]*32);
    #pragma unroll
    for (int q = 0; q < 8; ++q) {
      float4 v = tr[q];
      tgt[4*q+0]=v.x; tgt[4*q+1]=v.y; tgt[4*q+2]=v.z; tgt[4*q+3]=v.w;
    }
  }
  int ro[8], ri[8];
  #pragma unroll
  for (int k = 0; k < 8; ++k) { ro[k] = out_rels[n*8+k]; ri[k] = in_rels[n*8+k]; }
  float osem[32], isem[32];
  sem_att(rel_emb, ro, tgt, osem);
  sem_att(rel_emb, ri, tgt, isem);
  const float4* fr = (const float4*)(feat + (size_t)n*16);
  float4* ho = (float4*)(hin + (size_t)n*32);
  #pragma unroll
  for (int q = 0; q < 4; ++q) ho[q] = fr[q];
  #pragma unroll
  for (int j = 0; j < 16; ++j) {
    float s = bias[j];
    #pragma unroll
    for (int d = 0; d < 32; ++d) s += osem[d]*W[d*16+j] + isem[d]*W[(32+d)*16+j];
    hin[(size_t)n*32 + 16 + j] = sigm(s);
  }
}

// ---------------------------------------------------------------- k_gnn
__global__ __launch_bounds__(512) void k_gnn(
    const float* __restrict__ hsrc, int hstride, const float* __restrict__ r_l,
    const int* __restrict__ src, const int* __restrict__ dst, const int* __restrict__ etype,
    const int* __restrict__ deg, const float* __restrict__ Wm, const float* __restrict__ Ws,
    const float* __restrict__ bl, float* __restrict__ repr_out, int ofs) {
  __shared__ __align__(16) float hl[NT*32];
  __shared__ __align__(16) float agg[NT*32];
  __shared__ float rl[NREL*32];
  int g = blockIdx.x;
  int tid = threadIdx.x;
  for (int i = tid; i < NT*32; i += 512) {
    int row = i >> 5, col = i & 31;
    hl[i] = hsrc[(size_t)(g*NT + row)*hstride + col];
    agg[i] = 0.f;
  }
  for (int i = tid; i < NREL*32; i += 512) rl[i] = r_l[i];
  __syncthreads();
  {
    int d = tid & 31, grp = tid >> 5;   // 16 groups of 32 lanes
    int ebase = g*2048;
    for (int i = grp; i < 2048; i += 16) {
      int e = ebase + i;
      int sl = src[e] - g*NT;
      int dl = dst[e] - g*NT;
      float m = hl[sl*32 + d] * rl[etype[e]*32 + d];
      atomicAdd(&agg[dl*32 + d], m);
    }
  }
  __syncthreads();
  int j = tid & 31;
  float wm[32], ws[32];
  #pragma unroll
  for (int dd = 0; dd < 32; ++dd) { wm[dd] = Wm[dd*32+j]; ws[dd] = Ws[dd*32+j]; }
  float bj = bl[j];
  int nbase = tid >> 5;
  for (int k2 = 0; k2 < 8; ++k2) {
    int n = nbase + k2*16;
    int dv = deg[g*NT + n];
    float invd = 1.f / (float)(dv > 0 ? dv : 1);
    const float4* a4 = (const float4*)&agg[n*32];
    const float4* h4 = (const float4*)&hl[n*32];
    float sa = 0.f, sh = 0.f;
    #pragma unroll
    for (int q = 0; q < 8; ++q) {
      float4 av = a4[q], hv = h4[q];
      sa += av.x*wm[4*q+0] + av.y*wm[4*q+1] + av.z*wm[4*q+2] + av.w*wm[4*q+3];
      sh += hv.x*ws[4*q+0] + hv.y*ws[4*q+1] + hv.z*ws[4*q+2] + hv.w*ws[4*q+3];
    }
    float res = bj + invd*sa + sh;
    repr_out[(size_t)(g*NT + n)*96 + ofs + j] = fmaxf(res, 0.f);
  }
}

// ---------------------------------------------------------------- k_prep1 : AT = relu(repr+gbias)^T ; ghid0 = colmax(repr)
__global__ __launch_bounds__(256) void k_prep1(
    const float* __restrict__ repr, const float* __restrict__ gbias,
    float* __restrict__ AT, float* __restrict__ ghid0) {
  __shared__ float t[NT*97];
  int g = blockIdx.x, tid = threadIdx.x;
  const float* rb = repr + (size_t)g*NT*96;
  for (int i = tid; i < NT*96; i += 256) {
    int row = i / 96, col = i - row*96;
    t[row*97 + col] = rb[i];
  }
  __syncthreads();
  for (int i = tid; i < 96*NT; i += 256) {
    int k = i >> 7, n = i & 127;
    AT[(size_t)k*NNODE + g*NT + n] = fmaxf(t[n*97 + k] + gbias[k], 0.f);
  }
  if (tid < 96) {
    float m = -1e30f;
    for (int n = 0; n < NT; ++n) m = fmaxf(m, t[n*97 + tid]);
    ghid0[g*96 + tid] = m;
  }
}

// ---------------------------------------------------------------- k_gemm1 : GI[65536][576] = A(T) @ WT1 + bcat
__global__ __launch_bounds__(256) void k_gemm1(
    const float* __restrict__ AT, const float* __restrict__ WT1,
    const float* __restrict__ bcat, float* __restrict__ GI) {
  __shared__ __align__(16) float As[96*64];
  __shared__ __align__(16) float Bs[96*64];
  int nb = blockIdx.x, mb = blockIdx.y;
  int m0 = mb*64, n0 = nb*64;
  int tid = threadIdx.x;
  for (int i = tid; i < 1536; i += 256) {
    int r = i >> 4, c4 = i & 15;
    *(float4*)&As[r*64 + c4*4] = *(const float4*)&AT[(size_t)r*NNODE + m0 + c4*4];
  }
  for (int i = tid; i < 1536; i += 256) {
    int r = i >> 4, c4 = i & 15;
    *(float4*)&Bs[r*64 + c4*4] = *(const float4*)&WT1[r*576 + n0 + c4*4];
  }
  __syncthreads();
  int tc = tid & 15, tr = tid >> 4;
  int r0 = tr*4, c0 = tc*4;
  float acc[4][4] = {};
  #pragma unroll 8
  for (int k = 0; k < 96; ++k) {
    float4 a = *(float4*)&As[k*64 + r0];
    float4 b = *(float4*)&Bs[k*64 + c0];
    acc[0][0] += a.x*b.x; acc[0][1] += a.x*b.y; acc[0][2] += a.x*b.z; acc[0][3] += a.x*b.w;
    acc[1][0] += a.y*b.x; acc[1][1] += a.y*b.y; acc[1][2] += a.y*b.z; acc[1][3] += a.y*b.w;
    acc[2][0] += a.z*b.x; acc[2][1] += a.z*b.y; acc[2][2] += a.z*b.z; acc[2][3] += a.z*b.w;
    acc[3][0] += a.w*b.x; acc[3][1] += a.w*b.y; acc[3][2] += a.w*b.z; acc[3][3] += a.w*b.w;
  }
  float4 bia = *(const float4*)&bcat[n0 + c0];
  #pragma unroll
  for (int r = 0; r < 4; ++r) {
    float4 o = make_float4(acc[r][0]+bia.x, acc[r][1]+bia.y, acc[r][2]+bia.z, acc[r][3]+bia.w);
    *(float4*)&GI[(size_t)(m0 + r0 + r)*576 + n0 + c0] = o;
  }
}

// ---------------------------------------------------------------- k_gru : 2 (dir,graph) pairs per block
__global__ __launch_bounds__(288) void k_gru(
    const float* __restrict__ Whh_f, const float* __restrict__ bhh_f,
    const float* __restrict__ Whh_b, const float* __restrict__ bhh_b,
    const float* __restrict__ GI, const float* __restrict__ ghid0,
    float* __restrict__ gruout) {
  __shared__ __align__(16) float h_lds[2][96];
  __shared__ float gh_lds[2][288];
  __shared__ float gi_lds[2][288];
  int bx = blockIdx.x;            // 512 blocks
  int dir = bx >> 8;
  int gbase = (bx & 255)*2;
  int j = threadIdx.x;            // 0..287
  const float* Whh = dir ? Whh_b : Whh_f;
  float bj = (dir ? bhh_b : bhh_f)[j];
  float4 w[24];
  {
    const float4* wr = (const float4*)(Whh + (size_t)j*96);
    #pragma unroll
    for (int q = 0; q < 24; ++q) w[q] = wr[q];
  }
  if (j < 96) {
    h_lds[0][j] = ghid0[gbase*96 + j];
    h_lds[1][j] = ghid0[(gbase+1)*96 + j];
  }
  int pos0 = dir ? 127 : 0;
  float gp0 = GI[(size_t)(gbase*128 + pos0)*576 + dir*288 + j];
  float gp1 = GI[(size_t)((gbase+1)*128 + pos0)*576 + dir*288 + j];
  __syncthreads();
  for (int t = 0; t < 128; ++t) {
    int pos  = dir ? (127-t) : t;
    int posn = dir ? (126-t) : (t+1);
    gi_lds[0][j] = gp0; gi_lds[1][j] = gp1;
    float acc0 = bj, acc1 = bj;
    #pragma unroll
    for (int q = 0; q < 24; ++q) {
      float4 h0 = *(float4*)&h_lds[0][4*q];
      float4 h1 = *(float4*)&h_lds[1][4*q];
      acc0 += w[q].x*h0.x + w[q].y*h0.y + w[q].z*h0.z + w[q].w*h0.w;
      acc1 += w[q].x*h1.x + w[q].y*h1.y + w[q].z*h1.z + w[q].w*h1.w;
    }
    gh_lds[0][j] = acc0; gh_lds[1][j] = acc1;
    if (t < 127) {
      gp0 = GI[(size_t)(gbase*128 + posn)*576 + dir*288 + j];
      gp1 = GI[(size_t)((gbase+1)*128 + posn)*576 + dir*288 + j];
    }
    __syncthreads();
    if (j < 96) {
      #pragma unroll
      for (int i = 0; i < 2; ++i) {
        float r = sigm(gi_lds[i][j] + gh_lds[i][j]);
        float z = sigm(gi_lds[i][96+j] + gh_lds[i][96+j]);
        float nn = tanhf(gi_lds[i][192+j] + r*gh_lds[i][192+j]);
        float hv = (1.f - z)*nn + z*h_lds[i][j];
        h_lds[i][j] = hv;
        gruout[(size_t)((gbase+i)*128 + pos)*192 + dir*96 + j] = hv;
      }
    }
    __syncthreads();
  }
}

// ---------------------------------------------------------------- k_prep2 : AT2 = relu(gruout)^T
__global__ __launch_bounds__(256) void k_prep2(const float* __restrict__ gruo,
                                               float* __restrict__ AT2) {
  __shared__ float t[NT*97];
  int g = blockIdx.x, half = blockIdx.y, tid = threadIdx.x;
  const float* rb = gruo + (size_t)g*NT*192 + half*96;
  for (int i = tid; i < NT*96; i += 256) {
    int row = i / 96, col = i - row*96;
    t[row*97 + col] = rb[(size_t)row*192 + col];
  }
  __syncthreads();
  for (int i = tid; i < 96*NT; i += 256) {
    int k = i >> 7, n = i & 127;
    AT2[(size_t)(half*96 + k)*NNODE + g*NT + n] = fmaxf(t[n*97 + k], 0.f);
  }
}

// ---------------------------------------------------------------- k_gemm2 : nh = relu(A2 @ Wo + b)
__global__ __launch_bounds__(384) void k_gemm2(
    const float* __restrict__ AT2, const float* __restrict__ WoW,
    const float* __restrict__ Wob, float* __restrict__ nh) {
  __shared__ __align__(16) float As[96*64];
  __shared__ __align__(16) float Bs[96*96];
  int m0 = blockIdx.x*64;
  int tid = threadIdx.x;
  int tc = tid % 24, tr = tid / 24;   // tr<16
  int r0 = tr*4, c0 = tc*4;
  float acc[4][4] = {};
  for (int kc = 0; kc < 2; ++kc) {
    for (int i = tid; i < 1536; i += 384) {
      int r = i >> 4, c4 = i & 15;
      *(float4*)&As[r*64 + c4*4] = *(const float4*)&AT2[(size_t)(kc*96 + r)*NNODE + m0 + c4*4];
    }
    for (int i = tid; i < 2304; i += 384) {
      int r = i / 24, c4 = i % 24;
      *(float4*)&Bs[r*96 + c4*4] = *(const float4*)&WoW[(size_t)(kc*96 + r)*96 + c4*4];
    }
    __syncthreads();
    #pragma unroll 8
    for (int k = 0; k < 96; ++k) {
      float4 a = *(float4*)&As[k*64 + r0];
      float4 b = *(float4*)&Bs[k*96 + c0];
      acc[0][0] += a.x*b.x; acc[0][1] += a.x*b.y; acc[0][2] += a.x*b.z; acc[0][3] += a.x*b.w;
      acc[1][0] += a.y*b.x; acc[1][1] += a.y*b.y; acc[1][2] += a.y*b.z; acc[1][3] += a.y*b.w;
      acc[2][0] += a.z*b.x; acc[2][1] += a.z*b.y; acc[2][2] += a.z*b.z; acc[2][3] += a.z*b.w;
      acc[3][0] += a.w*b.x; acc[3][1] += a.w*b.y; acc[3][2] += a.w*b.z; acc[3][3] += a.w*b.w;
    }
    __syncthreads();
  }
  float4 bia = *(const float4*)&Wob[c0];
  #pragma unroll
  for (int r = 0; r < 4; ++r) {
    float4 o = make_float4(fmaxf(acc[r][0]+bia.x, 0.f), fmaxf(acc[r][1]+bia.y, 0.f),
                           fmaxf(acc[r][2]+bia.z, 0.f), fmaxf(acc[r][3]+bia.w, 0.f));
    *(float4*)&nh[(size_t)(m0 + r0 + r)*96 + c0] = o;
  }
}

// ---------------------------------------------------------------- k_pool2
__global__ __launch_bounds__(128) void k_pool2(const float* __restrict__ nh,
                                               float* __restrict__ goutb,
                                               float* __restrict__ headb,
                                               float* __restrict__ tailb) {
  int g = blockIdx.x, j = threadIdx.x;
  if (j >= 96) return;
  const float* base = nh + (size_t)g*NT*96;
  float s = 0.f;
  for (int n = 0; n < NT; ++n) s += base[(size_t)n*96 + j];
  goutb[g*96 + j] = s * (1.f/128.f);
  headb[g*96 + j] = base[j];
  tailb[g*96 + j] = base[96 + j];
}

// ---------------------------------------------------------------- k_path : XI-precomputed 3-step GRU
__global__ __launch_bounds__(128) void k_path(
    const float* __restrict__ XI, const int* __restrict__ in_rels,
    const int* __restrict__ labels, const float* __restrict__ pWhh,
    const float* __restrict__ pbhh, float* __restrict__ last) {
  __shared__ __align__(16) float wsh[96*32];
  __shared__ float bsh[96];
  __shared__ float hbuf[128*33];
  int tid = threadIdx.x;
  for (int i = tid; i < 96*32; i += 128) wsh[i] = pWhh[i];
  if (tid < 96) bsh[tid] = pbhh[tid];
  int p = blockIdx.x*128 + tid;
  int b = p >> 6, pp = p & 63;
  int rid0 = in_rels[b*1024 + (pp >> 3)];
  int rid1 = labels[b];
  int rid2 = in_rels[b*1024 + 8 + (pp & 7)];
  __syncthreads();
  float* hs = &hbuf[tid*33];
  {
    const float* xi = XI + rid0*96;
    #pragma unroll
    for (int gg = 0; gg < 32; ++gg) {
      float r = sigm(xi[gg] + bsh[gg]);
      float z = sigm(xi[32+gg] + bsh[32+gg]);
      float nn = tanhf(xi[64+gg] + r*bsh[64+gg]);
      hs[gg] = (1.f - z)*nn;
    }
  }
  float4 h4[8];
  #pragma unroll
  for (int q = 0; q < 8; ++q) h4[q] = make_float4(hs[4*q], hs[4*q+1], hs[4*q+2], hs[4*q+3]);
  for (int s = 0; s < 2; ++s) {
    const float* xi = XI + (s == 0 ? rid1 : rid2)*96;
    for (int gg = 0; gg < 32; ++gg) {
      float ar = bsh[gg], az = bsh[32+gg], an = bsh[64+gg];
      const float4* wr = (const float4*)&wsh[gg*32];
      const float4* wz = (const float4*)&wsh[(32+gg)*32];
      const float4* wn = (const float4*)&wsh[(64+gg)*32];
      #pragma unroll
      for (int q = 0; q < 8; ++q) {
        float4 hv = h4[q]; float4 w;
        w = wr[q]; ar += hv.x*w.x + hv.y*w.y + hv.z*w.z + hv.w*w.w;
        w = wz[q]; az += hv.x*w.x + hv.y*w.y + hv.z*w.z + hv.w*w.w;
        w = wn[q]; an += hv.x*w.x + hv.y*w.y + hv.z*w.z + hv.w*w.w;
      }
      float r = sigm(xi[gg] + ar);
      float z = sigm(xi[32+gg] + az);
      float nn = tanhf(xi[64+gg] + r*an);
      hs[gg] = (1.f - z)*nn + z*hs[gg];
    }
    #pragma unroll
    for (int q = 0; q < 8; ++q) h4[q] = make_float4(hs[4*q], hs[4*q+1], hs[4*q+2], hs[4*q+3]);
  }
  float* lp = last + (size_t)p*32;
  #pragma unroll
  for (int d = 0; d < 32; ++d) lp[d] = hs[d];
}

// ---------------------------------------------------------------- k_final
__global__ __launch_bounds__(64) void k_final(
    const float* __restrict__ last, const float* __restrict__ r3,
    const int* __restrict__ labels, const float* __restrict__ goutb,
    const float* __restrict__ headb, const float* __restrict__ tailb,
    const float* __restrict__ fcW, const float* __restrict__ fcb,
    float* __restrict__ out) {
  __shared__ float red[64*33];
  __shared__ float gpl[32];
  int b = blockIdx.x, lane = threadIdx.x;
  const float* rl = r3 + labels[b]*32;
  float l32[32];
  {
    const float4* lr = (const float4*)(last + (size_t)(b*64 + lane)*32);
    #pragma unroll
    for (int q = 0; q < 8; ++q) {
      float4 v = lr[q];
      l32[4*q+0]=v.x; l32[4*q+1]=v.y; l32[4*q+2]=v.z; l32[4*q+3]=v.w;
    }
  }
  float s = 0.f;
  #pragma unroll
  for (int d = 0; d < 32; ++d) s += l32[d]*rl[d];
  float mx = s;
  #pragma unroll
  for (int off = 32; off > 0; off >>= 1) mx = fmaxf(mx, __shfl_xor(mx, off));
  float e = __expf(s - mx);
  float den = e;
  #pragma unroll
  for (int off = 32; off > 0; off >>= 1) den += __shfl_xor(den, off);
  float att = e / den;
  #pragma unroll
  for (int d = 0; d < 32; ++d) red[lane*33 + d] = att*l32[d];
  __syncthreads();
  if (lane < 32) {
    float gp = 0.f;
    for (int p2 = 0; p2 < 64; ++p2) gp += red[p2*33 + lane];
    gpl[lane] = gp;
  }
  __syncthreads();
  float acc = 0.f;
  for (int i = lane; i < 352; i += 64) {
    float v;
    if (i < 96)       v = goutb[b*96 + i];
    else if (i < 192) v = headb[b*96 + (i-96)];
    else if (i < 288) v = tailb[b*96 + (i-192)];
    else if (i < 320) v = rl[i-288];
    else              v = gpl[i-320];
    acc += v*fcW[i];
  }
  #pragma unroll
  for (int off = 32; off > 0; off >>= 1) acc += __shfl_xor(acc, off);
  if (lane == 0) out[b] = acc + fcb[0];
}

// ---------------------------------------------------------------- launch
extern "C" void kernel_launch(void* const* d_in, const int* in_sizes, int n_in,
                              void* d_out, int out_size, void* d_ws, size_t ws_size,
                              hipStream_t stream) {
  const float* feat       = (const float*)d_in[0];
  const int*   out_rels   = (const int*)d_in[1];
  const int*   in_rels    = (const int*)d_in[2];
  const int*   r_label_nd = (const int*)d_in[3];
  const int*   src        = (const int*)d_in[4];
  const int*   dst        = (const int*)d_in[5];
  const int*   etype      = (const int*)d_in[6];
  const int*   rel_labels = (const int*)d_in[7];
  const float* rel_emb    = (const float*)d_in[8];
  const float* w2e_W      = (const float*)d_in[9];
  const float* w2e_b      = (const float*)d_in[10];
  const float* W_msg      = (const float*)d_in[11];
  const float* W_self     = (const float*)d_in[12];
  const float* b_gnn      = (const float*)d_in[13];
  const float* W_rel      = (const float*)d_in[14];
  const float* gru_bias   = (const float*)d_in[15];
  const float* Wih_f      = (const float*)d_in[16];
  const float* Whh_f      = (const float*)d_in[17];
  const float* bih_f      = (const float*)d_in[18];
  const float* bhh_f      = (const float*)d_in[19];
  const float* Wih_b      = (const float*)d_in[20];
  const float* Whh_b      = (const float*)d_in[21];
  const float* bih_b      = (const float*)d_in[22];
  const float* bhh_b      = (const float*)d_in[23];
  const float* Wo_W       = (const float*)d_in[24];
  const float* Wo_b       = (const float*)d_in[25];
  const float* pWih       = (const float*)d_in[26];
  const float* pWhh       = (const float*)d_in[27];
  const float* pbih       = (const float*)d_in[28];
  const float* pbhh       = (const float*)d_in[29];
  const float* fcW        = (const float*)d_in[30];
  const float* fcb        = (const float*)d_in[31];
  float* out = (float*)d_out;

  // workspace overlay:
  //   hin [NNODE*32]
  //   R1  [NNODE*192] : repr [NNODE*96] | AT [96*NNODE]  -> later gruo [NNODE*192]
  //   R2  [NNODE*576] : GI              -> later AT2 [192*NNODE] | nh [NNODE*96]
  float* p = (float*)d_ws;
  float* hin   = p; p += (size_t)NNODE*32;
  float* R1    = p; p += (size_t)NNODE*192;
  float* repr  = R1;
  float* AT    = R1 + (size_t)NNODE*96;
  float* gruo  = R1;
  float* R2    = p; p += (size_t)NNODE*576;
  float* GI    = R2;
  float* AT2   = R2;
  float* nh    = R2 + (size_t)192*NNODE;
  int*   deg   = (int*)p; p += NNODE;
  float* r123  = p; p += 3*NREL*32;
  float* WT1   = p; p += 96*576;
  float* bcat  = p; p += 576;
  float* XI    = p; p += NREL*96;
  float* ghid0 = p; p += BB*96;
  float* goutb = p; p += BB*96;
  float* headb = p; p += BB*96;
  float* tailb = p; p += BB*96;
  float* lastb = p; p += (size_t)BB*64*32;

  hipMemsetAsync(deg, 0, NNODE*sizeof(int), stream);
  k_rel<<<1, 256, 0, stream>>>(rel_emb, W_rel, Wih_f, Wih_b, bih_f, bih_b,
                               pWih, pbih, r123, WT1, bcat, XI);
  k_deg<<<NEDGE/256, 256, 0, stream>>>(dst, deg);
  k_sem<<<NNODE/256, 256, 0, stream>>>(feat, out_rels, in_rels, r_label_nd,
                                       rel_emb, w2e_W, w2e_b, hin);
  for (int l = 0; l < 3; ++l) {
    const float* hsrc = (l == 0) ? hin : (repr + (l-1)*32);
    int hstride = (l == 0) ? 32 : 96;
    const float* r_l = (l == 0) ? rel_emb : (r123 + (l-1)*NREL*32);
    k_gnn<<<BB, 512, 0, stream>>>(hsrc, hstride, r_l, src, dst, etype, deg,
                                  W_msg + l*1024, W_self + l*1024, b_gnn + l*32,
                                  repr, l*32);
  }
  k_prep1<<<BB, 256, 0, stream>>>(repr, gru_bias, AT, ghid0);
  k_gemm1<<<dim3(9, 1024), 256, 0, stream>>>(AT, WT1, bcat, GI);
  k_gru<<<512, 288, 0, stream>>>(Whh_f, bhh_f, Whh_b, bhh_b, GI, ghid0, gruo);
  k_prep2<<<dim3(BB, 2), 256, 0, stream>>>(gruo, AT2);
  k_gemm2<<<1024, 384, 0, stream>>>(AT2, Wo_W, Wo_b, nh);
  k_pool2<<<BB, 128, 0, stream>>>(nh, goutb, headb, tailb);
  k_path<<<256, 128, 0, stream>>>(XI, in_rels, rel_labels, pWhh, pbhh, lastb);
  k_final<<<BB, 64, 0, stream>>>(lastb, r123 + 2*NREL*32, rel_labels,
                                 goutb, headb, tailb, fcW, fcb, out);
}

// Round 3
// 1381.631 us; speedup vs baseline: 1.9306x; 1.0086x over previous
//
#include <hip/hip_runtime.h>
#include <math.h>

#define BB 512
#define NT 128
#define NREL 201
#define NNODE (BB*NT)
#define NEDGE (NNODE*16)

__device__ __forceinline__ float sigm(float x) { return 1.f/(1.f + __expf(-x)); }

// ---------------------------------------------------------------- k_rel
// rel chain r123; WT1[96][576] = [Wih_f;Wih_b]^T; bcat[576]; XI[201][96] = r3 @ pWih^T + pbih
__global__ void k_rel(const float* __restrict__ rel_emb, const float* __restrict__ W_rel,
                      const float* __restrict__ Wih_f, const float* __restrict__ Wih_b,
                      const float* __restrict__ bih_f, const float* __restrict__ bih_b,
                      const float* __restrict__ pWih, const float* __restrict__ pbih,
                      float* __restrict__ r123, float* __restrict__ WT1,
                      float* __restrict__ bcat, float* __restrict__ XI) {
  __shared__ float rcur[NREL*32];
  __shared__ float rnext[NREL*32];
  int tid = threadIdx.x;
  for (int i = tid; i < NREL*32; i += 256) rcur[i] = rel_emb[i];
  __syncthreads();
  for (int l = 0; l < 3; ++l) {
    const float* w = W_rel + l*1024;
    for (int i = tid; i < NREL*32; i += 256) {
      int row = i >> 5, col = i & 31;
      float s = 0.f;
      #pragma unroll
      for (int d = 0; d < 32; ++d) s += rcur[row*32 + d] * w[d*32 + col];
      rnext[i] = s;
    }
    __syncthreads();
    for (int i = tid; i < NREL*32; i += 256) { float v = rnext[i]; rcur[i] = v; r123[l*NREL*32 + i] = v; }
    __syncthreads();
  }
  for (int i = tid; i < 96*576; i += 256) {
    int k = i / 576, j = i - k*576;
    WT1[i] = (j < 288) ? Wih_f[j*96 + k] : Wih_b[(j-288)*96 + k];
  }
  for (int i = tid; i < 576; i += 256) bcat[i] = (i < 288) ? bih_f[i] : bih_b[i-288];
  for (int i = tid; i < NREL*96; i += 256) {
    int r = i / 96, j = i - r*96;
    float s = pbih[j];
    #pragma unroll
    for (int d = 0; d < 32; ++d) s += rcur[r*32 + d]*pWih[j*32 + d];
    XI[i] = s;
  }
}

// ---------------------------------------------------------------- k_deg
__global__ void k_deg(const int* __restrict__ dst, int* __restrict__ deg) {
  int e = blockIdx.x*256 + threadIdx.x;
  if (e < NEDGE) atomicAdd(&deg[dst[e]], 1);
}

// ---------------------------------------------------------------- k_sem
__device__ __forceinline__ void sem_att(const float* __restrict__ rel_emb,
                                        const int rels[8], const float tgt[32],
                                        float out[32]) {
  float dots[8]; float mx = -1e30f;
  #pragma unroll
  for (int k = 0; k < 8; ++k) {
    const float4* er = (const float4*)(rel_emb + rels[k]*32);
    float s = 0.f;
    #pragma unroll
    for (int q = 0; q < 8; ++q) {
      float4 v = er[q];
      s += v.x*tgt[4*q+0] + v.y*tgt[4*q+1] + v.z*tgt[4*q+2] + v.w*tgt[4*q+3];
    }
    dots[k] = s; mx = fmaxf(mx, s);
  }
  float den = 0.f;
  #pragma unroll
  for (int k = 0; k < 8; ++k) { float e = __expf(dots[k]-mx); dots[k] = e; den += e; }
  float inv = 1.f/den;
  #pragma unroll
  for (int d = 0; d < 32; ++d) out[d] = 0.f;
  #pragma unroll
  for (int k = 0; k < 8; ++k) {
    const float4* er = (const float4*)(rel_emb + rels[k]*32);
    float a = dots[k]*inv;
    #pragma unroll
    for (int q = 0; q < 8; ++q) {
      float4 v = er[q];
      out[4*q+0] += a*v.x; out[4*q+1] += a*v.y; out[4*q+2] += a*v.z; out[4*q+3] += a*v.w;
    }
  }
}

__global__ __launch_bounds__(256) void k_sem(
    const float* __restrict__ feat, const int* __restrict__ out_rels,
    const int* __restrict__ in_rels, const int* __restrict__ r_label_node,
    const float* __restrict__ rel_emb, const float* __restrict__ W,
    const float* __restrict__ bias, float* __restrict__ hin) {
  int n = blockIdx.x*256 + threadIdx.x;
  float tgt[32];
  {
    const float4* tr = (const float4*)(rel_emb + r_label_node[n]*32);
    #pragma unroll
    for (int q = 0; q < 8; ++q) {
      float4 v = tr[q];
      tgt[4*q+0]=v.x; tgt[4*q+1]=v.y; tgt[4*q+2]=v.z; tgt[4*q+3]=v.w;
    }
  }
  int ro[8], ri[8];
  #pragma unroll
  for (int k = 0; k < 8; ++k) { ro[k] = out_rels[n*8+k]; ri[k] = in_rels[n*8+k]; }
  float osem[32], isem[32];
  sem_att(rel_emb, ro, tgt, osem);
  sem_att(rel_emb, ri, tgt, isem);
  const float4* fr = (const float4*)(feat + (size_t)n*16);
  float4* ho = (float4*)(hin + (size_t)n*32);
  #pragma unroll
  for (int q = 0; q < 4; ++q) ho[q] = fr[q];
  #pragma unroll
  for (int j = 0; j < 16; ++j) {
    float s = bias[j];
    #pragma unroll
    for (int d = 0; d < 32; ++d) s += osem[d]*W[d*16+j] + isem[d]*W[(32+d)*16+j];
    hin[(size_t)n*32 + 16 + j] = sigm(s);
  }
}

// ---------------------------------------------------------------- k_gnn
__global__ __launch_bounds__(512) void k_gnn(
    const float* __restrict__ hsrc, int hstride, const float* __restrict__ r_l,
    const int* __restrict__ src, const int* __restrict__ dst, const int* __restrict__ etype,
    const int* __restrict__ deg, const float* __restrict__ Wm, const float* __restrict__ Ws,
    const float* __restrict__ bl, float* __restrict__ repr_out, int ofs) {
  __shared__ __align__(16) float hl[NT*32];
  __shared__ __align__(16) float agg[NT*32];
  __shared__ float rl[NREL*32];
  int g = blockIdx.x;
  int tid = threadIdx.x;
  for (int i = tid; i < NT*32; i += 512) {
    int row = i >> 5, col = i & 31;
    hl[i] = hsrc[(size_t)(g*NT + row)*hstride + col];
    agg[i] = 0.f;
  }
  for (int i = tid; i < NREL*32; i += 512) rl[i] = r_l[i];
  __syncthreads();
  {
    int d = tid & 31, grp = tid >> 5;   // 16 groups of 32 lanes
    int ebase = g*2048;
    for (int i = grp; i < 2048; i += 16) {
      int e = ebase + i;
      int sl = src[e] - g*NT;
      int dl = dst[e] - g*NT;
      float m = hl[sl*32 + d] * rl[etype[e]*32 + d];
      atomicAdd(&agg[dl*32 + d], m);
    }
  }
  __syncthreads();
  int j = tid & 31;
  float wm[32], ws[32];
  #pragma unroll
  for (int dd = 0; dd < 32; ++dd) { wm[dd] = Wm[dd*32+j]; ws[dd] = Ws[dd*32+j]; }
  float bj = bl[j];
  int nbase = tid >> 5;
  for (int k2 = 0; k2 < 8; ++k2) {
    int n = nbase + k2*16;
    int dv = deg[g*NT + n];
    float invd = 1.f / (float)(dv > 0 ? dv : 1);
    const float4* a4 = (const float4*)&agg[n*32];
    const float4* h4 = (const float4*)&hl[n*32];
    float sa = 0.f, sh = 0.f;
    #pragma unroll
    for (int q = 0; q < 8; ++q) {
      float4 av = a4[q], hv = h4[q];
      sa += av.x*wm[4*q+0] + av.y*wm[4*q+1] + av.z*wm[4*q+2] + av.w*wm[4*q+3];
      sh += hv.x*ws[4*q+0] + hv.y*ws[4*q+1] + hv.z*ws[4*q+2] + hv.w*ws[4*q+3];
    }
    float res = bj + invd*sa + sh;
    repr_out[(size_t)(g*NT + n)*96 + ofs + j] = fmaxf(res, 0.f);
  }
}

// ---------------------------------------------------------------- k_prep1 : AT = relu(repr+gbias)^T ; ghid0 = colmax(repr)
__global__ __launch_bounds__(256) void k_prep1(
    const float* __restrict__ repr, const float* __restrict__ gbias,
    float* __restrict__ AT, float* __restrict__ ghid0) {
  __shared__ float t[NT*97];
  int g = blockIdx.x, tid = threadIdx.x;
  const float* rb = repr + (size_t)g*NT*96;
  for (int i = tid; i < NT*96; i += 256) {
    int row = i / 96, col = i - row*96;
    t[row*97 + col] = rb[i];
  }
  __syncthreads();
  for (int i = tid; i < 96*NT; i += 256) {
    int k = i >> 7, n = i & 127;
    AT[(size_t)k*NNODE + g*NT + n] = fmaxf(t[n*97 + k] + gbias[k], 0.f);
  }
  if (tid < 96) {
    float m = -1e30f;
    for (int n = 0; n < NT; ++n) m = fmaxf(m, t[n*97 + tid]);
    ghid0[g*96 + tid] = m;
  }
}

// ---------------------------------------------------------------- k_gemm1 : GI[65536][576] = A(T) @ WT1 + bcat  (BM=128,BN=64,K=96)
__global__ __launch_bounds__(256) void k_gemm1(
    const float* __restrict__ AT, const float* __restrict__ WT1,
    const float* __restrict__ bcat, float* __restrict__ GI) {
  __shared__ __align__(16) float As[96*128];
  __shared__ __align__(16) float Bs[96*64];
  int nb = blockIdx.x;   // 0..8
  int mb = blockIdx.y;   // 0..511
  int m0 = mb*128, n0 = nb*64;
  int tid = threadIdx.x;
  for (int i = tid; i < 3072; i += 256) {
    int r = i >> 5, c4 = i & 31;
    *(float4*)&As[r*128 + c4*4] = *(const float4*)&AT[(size_t)r*NNODE + m0 + c4*4];
  }
  for (int i = tid; i < 1536; i += 256) {
    int r = i >> 4, c4 = i & 15;
    *(float4*)&Bs[r*64 + c4*4] = *(const float4*)&WT1[r*576 + n0 + c4*4];
  }
  __syncthreads();
  int tc = tid & 15, tr = tid >> 4;
  int r0 = tr*8, c0 = tc*4;
  float acc[8][4] = {};
  #pragma unroll 4
  for (int k = 0; k < 96; ++k) {
    float4 a0 = *(float4*)&As[k*128 + r0];
    float4 a1 = *(float4*)&As[k*128 + r0 + 4];
    float4 b  = *(float4*)&Bs[k*64 + c0];
    acc[0][0]+=a0.x*b.x; acc[0][1]+=a0.x*b.y; acc[0][2]+=a0.x*b.z; acc[0][3]+=a0.x*b.w;
    acc[1][0]+=a0.y*b.x; acc[1][1]+=a0.y*b.y; acc[1][2]+=a0.y*b.z; acc[1][3]+=a0.y*b.w;
    acc[2][0]+=a0.z*b.x; acc[2][1]+=a0.z*b.y; acc[2][2]+=a0.z*b.z; acc[2][3]+=a0.z*b.w;
    acc[3][0]+=a0.w*b.x; acc[3][1]+=a0.w*b.y; acc[3][2]+=a0.w*b.z; acc[3][3]+=a0.w*b.w;
    acc[4][0]+=a1.x*b.x; acc[4][1]+=a1.x*b.y; acc[4][2]+=a1.x*b.z; acc[4][3]+=a1.x*b.w;
    acc[5][0]+=a1.y*b.x; acc[5][1]+=a1.y*b.y; acc[5][2]+=a1.y*b.z; acc[5][3]+=a1.y*b.w;
    acc[6][0]+=a1.z*b.x; acc[6][1]+=a1.z*b.y; acc[6][2]+=a1.z*b.z; acc[6][3]+=a1.z*b.w;
    acc[7][0]+=a1.w*b.x; acc[7][1]+=a1.w*b.y; acc[7][2]+=a1.w*b.z; acc[7][3]+=a1.w*b.w;
  }
  float4 bia = *(const float4*)&bcat[n0 + c0];
  #pragma unroll
  for (int r = 0; r < 8; ++r) {
    float4 o = make_float4(acc[r][0]+bia.x, acc[r][1]+bia.y, acc[r][2]+bia.z, acc[r][3]+bia.w);
    *(float4*)&GI[(size_t)(m0 + r0 + r)*576 + n0 + c0] = o;
  }
}

// ---------------------------------------------------------------- k_gru : K-split-3, 2 seqs/block, weights resident
__global__ __launch_bounds__(288, 3) void k_gru(
    const float* __restrict__ Whh_f, const float* __restrict__ bhh_f,
    const float* __restrict__ Whh_b, const float* __restrict__ bhh_b,
    const float* __restrict__ GI, const float* __restrict__ ghid0,
    float* __restrict__ gruout) {
  __shared__ __align__(16) float h_lds[2][96];
  __shared__ float part[2][3][288];   // [seq][p][j]
  int bx = blockIdx.x;                // 512 blocks
  int dir = bx >> 8;
  int gbase = (bx & 255) * 2;
  int tid = threadIdx.x;
  int c = tid % 96;                   // 0..95
  int p = tid / 96;                   // 0..2  (K chunk)
  const float* Whh = dir ? Whh_b : Whh_f;
  const float* bhh = dir ? bhh_b : bhh_f;
  // rows c, 96+c, 192+c restricted to K in [32p, 32p+32): 96 floats total
  float4 w0[8], w1[8], w2[8];
  {
    const float4* wr0 = (const float4*)(Whh + (size_t)c*96 + p*32);
    const float4* wr1 = (const float4*)(Whh + (size_t)(96+c)*96 + p*32);
    const float4* wr2 = (const float4*)(Whh + (size_t)(192+c)*96 + p*32);
    #pragma unroll
    for (int q = 0; q < 8; ++q) { w0[q]=wr0[q]; w1[q]=wr1[q]; w2[q]=wr2[q]; }
  }
  float b0=0.f,b1=0.f,b2=0.f;
  float gi00=0.f,gi01=0.f,gi02=0.f, gi10=0.f,gi11=0.f,gi12=0.f;
  if (p == 0) {
    b0 = bhh[c]; b1 = bhh[96+c]; b2 = bhh[192+c];
    h_lds[0][c] = ghid0[gbase*96 + c];
    h_lds[1][c] = ghid0[(gbase+1)*96 + c];
    int pos0 = dir ? 127 : 0;
    const float* g0 = GI + (size_t)(gbase*128 + pos0)*576 + dir*288;
    const float* g1 = GI + (size_t)((gbase+1)*128 + pos0)*576 + dir*288;
    gi00 = g0[c]; gi01 = g0[96+c]; gi02 = g0[192+c];
    gi10 = g1[c]; gi11 = g1[96+c]; gi12 = g1[192+c];
  }
  __syncthreads();
  for (int t = 0; t < 128; ++t) {
    int pos  = dir ? (127-t) : t;
    int posn = dir ? (126-t) : (t+1);
    float a00=0.f,a01=0.f,a02=0.f,a10=0.f,a11=0.f,a12=0.f;
    #pragma unroll
    for (int q = 0; q < 8; ++q) {
      float4 h0 = *(const float4*)&h_lds[0][p*32 + 4*q];
      a00 += w0[q].x*h0.x + w0[q].y*h0.y + w0[q].z*h0.z + w0[q].w*h0.w;
      a01 += w1[q].x*h0.x + w1[q].y*h0.y + w1[q].z*h0.z + w1[q].w*h0.w;
      a02 += w2[q].x*h0.x + w2[q].y*h0.y + w2[q].z*h0.z + w2[q].w*h0.w;
      float4 h1 = *(const float4*)&h_lds[1][p*32 + 4*q];
      a10 += w0[q].x*h1.x + w0[q].y*h1.y + w0[q].z*h1.z + w0[q].w*h1.w;
      a11 += w1[q].x*h1.x + w1[q].y*h1.y + w1[q].z*h1.z + w1[q].w*h1.w;
      a12 += w2[q].x*h1.x + w2[q].y*h1.y + w2[q].z*h1.z + w2[q].w*h1.w;
    }
    part[0][p][c] = a00; part[0][p][96+c] = a01; part[0][p][192+c] = a02;
    part[1][p][c] = a10; part[1][p][96+c] = a11; part[1][p][192+c] = a12;
    __syncthreads();
    if (p == 0) {
      {
        float ghr = part[0][0][c]     + part[0][1][c]     + part[0][2][c]     + b0;
        float ghz = part[0][0][96+c]  + part[0][1][96+c]  + part[0][2][96+c]  + b1;
        float ghn = part[0][0][192+c] + part[0][1][192+c] + part[0][2][192+c] + b2;
        float r = sigm(gi00 + ghr);
        float z = sigm(gi01 + ghz);
        float nn = tanhf(gi02 + r*ghn);
        float hv = (1.f - z)*nn + z*h_lds[0][c];
        h_lds[0][c] = hv;
        gruout[(size_t)(gbase*128 + pos)*192 + dir*96 + c] = hv;
      }
      {
        float ghr = part[1][0][c]     + part[1][1][c]     + part[1][2][c]     + b0;
        float ghz = part[1][0][96+c]  + part[1][1][96+c]  + part[1][2][96+c]  + b1;
        float ghn = part[1][0][192+c] + part[1][1][192+c] + part[1][2][192+c] + b2;
        float r = sigm(gi10 + ghr);
        float z = sigm(gi11 + ghz);
        float nn = tanhf(gi12 + r*ghn);
        float hv = (1.f - z)*nn + z*h_lds[1][c];
        h_lds[1][c] = hv;
        gruout[(size_t)((gbase+1)*128 + pos)*192 + dir*96 + c] = hv;
      }
      if (t < 127) {
        const float* g0 = GI + (size_t)(gbase*128 + posn)*576 + dir*288;
        const float* g1 = GI + (size_t)((gbase+1)*128 + posn)*576 + dir*288;
        gi00 = g0[c]; gi01 = g0[96+c]; gi02 = g0[192+c];
        gi10 = g1[c]; gi11 = g1[96+c]; gi12 = g1[192+c];
      }
    }
    __syncthreads();
  }
}

// ---------------------------------------------------------------- k_prep2 : AT2 = relu(gruout)^T
__global__ __launch_bounds__(256) void k_prep2(const float* __restrict__ gruo,
                                               float* __restrict__ AT2) {
  __shared__ float t[NT*97];
  int g = blockIdx.x, half = blockIdx.y, tid = threadIdx.x;
  const float* rb = gruo + (size_t)g*NT*192 + half*96;
  for (int i = tid; i < NT*96; i += 256) {
    int row = i / 96, col = i - row*96;
    t[row*97 + col] = rb[(size_t)row*192 + col];
  }
  __syncthreads();
  for (int i = tid; i < 96*NT; i += 256) {
    int k = i >> 7, n = i & 127;
    AT2[(size_t)(half*96 + k)*NNODE + g*NT + n] = fmaxf(t[n*97 + k], 0.f);
  }
}

// ---------------------------------------------------------------- k_gemm2 : nh = relu(A2 @ Wo + b)
__global__ __launch_bounds__(384) void k_gemm2(
    const float* __restrict__ AT2, const float* __restrict__ WoW,
    const float* __restrict__ Wob, float* __restrict__ nh) {
  __shared__ __align__(16) float As[96*64];
  __shared__ __align__(16) float Bs[96*96];
  int m0 = blockIdx.x*64;
  int tid = threadIdx.x;
  int tc = tid % 24, tr = tid / 24;   // tr<16
  int r0 = tr*4, c0 = tc*4;
  float acc[4][4] = {};
  for (int kc = 0; kc < 2; ++kc) {
    for (int i = tid; i < 1536; i += 384) {
      int r = i >> 4, c4 = i & 15;
      *(float4*)&As[r*64 + c4*4] = *(const float4*)&AT2[(size_t)(kc*96 + r)*NNODE + m0 + c4*4];
    }
    for (int i = tid; i < 2304; i += 384) {
      int r = i / 24, c4 = i % 24;
      *(float4*)&Bs[r*96 + c4*4] = *(const float4*)&WoW[(size_t)(kc*96 + r)*96 + c4*4];
    }
    __syncthreads();
    #pragma unroll 8
    for (int k = 0; k < 96; ++k) {
      float4 a = *(float4*)&As[k*64 + r0];
      float4 b = *(float4*)&Bs[k*96 + c0];
      acc[0][0] += a.x*b.x; acc[0][1] += a.x*b.y; acc[0][2] += a.x*b.z; acc[0][3] += a.x*b.w;
      acc[1][0] += a.y*b.x; acc[1][1] += a.y*b.y; acc[1][2] += a.y*b.z; acc[1][3] += a.y*b.w;
      acc[2][0] += a.z*b.x; acc[2][1] += a.z*b.y; acc[2][2] += a.z*b.z; acc[2][3] += a.z*b.w;
      acc[3][0] += a.w*b.x; acc[3][1] += a.w*b.y; acc[3][2] += a.w*b.z; acc[3][3] += a.w*b.w;
    }
    __syncthreads();
  }
  float4 bia = *(const float4*)&Wob[c0];
  #pragma unroll
  for (int r = 0; r < 4; ++r) {
    float4 o = make_float4(fmaxf(acc[r][0]+bia.x, 0.f), fmaxf(acc[r][1]+bia.y, 0.f),
                           fmaxf(acc[r][2]+bia.z, 0.f), fmaxf(acc[r][3]+bia.w, 0.f));
    *(float4*)&nh[(size_t)(m0 + r0 + r)*96 + c0] = o;
  }
}

// ---------------------------------------------------------------- k_pool2
__global__ __launch_bounds__(128) void k_pool2(const float* __restrict__ nh,
                                               float* __restrict__ goutb,
                                               float* __restrict__ headb,
                                               float* __restrict__ tailb) {
  int g = blockIdx.x, j = threadIdx.x;
  if (j >= 96) return;
  const float* base = nh + (size_t)g*NT*96;
  float s = 0.f;
  for (int n = 0; n < NT; ++n) s += base[(size_t)n*96 + j];
  goutb[g*96 + j] = s * (1.f/128.f);
  headb[g*96 + j] = base[j];
  tailb[g*96 + j] = base[96 + j];
}

// ---------------------------------------------------------------- k_path : XI-precomputed 3-step GRU
__global__ __launch_bounds__(128) void k_path(
    const float* __restrict__ XI, const int* __restrict__ in_rels,
    const int* __restrict__ labels, const float* __restrict__ pWhh,
    const float* __restrict__ pbhh, float* __restrict__ last) {
  __shared__ __align__(16) float wsh[96*32];
  __shared__ float bsh[96];
  __shared__ float hbuf[128*33];
  int tid = threadIdx.x;
  for (int i = tid; i < 96*32; i += 128) wsh[i] = pWhh[i];
  if (tid < 96) bsh[tid] = pbhh[tid];
  int p = blockIdx.x*128 + tid;
  int b = p >> 6, pp = p & 63;
  int rid0 = in_rels[b*1024 + (pp >> 3)];
  int rid1 = labels[b];
  int rid2 = in_rels[b*1024 + 8 + (pp & 7)];
  __syncthreads();
  float* hs = &hbuf[tid*33];
  {
    const float* xi = XI + rid0*96;
    #pragma unroll
    for (int gg = 0; gg < 32; ++gg) {
      float r = sigm(xi[gg] + bsh[gg]);
      float z = sigm(xi[32+gg] + bsh[32+gg]);
      float nn = tanhf(xi[64+gg] + r*bsh[64+gg]);
      hs[gg] = (1.f - z)*nn;
    }
  }
  float4 h4[8];
  #pragma unroll
  for (int q = 0; q < 8; ++q) h4[q] = make_float4(hs[4*q], hs[4*q+1], hs[4*q+2], hs[4*q+3]);
  for (int s = 0; s < 2; ++s) {
    const float* xi = XI + (s == 0 ? rid1 : rid2)*96;
    for (int gg = 0; gg < 32; ++gg) {
      float ar = bsh[gg], az = bsh[32+gg], an = bsh[64+gg];
      const float4* wr = (const float4*)&wsh[gg*32];
      const float4* wz = (const float4*)&wsh[(32+gg)*32];
      const float4* wn = (const float4*)&wsh[(64+gg)*32];
      #pragma unroll
      for (int q = 0; q < 8; ++q) {
        float4 hv = h4[q]; float4 w;
        w = wr[q]; ar += hv.x*w.x + hv.y*w.y + hv.z*w.z + hv.w*w.w;
        w = wz[q]; az += hv.x*w.x + hv.y*w.y + hv.z*w.z + hv.w*w.w;
        w = wn[q]; an += hv.x*w.x + hv.y*w.y + hv.z*w.z + hv.w*w.w;
      }
      float r = sigm(xi[gg] + ar);
      float z = sigm(xi[32+gg] + az);
      float nn = tanhf(xi[64+gg] + r*an);
      hs[gg] = (1.f - z)*nn + z*hs[gg];
    }
    #pragma unroll
    for (int q = 0; q < 8; ++q) h4[q] = make_float4(hs[4*q], hs[4*q+1], hs[4*q+2], hs[4*q+3]);
  }
  float* lp = last + (size_t)p*32;
  #pragma unroll
  for (int d = 0; d < 32; ++d) lp[d] = hs[d];
}

// ---------------------------------------------------------------- k_final
__global__ __launch_bounds__(64) void k_final(
    const float* __restrict__ last, const float* __restrict__ r3,
    const int* __restrict__ labels, const float* __restrict__ goutb,
    const float* __restrict__ headb, const float* __restrict__ tailb,
    const float* __restrict__ fcW, const float* __restrict__ fcb,
    float* __restrict__ out) {
  __shared__ float red[64*33];
  __shared__ float gpl[32];
  int b = blockIdx.x, lane = threadIdx.x;
  const float* rl = r3 + labels[b]*32;
  float l32[32];
  {
    const float4* lr = (const float4*)(last + (size_t)(b*64 + lane)*32);
    #pragma unroll
    for (int q = 0; q < 8; ++q) {
      float4 v = lr[q];
      l32[4*q+0]=v.x; l32[4*q+1]=v.y; l32[4*q+2]=v.z; l32[4*q+3]=v.w;
    }
  }
  float s = 0.f;
  #pragma unroll
  for (int d = 0; d < 32; ++d) s += l32[d]*rl[d];
  float mx = s;
  #pragma unroll
  for (int off = 32; off > 0; off >>= 1) mx = fmaxf(mx, __shfl_xor(mx, off));
  float e = __expf(s - mx);
  float den = e;
  #pragma unroll
  for (int off = 32; off > 0; off >>= 1) den += __shfl_xor(den, off);
  float att = e / den;
  #pragma unroll
  for (int d = 0; d < 32; ++d) red[lane*33 + d] = att*l32[d];
  __syncthreads();
  if (lane < 32) {
    float gp = 0.f;
    for (int p2 = 0; p2 < 64; ++p2) gp += red[p2*33 + lane];
    gpl[lane] = gp;
  }
  __syncthreads();
  float acc = 0.f;
  for (int i = lane; i < 352; i += 64) {
    float v;
    if (i < 96)       v = goutb[b*96 + i];
    else if (i < 192) v = headb[b*96 + (i-96)];
    else if (i < 288) v = tailb[b*96 + (i-192)];
    else if (i < 320) v = rl[i-288];
    else              v = gpl[i-320];
    acc += v*fcW[i];
  }
  #pragma unroll
  for (int off = 32; off > 0; off >>= 1) acc += __shfl_xor(acc, off);
  if (lane == 0) out[b] = acc + fcb[0];
}

// ---------------------------------------------------------------- launch
extern "C" void kernel_launch(void* const* d_in, const int* in_sizes, int n_in,
                              void* d_out, int out_size, void* d_ws, size_t ws_size,
                              hipStream_t stream) {
  const float* feat       = (const float*)d_in[0];
  const int*   out_rels   = (const int*)d_in[1];
  const int*   in_rels    = (const int*)d_in[2];
  const int*   r_label_nd = (const int*)d_in[3];
  const int*   src        = (const int*)d_in[4];
  const int*   dst        = (const int*)d_in[5];
  const int*   etype      = (const int*)d_in[6];
  const int*   rel_labels = (const int*)d_in[7];
  const float* rel_emb    = (const float*)d_in[8];
  const float* w2e_W      = (const float*)d_in[9];
  const float* w2e_b      = (const float*)d_in[10];
  const float* W_msg      = (const float*)d_in[11];
  const float* W_self     = (const float*)d_in[12];
  const float* b_gnn      = (const float*)d_in[13];
  const float* W_rel      = (const float*)d_in[14];
  const float* gru_bias   = (const float*)d_in[15];
  const float* Wih_f      = (const float*)d_in[16];
  const float* Whh_f      = (const float*)d_in[17];
  const float* bih_f      = (const float*)d_in[18];
  const float* bhh_f      = (const float*)d_in[19];
  const float* Wih_b      = (const float*)d_in[20];
  const float* Whh_b      = (const float*)d_in[21];
  const float* bih_b      = (const float*)d_in[22];
  const float* bhh_b      = (const float*)d_in[23];
  const float* Wo_W       = (const float*)d_in[24];
  const float* Wo_b       = (const float*)d_in[25];
  const float* pWih       = (const float*)d_in[26];
  const float* pWhh       = (const float*)d_in[27];
  const float* pbih       = (const float*)d_in[28];
  const float* pbhh       = (const float*)d_in[29];
  const float* fcW        = (const float*)d_in[30];
  const float* fcb        = (const float*)d_in[31];
  float* out = (float*)d_out;

  float* p = (float*)d_ws;
  float* hin   = p; p += (size_t)NNODE*32;
  float* R1    = p; p += (size_t)NNODE*192;
  float* repr  = R1;
  float* AT    = R1 + (size_t)NNODE*96;
  float* gruo  = R1;
  float* R2    = p; p += (size_t)NNODE*576;
  float* GI    = R2;
  float* AT2   = R2;
  float* nh    = R2 + (size_t)192*NNODE;
  int*   deg   = (int*)p; p += NNODE;
  float* r123  = p; p += 3*NREL*32;
  float* WT1   = p; p += 96*576;
  float* bcat  = p; p += 576;
  float* XI    = p; p += NREL*96;
  float* ghid0 = p; p += BB*96;
  float* goutb = p; p += BB*96;
  float* headb = p; p += BB*96;
  float* tailb = p; p += BB*96;
  float* lastb = p; p += (size_t)BB*64*32;

  hipMemsetAsync(deg, 0, NNODE*sizeof(int), stream);
  k_rel<<<1, 256, 0, stream>>>(rel_emb, W_rel, Wih_f, Wih_b, bih_f, bih_b,
                               pWih, pbih, r123, WT1, bcat, XI);
  k_deg<<<NEDGE/256, 256, 0, stream>>>(dst, deg);
  k_sem<<<NNODE/256, 256, 0, stream>>>(feat, out_rels, in_rels, r_label_nd,
                                       rel_emb, w2e_W, w2e_b, hin);
  for (int l = 0; l < 3; ++l) {
    const float* hsrc = (l == 0) ? hin : (repr + (l-1)*32);
    int hstride = (l == 0) ? 32 : 96;
    const float* r_l = (l == 0) ? rel_emb : (r123 + (l-1)*NREL*32);
    k_gnn<<<BB, 512, 0, stream>>>(hsrc, hstride, r_l, src, dst, etype, deg,
                                  W_msg + l*1024, W_self + l*1024, b_gnn + l*32,
                                  repr, l*32);
  }
  k_prep1<<<BB, 256, 0, stream>>>(repr, gru_bias, AT, ghid0);
  k_gemm1<<<dim3(9, 512), 256, 0, stream>>>(AT, WT1, bcat, GI);
  k_gru<<<512, 288, 0, stream>>>(Whh_f, bhh_f, Whh_b, bhh_b, GI, ghid0, gruo);
  k_prep2<<<dim3(BB, 2), 256, 0, stream>>>(gruo, AT2);
  k_gemm2<<<1024, 384, 0, stream>>>(AT2, Wo_W, Wo_b, nh);
  k_pool2<<<BB, 128, 0, stream>>>(nh, goutb, headb, tailb);
  k_path<<<256, 128, 0, stream>>>(XI, in_rels, rel_labels, pWhh, pbhh, lastb);
  k_final<<<BB, 64, 0, stream>>>(lastb, r123 + 2*NREL*32, rel_labels,
                                 goutb, headb, tailb, fcW, fcb, out);
}

// Round 4
// 1274.603 us; speedup vs baseline: 2.0927x; 1.0840x over previous
//
#include <hip/hip_runtime.h>
#include <math.h>

#define BB 512
#define NT 128
#define NREL 201
#define NNODE (BB*NT)
#define NEDGE (NNODE*16)

__device__ __forceinline__ float sigm(float x) { return 1.f/(1.f + __expf(-x)); }

// ---------------------------------------------------------------- k_rel
// rel chain r123; WT1[96][576] = [Wih_f;Wih_b]^T; bcat[576]; XI[201][96] = r3 @ pWih^T + pbih
__global__ void k_rel(const float* __restrict__ rel_emb, const float* __restrict__ W_rel,
                      const float* __restrict__ Wih_f, const float* __restrict__ Wih_b,
                      const float* __restrict__ bih_f, const float* __restrict__ bih_b,
                      const float* __restrict__ pWih, const float* __restrict__ pbih,
                      float* __restrict__ r123, float* __restrict__ WT1,
                      float* __restrict__ bcat, float* __restrict__ XI) {
  __shared__ float rcur[NREL*32];
  __shared__ float rnext[NREL*32];
  int tid = threadIdx.x;
  for (int i = tid; i < NREL*32; i += 256) rcur[i] = rel_emb[i];
  __syncthreads();
  for (int l = 0; l < 3; ++l) {
    const float* w = W_rel + l*1024;
    for (int i = tid; i < NREL*32; i += 256) {
      int row = i >> 5, col = i & 31;
      float s = 0.f;
      #pragma unroll
      for (int d = 0; d < 32; ++d) s += rcur[row*32 + d] * w[d*32 + col];
      rnext[i] = s;
    }
    __syncthreads();
    for (int i = tid; i < NREL*32; i += 256) { float v = rnext[i]; rcur[i] = v; r123[l*NREL*32 + i] = v; }
    __syncthreads();
  }
  for (int i = tid; i < 96*576; i += 256) {
    int k = i / 576, j = i - k*576;
    WT1[i] = (j < 288) ? Wih_f[j*96 + k] : Wih_b[(j-288)*96 + k];
  }
  for (int i = tid; i < 576; i += 256) bcat[i] = (i < 288) ? bih_f[i] : bih_b[i-288];
  for (int i = tid; i < NREL*96; i += 256) {
    int r = i / 96, j = i - r*96;
    float s = pbih[j];
    #pragma unroll
    for (int d = 0; d < 32; ++d) s += rcur[r*32 + d]*pWih[j*32 + d];
    XI[i] = s;
  }
}

// ---------------------------------------------------------------- k_deg
__global__ void k_deg(const int* __restrict__ dst, int* __restrict__ deg) {
  int e = blockIdx.x*256 + threadIdx.x;
  if (e < NEDGE) atomicAdd(&deg[dst[e]], 1);
}

// ---------------------------------------------------------------- k_sem
__device__ __forceinline__ void sem_att(const float* __restrict__ rel_emb,
                                        const int rels[8], const float tgt[32],
                                        float out[32]) {
  float dots[8]; float mx = -1e30f;
  #pragma unroll
  for (int k = 0; k < 8; ++k) {
    const float4* er = (const float4*)(rel_emb + rels[k]*32);
    float s = 0.f;
    #pragma unroll
    for (int q = 0; q < 8; ++q) {
      float4 v = er[q];
      s += v.x*tgt[4*q+0] + v.y*tgt[4*q+1] + v.z*tgt[4*q+2] + v.w*tgt[4*q+3];
    }
    dots[k] = s; mx = fmaxf(mx, s);
  }
  float den = 0.f;
  #pragma unroll
  for (int k = 0; k < 8; ++k) { float e = __expf(dots[k]-mx); dots[k] = e; den += e; }
  float inv = 1.f/den;
  #pragma unroll
  for (int d = 0; d < 32; ++d) out[d] = 0.f;
  #pragma unroll
  for (int k = 0; k < 8; ++k) {
    const float4* er = (const float4*)(rel_emb + rels[k]*32);
    float a = dots[k]*inv;
    #pragma unroll
    for (int q = 0; q < 8; ++q) {
      float4 v = er[q];
      out[4*q+0] += a*v.x; out[4*q+1] += a*v.y; out[4*q+2] += a*v.z; out[4*q+3] += a*v.w;
    }
  }
}

__global__ __launch_bounds__(256) void k_sem(
    const float* __restrict__ feat, const int* __restrict__ out_rels,
    const int* __restrict__ in_rels, const int* __restrict__ r_label_node,
    const float* __restrict__ rel_emb, const float* __restrict__ W,
    const float* __restrict__ bias, float* __restrict__ hin) {
  int n = blockIdx.x*256 + threadIdx.x;
  float tgt[32];
  {
    const float4* tr = (const float4*)(rel_emb + r_label_node[n]*32);
    #pragma unroll
    for (int q = 0; q < 8; ++q) {
      float4 v = tr[q];
      tgt[4*q+0]=v.x; tgt[4*q+1]=v.y; tgt[4*q+2]=v.z; tgt[4*q+3]=v.w;
    }
  }
  int ro[8], ri[8];
  #pragma unroll
  for (int k = 0; k < 8; ++k) { ro[k] = out_rels[n*8+k]; ri[k] = in_rels[n*8+k]; }
  float osem[32], isem[32];
  sem_att(rel_emb, ro, tgt, osem);
  sem_att(rel_emb, ri, tgt, isem);
  const float4* fr = (const float4*)(feat + (size_t)n*16);
  float4* ho = (float4*)(hin + (size_t)n*32);
  #pragma unroll
  for (int q = 0; q < 4; ++q) ho[q] = fr[q];
  #pragma unroll
  for (int j = 0; j < 16; ++j) {
    float s = bias[j];
    #pragma unroll
    for (int d = 0; d < 32; ++d) s += osem[d]*W[d*16+j] + isem[d]*W[(32+d)*16+j];
    hin[(size_t)n*32 + 16 + j] = sigm(s);
  }
}

// ---------------------------------------------------------------- k_gnn
__global__ __launch_bounds__(512) void k_gnn(
    const float* __restrict__ hsrc, int hstride, const float* __restrict__ r_l,
    const int* __restrict__ src, const int* __restrict__ dst, const int* __restrict__ etype,
    const int* __restrict__ deg, const float* __restrict__ Wm, const float* __restrict__ Ws,
    const float* __restrict__ bl, float* __restrict__ repr_out, int ofs) {
  __shared__ __align__(16) float hl[NT*32];
  __shared__ __align__(16) float agg[NT*32];
  __shared__ float rl[NREL*32];
  int g = blockIdx.x;
  int tid = threadIdx.x;
  for (int i = tid; i < NT*32; i += 512) {
    int row = i >> 5, col = i & 31;
    hl[i] = hsrc[(size_t)(g*NT + row)*hstride + col];
    agg[i] = 0.f;
  }
  for (int i = tid; i < NREL*32; i += 512) rl[i] = r_l[i];
  __syncthreads();
  {
    int d = tid & 31, grp = tid >> 5;   // 16 groups of 32 lanes
    int ebase = g*2048;
    for (int i = grp; i < 2048; i += 16) {
      int e = ebase + i;
      int sl = src[e] - g*NT;
      int dl = dst[e] - g*NT;
      float m = hl[sl*32 + d] * rl[etype[e]*32 + d];
      atomicAdd(&agg[dl*32 + d], m);
    }
  }
  __syncthreads();
  int j = tid & 31;
  float wm[32], ws[32];
  #pragma unroll
  for (int dd = 0; dd < 32; ++dd) { wm[dd] = Wm[dd*32+j]; ws[dd] = Ws[dd*32+j]; }
  float bj = bl[j];
  int nbase = tid >> 5;
  for (int k2 = 0; k2 < 8; ++k2) {
    int n = nbase + k2*16;
    int dv = deg[g*NT + n];
    float invd = 1.f / (float)(dv > 0 ? dv : 1);
    const float4* a4 = (const float4*)&agg[n*32];
    const float4* h4 = (const float4*)&hl[n*32];
    float sa = 0.f, sh = 0.f;
    #pragma unroll
    for (int q = 0; q < 8; ++q) {
      float4 av = a4[q], hv = h4[q];
      sa += av.x*wm[4*q+0] + av.y*wm[4*q+1] + av.z*wm[4*q+2] + av.w*wm[4*q+3];
      sh += hv.x*ws[4*q+0] + hv.y*ws[4*q+1] + hv.z*ws[4*q+2] + hv.w*ws[4*q+3];
    }
    float res = bj + invd*sa + sh;
    repr_out[(size_t)(g*NT + n)*96 + ofs + j] = fmaxf(res, 0.f);
  }
}

// ---------------------------------------------------------------- k_prep1 : AT = relu(repr+gbias)^T ; ghid0 = colmax(repr)
__global__ __launch_bounds__(256) void k_prep1(
    const float* __restrict__ repr, const float* __restrict__ gbias,
    float* __restrict__ AT, float* __restrict__ ghid0) {
  __shared__ float t[NT*97];
  int g = blockIdx.x, tid = threadIdx.x;
  const float* rb = repr + (size_t)g*NT*96;
  for (int i = tid; i < NT*96; i += 256) {
    int row = i / 96, col = i - row*96;
    t[row*97 + col] = rb[i];
  }
  __syncthreads();
  for (int i = tid; i < 96*NT; i += 256) {
    int k = i >> 7, n = i & 127;
    AT[(size_t)k*NNODE + g*NT + n] = fmaxf(t[n*97 + k] + gbias[k], 0.f);
  }
  if (tid < 96) {
    float m = -1e30f;
    for (int n = 0; n < NT; ++n) m = fmaxf(m, t[n*97 + tid]);
    ghid0[g*96 + tid] = m;
  }
}

// ---------------------------------------------------------------- k_gemm1 : GI[65536][576] = A(T) @ WT1 + bcat  (BM=128,BN=64,K=96)
__global__ __launch_bounds__(256) void k_gemm1(
    const float* __restrict__ AT, const float* __restrict__ WT1,
    const float* __restrict__ bcat, float* __restrict__ GI) {
  __shared__ __align__(16) float As[96*128];
  __shared__ __align__(16) float Bs[96*64];
  int nb = blockIdx.x;   // 0..8
  int mb = blockIdx.y;   // 0..511
  int m0 = mb*128, n0 = nb*64;
  int tid = threadIdx.x;
  for (int i = tid; i < 3072; i += 256) {
    int r = i >> 5, c4 = i & 31;
    *(float4*)&As[r*128 + c4*4] = *(const float4*)&AT[(size_t)r*NNODE + m0 + c4*4];
  }
  for (int i = tid; i < 1536; i += 256) {
    int r = i >> 4, c4 = i & 15;
    *(float4*)&Bs[r*64 + c4*4] = *(const float4*)&WT1[r*576 + n0 + c4*4];
  }
  __syncthreads();
  int tc = tid & 15, tr = tid >> 4;
  int r0 = tr*8, c0 = tc*4;
  float acc[8][4] = {};
  #pragma unroll 4
  for (int k = 0; k < 96; ++k) {
    float4 a0 = *(float4*)&As[k*128 + r0];
    float4 a1 = *(float4*)&As[k*128 + r0 + 4];
    float4 b  = *(float4*)&Bs[k*64 + c0];
    acc[0][0]+=a0.x*b.x; acc[0][1]+=a0.x*b.y; acc[0][2]+=a0.x*b.z; acc[0][3]+=a0.x*b.w;
    acc[1][0]+=a0.y*b.x; acc[1][1]+=a0.y*b.y; acc[1][2]+=a0.y*b.z; acc[1][3]+=a0.y*b.w;
    acc[2][0]+=a0.z*b.x; acc[2][1]+=a0.z*b.y; acc[2][2]+=a0.z*b.z; acc[2][3]+=a0.z*b.w;
    acc[3][0]+=a0.w*b.x; acc[3][1]+=a0.w*b.y; acc[3][2]+=a0.w*b.z; acc[3][3]+=a0.w*b.w;
    acc[4][0]+=a1.x*b.x; acc[4][1]+=a1.x*b.y; acc[4][2]+=a1.x*b.z; acc[4][3]+=a1.x*b.w;
    acc[5][0]+=a1.y*b.x; acc[5][1]+=a1.y*b.y; acc[5][2]+=a1.y*b.z; acc[5][3]+=a1.y*b.w;
    acc[6][0]+=a1.z*b.x; acc[6][1]+=a1.z*b.y; acc[6][2]+=a1.z*b.z; acc[6][3]+=a1.z*b.w;
    acc[7][0]+=a1.w*b.x; acc[7][1]+=a1.w*b.y; acc[7][2]+=a1.w*b.z; acc[7][3]+=a1.w*b.w;
  }
  float4 bia = *(const float4*)&bcat[n0 + c0];
  #pragma unroll
  for (int r = 0; r < 8; ++r) {
    float4 o = make_float4(acc[r][0]+bia.x, acc[r][1]+bia.y, acc[r][2]+bia.z, acc[r][3]+bia.w);
    *(float4*)&GI[(size_t)(m0 + r0 + r)*576 + n0 + c0] = o;
  }
}

// ---------------------------------------------------------------- k_gru : K-split-6, 2 same-dir seqs/block, pinned weights
#define PIN4(v) asm volatile("" : "+v"(v.x), "+v"(v.y), "+v"(v.z), "+v"(v.w))
#define DOT16(acc, W0,W1,W2,W3, X0,X1,X2,X3) \
  acc += W0.x*X0.x + W0.y*X0.y + W0.z*X0.z + W0.w*X0.w \
       + W1.x*X1.x + W1.y*X1.y + W1.z*X1.z + W1.w*X1.w \
       + W2.x*X2.x + W2.y*X2.y + W2.z*X2.z + W2.w*X2.w \
       + W3.x*X3.x + W3.y*X3.y + W3.z*X3.z + W3.w*X3.w

__global__ __launch_bounds__(576, 2) void k_gru(
    const float* __restrict__ Whh_f, const float* __restrict__ bhh_f,
    const float* __restrict__ Whh_b, const float* __restrict__ bhh_b,
    const float* __restrict__ GI, const float* __restrict__ ghid0,
    float* __restrict__ gruout) {
  __shared__ __align__(16) float h_lds[2][96];
  __shared__ float part[2][288][9];     // pad 9: bank-stride 9, conflict-free
  int bx = blockIdx.x;                  // 512 blocks
  int dir = bx >> 8;
  int gbase = (bx & 255) * 2;
  int tid = threadIdx.x;                // 0..575
  int c = tid % 96;                     // output channel within gate
  int p = tid / 96;                     // K chunk 0..5 (16 wide)
  bool fin = (tid < 192);
  int s = p;                            // for fin threads: p in {0,1} == seq

  const float* Whh = dir ? Whh_b : Whh_f;
  // rows c, 96+c, 192+c; K slice [16p, 16p+16)
  const float4* wr0 = (const float4*)(Whh + (size_t)c*96 + p*16);
  const float4* wr1 = (const float4*)(Whh + (size_t)(96+c)*96 + p*16);
  const float4* wr2 = (const float4*)(Whh + (size_t)(192+c)*96 + p*16);
  float4 wa0=wr0[0], wa1=wr0[1], wa2=wr0[2], wa3=wr0[3];
  float4 wb0=wr1[0], wb1=wr1[1], wb2=wr1[2], wb3=wr1[3];
  float4 wc0=wr2[0], wc1=wr2[1], wc2=wr2[2], wc3=wr2[3];
  PIN4(wa0); PIN4(wa1); PIN4(wa2); PIN4(wa3);
  PIN4(wb0); PIN4(wb1); PIN4(wb2); PIN4(wb3);
  PIN4(wc0); PIN4(wc1); PIN4(wc2); PIN4(wc3);

  float bh0=0.f, bh1=0.f, bh2=0.f;
  float gi0=0.f, gi1=0.f, gi2=0.f;
  if (fin) {
    const float* bhh = dir ? bhh_b : bhh_f;
    bh0 = bhh[c]; bh1 = bhh[96+c]; bh2 = bhh[192+c];
    h_lds[s][c] = ghid0[(gbase+s)*96 + c];
    int pos0 = dir ? 127 : 0;
    const float* g = GI + (size_t)((gbase+s)*128 + pos0)*576 + dir*288;
    gi0 = g[c]; gi1 = g[96+c]; gi2 = g[192+c];
  }
  __syncthreads();
  for (int t = 0; t < 128; ++t) {
    int pos = dir ? (127-t) : t;
    float gn0=0.f, gn1=0.f, gn2=0.f;
    if (fin && t < 127) {               // prefetch next step's GI (1 step ahead)
      int posn = dir ? (126-t) : (t+1);
      const float* g = GI + (size_t)((gbase+s)*128 + posn)*576 + dir*288;
      gn0 = g[c]; gn1 = g[96+c]; gn2 = g[192+c];
    }
    // matvec partials: 2 seqs x 3 gate rows x 16 K
    float p00=0.f,p01=0.f,p02=0.f, p10=0.f,p11=0.f,p12=0.f;
    {
      const float4* h0 = (const float4*)&h_lds[0][p*16];
      float4 x0=h0[0], x1=h0[1], x2=h0[2], x3=h0[3];
      DOT16(p00, wa0,wa1,wa2,wa3, x0,x1,x2,x3);
      DOT16(p01, wb0,wb1,wb2,wb3, x0,x1,x2,x3);
      DOT16(p02, wc0,wc1,wc2,wc3, x0,x1,x2,x3);
      const float4* h1 = (const float4*)&h_lds[1][p*16];
      float4 y0=h1[0], y1=h1[1], y2=h1[2], y3=h1[3];
      DOT16(p10, wa0,wa1,wa2,wa3, y0,y1,y2,y3);
      DOT16(p11, wb0,wb1,wb2,wb3, y0,y1,y2,y3);
      DOT16(p12, wc0,wc1,wc2,wc3, y0,y1,y2,y3);
    }
    part[0][c][p]     = p00; part[0][96+c][p]  = p01; part[0][192+c][p] = p02;
    part[1][c][p]     = p10; part[1][96+c][p]  = p11; part[1][192+c][p] = p12;
    __syncthreads();
    if (fin) {
      const float* pr = part[s][c];
      const float* pz = part[s][96+c];
      const float* pn = part[s][192+c];
      float ghr = pr[0]+pr[1]+pr[2]+pr[3]+pr[4]+pr[5] + bh0;
      float ghz = pz[0]+pz[1]+pz[2]+pz[3]+pz[4]+pz[5] + bh1;
      float ghn = pn[0]+pn[1]+pn[2]+pn[3]+pn[4]+pn[5] + bh2;
      float r  = sigm(gi0 + ghr);
      float z  = sigm(gi1 + ghz);
      float nn = tanhf(gi2 + r*ghn);
      float hv = (1.f - z)*nn + z*h_lds[s][c];
      h_lds[s][c] = hv;
      gruout[(size_t)((gbase+s)*128 + pos)*192 + dir*96 + c] = hv;
      gi0 = gn0; gi1 = gn1; gi2 = gn2;
    }
    __syncthreads();
  }
}

// ---------------------------------------------------------------- k_prep2 : AT2 = relu(gruout)^T
__global__ __launch_bounds__(256) void k_prep2(const float* __restrict__ gruo,
                                               float* __restrict__ AT2) {
  __shared__ float t[NT*97];
  int g = blockIdx.x, half = blockIdx.y, tid = threadIdx.x;
  const float* rb = gruo + (size_t)g*NT*192 + half*96;
  for (int i = tid; i < NT*96; i += 256) {
    int row = i / 96, col = i - row*96;
    t[row*97 + col] = rb[(size_t)row*192 + col];
  }
  __syncthreads();
  for (int i = tid; i < 96*NT; i += 256) {
    int k = i >> 7, n = i & 127;
    AT2[(size_t)(half*96 + k)*NNODE + g*NT + n] = fmaxf(t[n*97 + k], 0.f);
  }
}

// ---------------------------------------------------------------- k_gemm2 : nh = relu(A2 @ Wo + b)
__global__ __launch_bounds__(384) void k_gemm2(
    const float* __restrict__ AT2, const float* __restrict__ WoW,
    const float* __restrict__ Wob, float* __restrict__ nh) {
  __shared__ __align__(16) float As[96*64];
  __shared__ __align__(16) float Bs[96*96];
  int m0 = blockIdx.x*64;
  int tid = threadIdx.x;
  int tc = tid % 24, tr = tid / 24;   // tr<16
  int r0 = tr*4, c0 = tc*4;
  float acc[4][4] = {};
  for (int kc = 0; kc < 2; ++kc) {
    for (int i = tid; i < 1536; i += 384) {
      int r = i >> 4, c4 = i & 15;
      *(float4*)&As[r*64 + c4*4] = *(const float4*)&AT2[(size_t)(kc*96 + r)*NNODE + m0 + c4*4];
    }
    for (int i = tid; i < 2304; i += 384) {
      int r = i / 24, c4 = i % 24;
      *(float4*)&Bs[r*96 + c4*4] = *(const float4*)&WoW[(size_t)(kc*96 + r)*96 + c4*4];
    }
    __syncthreads();
    #pragma unroll 8
    for (int k = 0; k < 96; ++k) {
      float4 a = *(float4*)&As[k*64 + r0];
      float4 b = *(float4*)&Bs[k*96 + c0];
      acc[0][0] += a.x*b.x; acc[0][1] += a.x*b.y; acc[0][2] += a.x*b.z; acc[0][3] += a.x*b.w;
      acc[1][0] += a.y*b.x; acc[1][1] += a.y*b.y; acc[1][2] += a.y*b.z; acc[1][3] += a.y*b.w;
      acc[2][0] += a.z*b.x; acc[2][1] += a.z*b.y; acc[2][2] += a.z*b.z; acc[2][3] += a.z*b.w;
      acc[3][0] += a.w*b.x; acc[3][1] += a.w*b.y; acc[3][2] += a.w*b.z; acc[3][3] += a.w*b.w;
    }
    __syncthreads();
  }
  float4 bia = *(const float4*)&Wob[c0];
  #pragma unroll
  for (int r = 0; r < 4; ++r) {
    float4 o = make_float4(fmaxf(acc[r][0]+bia.x, 0.f), fmaxf(acc[r][1]+bia.y, 0.f),
                           fmaxf(acc[r][2]+bia.z, 0.f), fmaxf(acc[r][3]+bia.w, 0.f));
    *(float4*)&nh[(size_t)(m0 + r0 + r)*96 + c0] = o;
  }
}

// ---------------------------------------------------------------- k_pool2
__global__ __launch_bounds__(128) void k_pool2(const float* __restrict__ nh,
                                               float* __restrict__ goutb,
                                               float* __restrict__ headb,
                                               float* __restrict__ tailb) {
  int g = blockIdx.x, j = threadIdx.x;
  if (j >= 96) return;
  const float* base = nh + (size_t)g*NT*96;
  float s = 0.f;
  for (int n = 0; n < NT; ++n) s += base[(size_t)n*96 + j];
  goutb[g*96 + j] = s * (1.f/128.f);
  headb[g*96 + j] = base[j];
  tailb[g*96 + j] = base[96 + j];
}

// ---------------------------------------------------------------- k_path : XI-precomputed 3-step GRU
__global__ __launch_bounds__(128) void k_path(
    const float* __restrict__ XI, const int* __restrict__ in_rels,
    const int* __restrict__ labels, const float* __restrict__ pWhh,
    const float* __restrict__ pbhh, float* __restrict__ last) {
  __shared__ __align__(16) float wsh[96*32];
  __shared__ float bsh[96];
  __shared__ float hbuf[128*33];
  int tid = threadIdx.x;
  for (int i = tid; i < 96*32; i += 128) wsh[i] = pWhh[i];
  if (tid < 96) bsh[tid] = pbhh[tid];
  int p = blockIdx.x*128 + tid;
  int b = p >> 6, pp = p & 63;
  int rid0 = in_rels[b*1024 + (pp >> 3)];
  int rid1 = labels[b];
  int rid2 = in_rels[b*1024 + 8 + (pp & 7)];
  __syncthreads();
  float* hs = &hbuf[tid*33];
  {
    const float* xi = XI + rid0*96;
    #pragma unroll
    for (int gg = 0; gg < 32; ++gg) {
      float r = sigm(xi[gg] + bsh[gg]);
      float z = sigm(xi[32+gg] + bsh[32+gg]);
      float nn = tanhf(xi[64+gg] + r*bsh[64+gg]);
      hs[gg] = (1.f - z)*nn;
    }
  }
  float4 h4[8];
  #pragma unroll
  for (int q = 0; q < 8; ++q) h4[q] = make_float4(hs[4*q], hs[4*q+1], hs[4*q+2], hs[4*q+3]);
  for (int s = 0; s < 2; ++s) {
    const float* xi = XI + (s == 0 ? rid1 : rid2)*96;
    for (int gg = 0; gg < 32; ++gg) {
      float ar = bsh[gg], az = bsh[32+gg], an = bsh[64+gg];
      const float4* wr = (const float4*)&wsh[gg*32];
      const float4* wz = (const float4*)&wsh[(32+gg)*32];
      const float4* wn = (const float4*)&wsh[(64+gg)*32];
      #pragma unroll
      for (int q = 0; q < 8; ++q) {
        float4 hv = h4[q]; float4 w;
        w = wr[q]; ar += hv.x*w.x + hv.y*w.y + hv.z*w.z + hv.w*w.w;
        w = wz[q]; az += hv.x*w.x + hv.y*w.y + hv.z*w.z + hv.w*w.w;
        w = wn[q]; an += hv.x*w.x + hv.y*w.y + hv.z*w.z + hv.w*w.w;
      }
      float r = sigm(xi[gg] + ar);
      float z = sigm(xi[32+gg] + az);
      float nn = tanhf(xi[64+gg] + r*an);
      hs[gg] = (1.f - z)*nn + z*hs[gg];
    }
    #pragma unroll
    for (int q = 0; q < 8; ++q) h4[q] = make_float4(hs[4*q], hs[4*q+1], hs[4*q+2], hs[4*q+3]);
  }
  float* lp = last + (size_t)p*32;
  #pragma unroll
  for (int d = 0; d < 32; ++d) lp[d] = hs[d];
}

// ---------------------------------------------------------------- k_final
__global__ __launch_bounds__(64) void k_final(
    const float* __restrict__ last, const float* __restrict__ r3,
    const int* __restrict__ labels, const float* __restrict__ goutb,
    const float* __restrict__ headb, const float* __restrict__ tailb,
    const float* __restrict__ fcW, const float* __restrict__ fcb,
    float* __restrict__ out) {
  __shared__ float red[64*33];
  __shared__ float gpl[32];
  int b = blockIdx.x, lane = threadIdx.x;
  const float* rl = r3 + labels[b]*32;
  float l32[32];
  {
    const float4* lr = (const float4*)(last + (size_t)(b*64 + lane)*32);
    #pragma unroll
    for (int q = 0; q < 8; ++q) {
      float4 v = lr[q];
      l32[4*q+0]=v.x; l32[4*q+1]=v.y; l32[4*q+2]=v.z; l32[4*q+3]=v.w;
    }
  }
  float s = 0.f;
  #pragma unroll
  for (int d = 0; d < 32; ++d) s += l32[d]*rl[d];
  float mx = s;
  #pragma unroll
  for (int off = 32; off > 0; off >>= 1) mx = fmaxf(mx, __shfl_xor(mx, off));
  float e = __expf(s - mx);
  float den = e;
  #pragma unroll
  for (int off = 32; off > 0; off >>= 1) den += __shfl_xor(den, off);
  float att = e / den;
  #pragma unroll
  for (int d = 0; d < 32; ++d) red[lane*33 + d] = att*l32[d];
  __syncthreads();
  if (lane < 32) {
    float gp = 0.f;
    for (int p2 = 0; p2 < 64; ++p2) gp += red[p2*33 + lane];
    gpl[lane] = gp;
  }
  __syncthreads();
  float acc = 0.f;
  for (int i = lane; i < 352; i += 64) {
    float v;
    if (i < 96)       v = goutb[b*96 + i];
    else if (i < 192) v = headb[b*96 + (i-96)];
    else if (i < 288) v = tailb[b*96 + (i-192)];
    else if (i < 320) v = rl[i-288];
    else              v = gpl[i-320];
    acc += v*fcW[i];
  }
  #pragma unroll
  for (int off = 32; off > 0; off >>= 1) acc += __shfl_xor(acc, off);
  if (lane == 0) out[b] = acc + fcb[0];
}

// ---------------------------------------------------------------- launch
extern "C" void kernel_launch(void* const* d_in, const int* in_sizes, int n_in,
                              void* d_out, int out_size, void* d_ws, size_t ws_size,
                              hipStream_t stream) {
  const float* feat       = (const float*)d_in[0];
  const int*   out_rels   = (const int*)d_in[1];
  const int*   in_rels    = (const int*)d_in[2];
  const int*   r_label_nd = (const int*)d_in[3];
  const int*   src        = (const int*)d_in[4];
  const int*   dst        = (const int*)d_in[5];
  const int*   etype      = (const int*)d_in[6];
  const int*   rel_labels = (const int*)d_in[7];
  const float* rel_emb    = (const float*)d_in[8];
  const float* w2e_W      = (const float*)d_in[9];
  const float* w2e_b      = (const float*)d_in[10];
  const float* W_msg      = (const float*)d_in[11];
  const float* W_self     = (const float*)d_in[12];
  const float* b_gnn      = (const float*)d_in[13];
  const float* W_rel      = (const float*)d_in[14];
  const float* gru_bias   = (const float*)d_in[15];
  const float* Wih_f      = (const float*)d_in[16];
  const float* Whh_f      = (const float*)d_in[17];
  const float* bih_f      = (const float*)d_in[18];
  const float* bhh_f      = (const float*)d_in[19];
  const float* Wih_b      = (const float*)d_in[20];
  const float* Whh_b      = (const float*)d_in[21];
  const float* bih_b      = (const float*)d_in[22];
  const float* bhh_b      = (const float*)d_in[23];
  const float* Wo_W       = (const float*)d_in[24];
  const float* Wo_b       = (const float*)d_in[25];
  const float* pWih       = (const float*)d_in[26];
  const float* pWhh       = (const float*)d_in[27];
  const float* pbih       = (const float*)d_in[28];
  const float* pbhh       = (const float*)d_in[29];
  const float* fcW        = (const float*)d_in[30];
  const float* fcb        = (const float*)d_in[31];
  float* out = (float*)d_out;

  float* p = (float*)d_ws;
  float* hin   = p; p += (size_t)NNODE*32;
  float* R1    = p; p += (size_t)NNODE*192;
  float* repr  = R1;
  float* AT    = R1 + (size_t)NNODE*96;
  float* gruo  = R1;
  float* R2    = p; p += (size_t)NNODE*576;
  float* GI    = R2;
  float* AT2   = R2;
  float* nh    = R2 + (size_t)192*NNODE;
  int*   deg   = (int*)p; p += NNODE;
  float* r123  = p; p += 3*NREL*32;
  float* WT1   = p; p += 96*576;
  float* bcat  = p; p += 576;
  float* XI    = p; p += NREL*96;
  float* ghid0 = p; p += BB*96;
  float* goutb = p; p += BB*96;
  float* headb = p; p += BB*96;
  float* tailb = p; p += BB*96;
  float* lastb = p; p += (size_t)BB*64*32;

  hipMemsetAsync(deg, 0, NNODE*sizeof(int), stream);
  k_rel<<<1, 256, 0, stream>>>(rel_emb, W_rel, Wih_f, Wih_b, bih_f, bih_b,
                               pWih, pbih, r123, WT1, bcat, XI);
  k_deg<<<NEDGE/256, 256, 0, stream>>>(dst, deg);
  k_sem<<<NNODE/256, 256, 0, stream>>>(feat, out_rels, in_rels, r_label_nd,
                                       rel_emb, w2e_W, w2e_b, hin);
  for (int l = 0; l < 3; ++l) {
    const float* hsrc = (l == 0) ? hin : (repr + (l-1)*32);
    int hstride = (l == 0) ? 32 : 96;
    const float* r_l = (l == 0) ? rel_emb : (r123 + (l-1)*NREL*32);
    k_gnn<<<BB, 512, 0, stream>>>(hsrc, hstride, r_l, src, dst, etype, deg,
                                  W_msg + l*1024, W_self + l*1024, b_gnn + l*32,
                                  repr, l*32);
  }
  k_prep1<<<BB, 256, 0, stream>>>(repr, gru_bias, AT, ghid0);
  k_gemm1<<<dim3(9, 512), 256, 0, stream>>>(AT, WT1, bcat, GI);
  k_gru<<<512, 576, 0, stream>>>(Whh_f, bhh_f, Whh_b, bhh_b, GI, ghid0, gruo);
  k_prep2<<<dim3(BB, 2), 256, 0, stream>>>(gruo, AT2);
  k_gemm2<<<1024, 384, 0, stream>>>(AT2, Wo_W, Wo_b, nh);
  k_pool2<<<BB, 128, 0, stream>>>(nh, goutb, headb, tailb);
  k_path<<<256, 128, 0, stream>>>(XI, in_rels, rel_labels, pWhh, pbhh, lastb);
  k_final<<<BB, 64, 0, stream>>>(lastb, r123 + 2*NREL*32, rel_labels,
                                 goutb, headb, tailb, fcW, fcb, out);
}

// Round 6
// 1177.645 us; speedup vs baseline: 2.2650x; 1.0823x over previous
//
#include <hip/hip_runtime.h>
#include <math.h>

#define BB 512
#define NT 128
#define NREL 201
#define NNODE (BB*NT)
#define NEDGE (NNODE*16)

typedef float f32x4 __attribute__((ext_vector_type(4)));

__device__ __forceinline__ float sigm(float x) { return 1.f/(1.f + __expf(-x)); }

// ---------------------------------------------------------------- k_relchain : r123 (serial 3-layer chain, 1 block)
__global__ void k_relchain(const float* __restrict__ rel_emb, const float* __restrict__ W_rel,
                           float* __restrict__ r123) {
  __shared__ float rcur[NREL*32];
  __shared__ float rnext[NREL*32];
  int tid = threadIdx.x;
  for (int i = tid; i < NREL*32; i += 256) rcur[i] = rel_emb[i];
  __syncthreads();
  for (int l = 0; l < 3; ++l) {
    const float* w = W_rel + l*1024;
    for (int i = tid; i < NREL*32; i += 256) {
      int row = i >> 5, col = i & 31;
      float s = 0.f;
      #pragma unroll
      for (int d = 0; d < 32; ++d) s += rcur[row*32 + d] * w[d*32 + col];
      rnext[i] = s;
    }
    __syncthreads();
    for (int i = tid; i < NREL*32; i += 256) { float v = rnext[i]; rcur[i] = v; r123[l*NREL*32 + i] = v; }
    __syncthreads();
  }
}

// ---------------------------------------------------------------- k_wt1 : WT1[96][576] = [Wih_f;Wih_b]^T ; bcat
__global__ __launch_bounds__(256) void k_wt1(const float* __restrict__ Wih_f,
                                             const float* __restrict__ Wih_b,
                                             const float* __restrict__ bih_f,
                                             const float* __restrict__ bih_b,
                                             float* __restrict__ WT1,
                                             float* __restrict__ bcat) {
  int i = blockIdx.x*256 + threadIdx.x;   // 216 blocks: 96*576
  if (i < 96*576) {
    int k = i / 576, j = i - k*576;
    WT1[i] = (j < 288) ? Wih_f[j*96 + k] : Wih_b[(j-288)*96 + k];
  }
  if (i < 576) bcat[i] = (i < 288) ? bih_f[i] : bih_b[i-288];
}

// ---------------------------------------------------------------- k_xi : XI[201][96] = r3 @ pWih^T + pbih
__global__ __launch_bounds__(96) void k_xi(const float* __restrict__ r3,
                                           const float* __restrict__ pWih,
                                           const float* __restrict__ pbih,
                                           float* __restrict__ XI) {
  __shared__ float rrow[32];
  int r = blockIdx.x, j = threadIdx.x;
  if (j < 32) rrow[j] = r3[r*32 + j];
  __syncthreads();
  float s = pbih[j];
  const float4* w4 = (const float4*)(pWih + j*32);
  #pragma unroll
  for (int q = 0; q < 8; ++q) {
    float4 w = w4[q];
    s += rrow[4*q+0]*w.x + rrow[4*q+1]*w.y + rrow[4*q+2]*w.z + rrow[4*q+3]*w.w;
  }
  XI[r*96 + j] = s;
}

// ---------------------------------------------------------------- k_deg
__global__ void k_deg(const int* __restrict__ dst, int* __restrict__ deg) {
  int e = blockIdx.x*256 + threadIdx.x;
  if (e < NEDGE) atomicAdd(&deg[dst[e]], 1);
}

// ---------------------------------------------------------------- k_sem
__device__ __forceinline__ void sem_att(const float* __restrict__ rel_emb,
                                        const int rels[8], const float tgt[32],
                                        float out[32]) {
  float dots[8]; float mx = -1e30f;
  #pragma unroll
  for (int k = 0; k < 8; ++k) {
    const float4* er = (const float4*)(rel_emb + rels[k]*32);
    float s = 0.f;
    #pragma unroll
    for (int q = 0; q < 8; ++q) {
      float4 v = er[q];
      s += v.x*tgt[4*q+0] + v.y*tgt[4*q+1] + v.z*tgt[4*q+2] + v.w*tgt[4*q+3];
    }
    dots[k] = s; mx = fmaxf(mx, s);
  }
  float den = 0.f;
  #pragma unroll
  for (int k = 0; k < 8; ++k) { float e = __expf(dots[k]-mx); dots[k] = e; den += e; }
  float inv = 1.f/den;
  #pragma unroll
  for (int d = 0; d < 32; ++d) out[d] = 0.f;
  #pragma unroll
  for (int k = 0; k < 8; ++k) {
    const float4* er = (const float4*)(rel_emb + rels[k]*32);
    float a = dots[k]*inv;
    #pragma unroll
    for (int q = 0; q < 8; ++q) {
      float4 v = er[q];
      out[4*q+0] += a*v.x; out[4*q+1] += a*v.y; out[4*q+2] += a*v.z; out[4*q+3] += a*v.w;
    }
  }
}

__global__ __launch_bounds__(256) void k_sem(
    const float* __restrict__ feat, const int* __restrict__ out_rels,
    const int* __restrict__ in_rels, const int* __restrict__ r_label_node,
    const float* __restrict__ rel_emb, const float* __restrict__ W,
    const float* __restrict__ bias, float* __restrict__ hin) {
  int n = blockIdx.x*256 + threadIdx.x;
  float tgt[32];
  {
    const float4* tr = (const float4*)(rel_emb + r_label_node[n]*32);
    #pragma unroll
    for (int q = 0; q < 8; ++q) {
      float4 v = tr[q];
      tgt[4*q+0]=v.x; tgt[4*q+1]=v.y; tgt[4*q+2]=v.z; tgt[4*q+3]=v.w;
    }
  }
  int ro[8], ri[8];
  #pragma unroll
  for (int k = 0; k < 8; ++k) { ro[k] = out_rels[n*8+k]; ri[k] = in_rels[n*8+k]; }
  float osem[32], isem[32];
  sem_att(rel_emb, ro, tgt, osem);
  sem_att(rel_emb, ri, tgt, isem);
  const float4* fr = (const float4*)(feat + (size_t)n*16);
  float4* ho = (float4*)(hin + (size_t)n*32);
  #pragma unroll
  for (int q = 0; q < 4; ++q) ho[q] = fr[q];
  #pragma unroll
  for (int j = 0; j < 16; ++j) {
    float s = bias[j];
    #pragma unroll
    for (int d = 0; d < 32; ++d) s += osem[d]*W[d*16+j] + isem[d]*W[(32+d)*16+j];
    hin[(size_t)n*32 + 16 + j] = sigm(s);
  }
}

// ---------------------------------------------------------------- k_gnn
__global__ __launch_bounds__(512) void k_gnn(
    const float* __restrict__ hsrc, int hstride, const float* __restrict__ r_l,
    const int* __restrict__ src, const int* __restrict__ dst, const int* __restrict__ etype,
    const int* __restrict__ deg, const float* __restrict__ Wm, const float* __restrict__ Ws,
    const float* __restrict__ bl, float* __restrict__ repr_out, int ofs) {
  __shared__ __align__(16) float hl[NT*32];
  __shared__ __align__(16) float agg[NT*32];
  __shared__ float rl[NREL*32];
  int g = blockIdx.x;
  int tid = threadIdx.x;
  for (int i = tid; i < NT*32; i += 512) {
    int row = i >> 5, col = i & 31;
    hl[i] = hsrc[(size_t)(g*NT + row)*hstride + col];
    agg[i] = 0.f;
  }
  for (int i = tid; i < NREL*32; i += 512) rl[i] = r_l[i];
  __syncthreads();
  {
    int d = tid & 31, grp = tid >> 5;   // 16 groups of 32 lanes
    int ebase = g*2048;
    for (int i = grp; i < 2048; i += 16) {
      int e = ebase + i;
      int sl = src[e] - g*NT;
      int dl = dst[e] - g*NT;
      float m = hl[sl*32 + d] * rl[etype[e]*32 + d];
      atomicAdd(&agg[dl*32 + d], m);
    }
  }
  __syncthreads();
  int j = tid & 31;
  float wm[32], ws[32];
  #pragma unroll
  for (int dd = 0; dd < 32; ++dd) { wm[dd] = Wm[dd*32+j]; ws[dd] = Ws[dd*32+j]; }
  float bj = bl[j];
  int nbase = tid >> 5;
  for (int k2 = 0; k2 < 8; ++k2) {
    int n = nbase + k2*16;
    int dv = deg[g*NT + n];
    float invd = 1.f / (float)(dv > 0 ? dv : 1);
    const float4* a4 = (const float4*)&agg[n*32];
    const float4* h4 = (const float4*)&hl[n*32];
    float sa = 0.f, sh = 0.f;
    #pragma unroll
    for (int q = 0; q < 8; ++q) {
      float4 av = a4[q], hv = h4[q];
      sa += av.x*wm[4*q+0] + av.y*wm[4*q+1] + av.z*wm[4*q+2] + av.w*wm[4*q+3];
      sh += hv.x*ws[4*q+0] + hv.y*ws[4*q+1] + hv.z*ws[4*q+2] + hv.w*ws[4*q+3];
    }
    float res = bj + invd*sa + sh;
    repr_out[(size_t)(g*NT + n)*96 + ofs + j] = fmaxf(res, 0.f);
  }
}

// ---------------------------------------------------------------- k_prep1 : AT = relu(repr+gbias)^T ; ghid0 = colmax(repr)
__global__ __launch_bounds__(256) void k_prep1(
    const float* __restrict__ repr, const float* __restrict__ gbias,
    float* __restrict__ AT, float* __restrict__ ghid0) {
  __shared__ float t[NT*97];
  int g = blockIdx.x, tid = threadIdx.x;
  const float* rb = repr + (size_t)g*NT*96;
  for (int i = tid; i < NT*96; i += 256) {
    int row = i / 96, col = i - row*96;
    t[row*97 + col] = rb[i];
  }
  __syncthreads();
  for (int i = tid; i < 96*NT; i += 256) {
    int k = i >> 7, n = i & 127;
    AT[(size_t)k*NNODE + g*NT + n] = fmaxf(t[n*97 + k] + gbias[k], 0.f);
  }
  if (tid < 96) {
    float m = -1e30f;
    for (int n = 0; n < NT; ++n) m = fmaxf(m, t[n*97 + tid]);
    ghid0[g*96 + tid] = m;
  }
}

// ---------------------------------------------------------------- k_gemm1 : GI[65536][576] = A(T) @ WT1 + bcat  (BM=128,BN=64,K=96)
__global__ __launch_bounds__(256) void k_gemm1(
    const float* __restrict__ AT, const float* __restrict__ WT1,
    const float* __restrict__ bcat, float* __restrict__ GI) {
  __shared__ __align__(16) float As[96*128];
  __shared__ __align__(16) float Bs[96*64];
  int nb = blockIdx.x;   // 0..8
  int mb = blockIdx.y;   // 0..511
  int m0 = mb*128, n0 = nb*64;
  int tid = threadIdx.x;
  for (int i = tid; i < 3072; i += 256) {
    int r = i >> 5, c4 = i & 31;
    *(float4*)&As[r*128 + c4*4] = *(const float4*)&AT[(size_t)r*NNODE + m0 + c4*4];
  }
  for (int i = tid; i < 1536; i += 256) {
    int r = i >> 4, c4 = i & 15;
    *(float4*)&Bs[r*64 + c4*4] = *(const float4*)&WT1[r*576 + n0 + c4*4];
  }
  __syncthreads();
  int tc = tid & 15, tr = tid >> 4;
  int r0 = tr*8, c0 = tc*4;
  float acc[8][4] = {};
  #pragma unroll 4
  for (int k = 0; k < 96; ++k) {
    float4 a0 = *(float4*)&As[k*128 + r0];
    float4 a1 = *(float4*)&As[k*128 + r0 + 4];
    float4 b  = *(float4*)&Bs[k*64 + c0];
    acc[0][0]+=a0.x*b.x; acc[0][1]+=a0.x*b.y; acc[0][2]+=a0.x*b.z; acc[0][3]+=a0.x*b.w;
    acc[1][0]+=a0.y*b.x; acc[1][1]+=a0.y*b.y; acc[1][2]+=a0.y*b.z; acc[1][3]+=a0.y*b.w;
    acc[2][0]+=a0.z*b.x; acc[2][1]+=a0.z*b.y; acc[2][2]+=a0.z*b.z; acc[2][3]+=a0.z*b.w;
    acc[3][0]+=a0.w*b.x; acc[3][1]+=a0.w*b.y; acc[3][2]+=a0.w*b.z; acc[3][3]+=a0.w*b.w;
    acc[4][0]+=a1.x*b.x; acc[4][1]+=a1.x*b.y; acc[4][2]+=a1.x*b.z; acc[4][3]+=a1.x*b.w;
    acc[5][0]+=a1.y*b.x; acc[5][1]+=a1.y*b.y; acc[5][2]+=a1.y*b.z; acc[5][3]+=a1.y*b.w;
    acc[6][0]+=a1.z*b.x; acc[6][1]+=a1.z*b.y; acc[6][2]+=a1.z*b.z; acc[6][3]+=a1.z*b.w;
    acc[7][0]+=a1.w*b.x; acc[7][1]+=a1.w*b.y; acc[7][2]+=a1.w*b.z; acc[7][3]+=a1.w*b.w;
  }
  float4 bia = *(const float4*)&bcat[n0 + c0];
  #pragma unroll
  for (int r = 0; r < 8; ++r) {
    f32x4 o = { acc[r][0]+bia.x, acc[r][1]+bia.y, acc[r][2]+bia.z, acc[r][3]+bia.w };
    __builtin_nontemporal_store(o, (f32x4*)&GI[(size_t)(m0 + r0 + r)*576 + n0 + c0]);
  }
}

// ---------------------------------------------------------------- k_gru : K-split-6, weights pinned LIVE (in-loop PIN defeats remat)
#define PIN4(v) asm volatile("" : "+v"(v.x), "+v"(v.y), "+v"(v.z), "+v"(v.w))
#define DOT16(acc, W0,W1,W2,W3, X0,X1,X2,X3) \
  acc += W0.x*X0.x + W0.y*X0.y + W0.z*X0.z + W0.w*X0.w \
       + W1.x*X1.x + W1.y*X1.y + W1.z*X1.z + W1.w*X1.w \
       + W2.x*X2.x + W2.y*X2.y + W2.z*X2.z + W2.w*X2.w \
       + W3.x*X3.x + W3.y*X3.y + W3.z*X3.z + W3.w*X3.w

__global__ __launch_bounds__(576, 2) void k_gru(
    const float* __restrict__ Whh_f, const float* __restrict__ bhh_f,
    const float* __restrict__ Whh_b, const float* __restrict__ bhh_b,
    const float* __restrict__ GI, const float* __restrict__ ghid0,
    float* __restrict__ gruout) {
  __shared__ __align__(16) float h_lds[2][96];
  __shared__ float part[2][288][9];     // pad 9: bank-stride 9, conflict-free
  int bx = blockIdx.x;                  // 512 blocks
  int dir = bx >> 8;
  int gbase = (bx & 255) * 2;
  int tid = threadIdx.x;                // 0..575
  int c = tid % 96;                     // output channel within gate
  int p = tid / 96;                     // K chunk 0..5 (16 wide)
  bool fin = (tid < 192);
  int s = p;                            // for fin threads: p in {0,1} == seq

  const float* Whh = dir ? Whh_b : Whh_f;
  const float4* wr0 = (const float4*)(Whh + (size_t)c*96 + p*16);
  const float4* wr1 = (const float4*)(Whh + (size_t)(96+c)*96 + p*16);
  const float4* wr2 = (const float4*)(Whh + (size_t)(192+c)*96 + p*16);
  float4 wa0=wr0[0], wa1=wr0[1], wa2=wr0[2], wa3=wr0[3];
  float4 wb0=wr1[0], wb1=wr1[1], wb2=wr1[2], wb3=wr1[3];
  float4 wc0=wr2[0], wc1=wr2[1], wc2=wr2[2], wc3=wr2[3];

  float bh0=0.f, bh1=0.f, bh2=0.f;
  float gi0=0.f, gi1=0.f, gi2=0.f;
  if (fin) {
    const float* bhh = dir ? bhh_b : bhh_f;
    bh0 = bhh[c]; bh1 = bhh[96+c]; bh2 = bhh[192+c];
    h_lds[s][c] = ghid0[(gbase+s)*96 + c];
    int pos0 = dir ? 127 : 0;
    const float* g = GI + (size_t)((gbase+s)*128 + pos0)*576 + dir*288;
    gi0 = g[c]; gi1 = g[96+c]; gi2 = g[192+c];
  }
  __syncthreads();
  for (int t = 0; t < 128; ++t) {
    // redefine weights via no-op asm each iteration: the allocator cannot
    // rematerialize the loads, so the 48 floats stay live in VGPRs.
    PIN4(wa0); PIN4(wa1); PIN4(wa2); PIN4(wa3);
    PIN4(wb0); PIN4(wb1); PIN4(wb2); PIN4(wb3);
    PIN4(wc0); PIN4(wc1); PIN4(wc2); PIN4(wc3);
    int pos = dir ? (127-t) : t;
    float gn0=0.f, gn1=0.f, gn2=0.f;
    if (fin && t < 127) {               // prefetch next step's GI
      int posn = dir ? (126-t) : (t+1);
      const float* g = GI + (size_t)((gbase+s)*128 + posn)*576 + dir*288;
      gn0 = g[c]; gn1 = g[96+c]; gn2 = g[192+c];
    }
    float p00=0.f,p01=0.f,p02=0.f, p10=0.f,p11=0.f,p12=0.f;
    {
      const float4* h0 = (const float4*)&h_lds[0][p*16];
      float4 x0=h0[0], x1=h0[1], x2=h0[2], x3=h0[3];
      DOT16(p00, wa0,wa1,wa2,wa3, x0,x1,x2,x3);
      DOT16(p01, wb0,wb1,wb2,wb3, x0,x1,x2,x3);
      DOT16(p02, wc0,wc1,wc2,wc3, x0,x1,x2,x3);
      const float4* h1 = (const float4*)&h_lds[1][p*16];
      float4 y0=h1[0], y1=h1[1], y2=h1[2], y3=h1[3];
      DOT16(p10, wa0,wa1,wa2,wa3, y0,y1,y2,y3);
      DOT16(p11, wb0,wb1,wb2,wb3, y0,y1,y2,y3);
      DOT16(p12, wc0,wc1,wc2,wc3, y0,y1,y2,y3);
    }
    part[0][c][p]     = p00; part[0][96+c][p]  = p01; part[0][192+c][p] = p02;
    part[1][c][p]     = p10; part[1][96+c][p]  = p11; part[1][192+c][p] = p12;
    __syncthreads();
    if (fin) {
      const float* pr = part[s][c];
      const float* pz = part[s][96+c];
      const float* pn = part[s][192+c];
      float ghr = pr[0]+pr[1]+pr[2]+pr[3]+pr[4]+pr[5] + bh0;
      float ghz = pz[0]+pz[1]+pz[2]+pz[3]+pz[4]+pz[5] + bh1;
      float ghn = pn[0]+pn[1]+pn[2]+pn[3]+pn[4]+pn[5] + bh2;
      float r  = sigm(gi0 + ghr);
      float z  = sigm(gi1 + ghz);
      float nn = tanhf(gi2 + r*ghn);
      float hv = (1.f - z)*nn + z*h_lds[s][c];
      h_lds[s][c] = hv;
      gruout[(size_t)((gbase+s)*128 + pos)*192 + dir*96 + c] = hv;
      gi0 = gn0; gi1 = gn1; gi2 = gn2;
    }
    __syncthreads();
  }
}

// ---------------------------------------------------------------- k_prep2 : AT2 = relu(gruout)^T
__global__ __launch_bounds__(256) void k_prep2(const float* __restrict__ gruo,
                                               float* __restrict__ AT2) {
  __shared__ float t[NT*97];
  int g = blockIdx.x, half = blockIdx.y, tid = threadIdx.x;
  const float* rb = gruo + (size_t)g*NT*192 + half*96;
  for (int i = tid; i < NT*96; i += 256) {
    int row = i / 96, col = i - row*96;
    t[row*97 + col] = rb[(size_t)row*192 + col];
  }
  __syncthreads();
  for (int i = tid; i < 96*NT; i += 256) {
    int k = i >> 7, n = i & 127;
    AT2[(size_t)(half*96 + k)*NNODE + g*NT + n] = fmaxf(t[n*97 + k], 0.f);
  }
}

// ---------------------------------------------------------------- k_gemm2 : nh = relu(A2 @ Wo + b)
__global__ __launch_bounds__(384) void k_gemm2(
    const float* __restrict__ AT2, const float* __restrict__ WoW,
    const float* __restrict__ Wob, float* __restrict__ nh) {
  __shared__ __align__(16) float As[96*64];
  __shared__ __align__(16) float Bs[96*96];
  int m0 = blockIdx.x*64;
  int tid = threadIdx.x;
  int tc = tid % 24, tr = tid / 24;   // tr<16
  int r0 = tr*4, c0 = tc*4;
  float acc[4][4] = {};
  for (int kc = 0; kc < 2; ++kc) {
    for (int i = tid; i < 1536; i += 384) {
      int r = i >> 4, c4 = i & 15;
      *(float4*)&As[r*64 + c4*4] = *(const float4*)&AT2[(size_t)(kc*96 + r)*NNODE + m0 + c4*4];
    }
    for (int i = tid; i < 2304; i += 384) {
      int r = i / 24, c4 = i % 24;
      *(float4*)&Bs[r*96 + c4*4] = *(const float4*)&WoW[(size_t)(kc*96 + r)*96 + c4*4];
    }
    __syncthreads();
    #pragma unroll 8
    for (int k = 0; k < 96; ++k) {
      float4 a = *(float4*)&As[k*64 + r0];
      float4 b = *(float4*)&Bs[k*96 + c0];
      acc[0][0] += a.x*b.x; acc[0][1] += a.x*b.y; acc[0][2] += a.x*b.z; acc[0][3] += a.x*b.w;
      acc[1][0] += a.y*b.x; acc[1][1] += a.y*b.y; acc[1][2] += a.y*b.z; acc[1][3] += a.y*b.w;
      acc[2][0] += a.z*b.x; acc[2][1] += a.z*b.y; acc[2][2] += a.z*b.z; acc[2][3] += a.z*b.w;
      acc[3][0] += a.w*b.x; acc[3][1] += a.w*b.y; acc[3][2] += a.w*b.z; acc[3][3] += a.w*b.w;
    }
    __syncthreads();
  }
  float4 bia = *(const float4*)&Wob[c0];
  #pragma unroll
  for (int r = 0; r < 4; ++r) {
    float4 o = make_float4(fmaxf(acc[r][0]+bia.x, 0.f), fmaxf(acc[r][1]+bia.y, 0.f),
                           fmaxf(acc[r][2]+bia.z, 0.f), fmaxf(acc[r][3]+bia.w, 0.f));
    *(float4*)&nh[(size_t)(m0 + r0 + r)*96 + c0] = o;
  }
}

// ---------------------------------------------------------------- k_pool2
__global__ __launch_bounds__(128) void k_pool2(const float* __restrict__ nh,
                                               float* __restrict__ goutb,
                                               float* __restrict__ headb,
                                               float* __restrict__ tailb) {
  int g = blockIdx.x, j = threadIdx.x;
  if (j >= 96) return;
  const float* base = nh + (size_t)g*NT*96;
  float s = 0.f;
  for (int n = 0; n < NT; ++n) s += base[(size_t)n*96 + j];
  goutb[g*96 + j] = s * (1.f/128.f);
  headb[g*96 + j] = base[j];
  tailb[g*96 + j] = base[96 + j];
}

// ---------------------------------------------------------------- k_path : XI-precomputed 3-step GRU
__global__ __launch_bounds__(128) void k_path(
    const float* __restrict__ XI, const int* __restrict__ in_rels,
    const int* __restrict__ labels, const float* __restrict__ pWhh,
    const float* __restrict__ pbhh, float* __restrict__ last) {
  __shared__ __align__(16) float wsh[96*32];
  __shared__ float bsh[96];
  __shared__ float hbuf[128*33];
  int tid = threadIdx.x;
  for (int i = tid; i < 96*32; i += 128) wsh[i] = pWhh[i];
  if (tid < 96) bsh[tid] = pbhh[tid];
  int p = blockIdx.x*128 + tid;
  int b = p >> 6, pp = p & 63;
  int rid0 = in_rels[b*1024 + (pp >> 3)];
  int rid1 = labels[b];
  int rid2 = in_rels[b*1024 + 8 + (pp & 7)];
  __syncthreads();
  float* hs = &hbuf[tid*33];
  {
    const float* xi = XI + rid0*96;
    #pragma unroll
    for (int gg = 0; gg < 32; ++gg) {
      float r = sigm(xi[gg] + bsh[gg]);
      float z = sigm(xi[32+gg] + bsh[32+gg]);
      float nn = tanhf(xi[64+gg] + r*bsh[64+gg]);
      hs[gg] = (1.f - z)*nn;
    }
  }
  float4 h4[8];
  #pragma unroll
  for (int q = 0; q < 8; ++q) h4[q] = make_float4(hs[4*q], hs[4*q+1], hs[4*q+2], hs[4*q+3]);
  for (int s = 0; s < 2; ++s) {
    const float* xi = XI + (s == 0 ? rid1 : rid2)*96;
    for (int gg = 0; gg < 32; ++gg) {
      float ar = bsh[gg], az = bsh[32+gg], an = bsh[64+gg];
      const float4* wr = (const float4*)&wsh[gg*32];
      const float4* wz = (const float4*)&wsh[(32+gg)*32];
      const float4* wn = (const float4*)&wsh[(64+gg)*32];
      #pragma unroll
      for (int q = 0; q < 8; ++q) {
        float4 hv = h4[q]; float4 w;
        w = wr[q]; ar += hv.x*w.x + hv.y*w.y + hv.z*w.z + hv.w*w.w;
        w = wz[q]; az += hv.x*w.x + hv.y*w.y + hv.z*w.z + hv.w*w.w;
        w = wn[q]; an += hv.x*w.x + hv.y*w.y + hv.z*w.z + hv.w*w.w;
      }
      float r = sigm(xi[gg] + ar);
      float z = sigm(xi[32+gg] + az);
      float nn = tanhf(xi[64+gg] + r*an);
      hs[gg] = (1.f - z)*nn + z*hs[gg];
    }
    #pragma unroll
    for (int q = 0; q < 8; ++q) h4[q] = make_float4(hs[4*q], hs[4*q+1], hs[4*q+2], hs[4*q+3]);
  }
  float* lp = last + (size_t)p*32;
  #pragma unroll
  for (int d = 0; d < 32; ++d) lp[d] = hs[d];
}

// ---------------------------------------------------------------- k_final
__global__ __launch_bounds__(64) void k_final(
    const float* __restrict__ last, const float* __restrict__ r3,
    const int* __restrict__ labels, const float* __restrict__ goutb,
    const float* __restrict__ headb, const float* __restrict__ tailb,
    const float* __restrict__ fcW, const float* __restrict__ fcb,
    float* __restrict__ out) {
  __shared__ float red[64*33];
  __shared__ float gpl[32];
  int b = blockIdx.x, lane = threadIdx.x;
  const float* rl = r3 + labels[b]*32;
  float l32[32];
  {
    const float4* lr = (const float4*)(last + (size_t)(b*64 + lane)*32);
    #pragma unroll
    for (int q = 0; q < 8; ++q) {
      float4 v = lr[q];
      l32[4*q+0]=v.x; l32[4*q+1]=v.y; l32[4*q+2]=v.z; l32[4*q+3]=v.w;
    }
  }
  float s = 0.f;
  #pragma unroll
  for (int d = 0; d < 32; ++d) s += l32[d]*rl[d];
  float mx = s;
  #pragma unroll
  for (int off = 32; off > 0; off >>= 1) mx = fmaxf(mx, __shfl_xor(mx, off));
  float e = __expf(s - mx);
  float den = e;
  #pragma unroll
  for (int off = 32; off > 0; off >>= 1) den += __shfl_xor(den, off);
  float att = e / den;
  #pragma unroll
  for (int d = 0; d < 32; ++d) red[lane*33 + d] = att*l32[d];
  __syncthreads();
  if (lane < 32) {
    float gp = 0.f;
    for (int p2 = 0; p2 < 64; ++p2) gp += red[p2*33 + lane];
    gpl[lane] = gp;
  }
  __syncthreads();
  float acc = 0.f;
  for (int i = lane; i < 352; i += 64) {
    float v;
    if (i < 96)       v = goutb[b*96 + i];
    else if (i < 192) v = headb[b*96 + (i-96)];
    else if (i < 288) v = tailb[b*96 + (i-192)];
    else if (i < 320) v = rl[i-288];
    else              v = gpl[i-320];
    acc += v*fcW[i];
  }
  #pragma unroll
  for (int off = 32; off > 0; off >>= 1) acc += __shfl_xor(acc, off);
  if (lane == 0) out[b] = acc + fcb[0];
}

// ---------------------------------------------------------------- launch
extern "C" void kernel_launch(void* const* d_in, const int* in_sizes, int n_in,
                              void* d_out, int out_size, void* d_ws, size_t ws_size,
                              hipStream_t stream) {
  const float* feat       = (const float*)d_in[0];
  const int*   out_rels   = (const int*)d_in[1];
  const int*   in_rels    = (const int*)d_in[2];
  const int*   r_label_nd = (const int*)d_in[3];
  const int*   src        = (const int*)d_in[4];
  const int*   dst        = (const int*)d_in[5];
  const int*   etype      = (const int*)d_in[6];
  const int*   rel_labels = (const int*)d_in[7];
  const float* rel_emb    = (const float*)d_in[8];
  const float* w2e_W      = (const float*)d_in[9];
  const float* w2e_b      = (const float*)d_in[10];
  const float* W_msg      = (const float*)d_in[11];
  const float* W_self     = (const float*)d_in[12];
  const float* b_gnn      = (const float*)d_in[13];
  const float* W_rel      = (const float*)d_in[14];
  const float* gru_bias   = (const float*)d_in[15];
  const float* Wih_f      = (const float*)d_in[16];
  const float* Whh_f      = (const float*)d_in[17];
  const float* bih_f      = (const float*)d_in[18];
  const float* bhh_f      = (const float*)d_in[19];
  const float* Wih_b      = (const float*)d_in[20];
  const float* Whh_b      = (const float*)d_in[21];
  const float* bih_b      = (const float*)d_in[22];
  const float* bhh_b      = (const float*)d_in[23];
  const float* Wo_W       = (const float*)d_in[24];
  const float* Wo_b       = (const float*)d_in[25];
  const float* pWih       = (const float*)d_in[26];
  const float* pWhh       = (const float*)d_in[27];
  const float* pbih       = (const float*)d_in[28];
  const float* pbhh       = (const float*)d_in[29];
  const float* fcW        = (const float*)d_in[30];
  const float* fcb        = (const float*)d_in[31];
  float* out = (float*)d_out;

  float* p = (float*)d_ws;
  float* hin   = p; p += (size_t)NNODE*32;
  float* R1    = p; p += (size_t)NNODE*192;
  float* repr  = R1;
  float* AT    = R1 + (size_t)NNODE*96;
  float* gruo  = R1;
  float* R2    = p; p += (size_t)NNODE*576;
  float* GI    = R2;
  float* AT2   = R2;
  float* nh    = R2 + (size_t)192*NNODE;
  int*   deg   = (int*)p; p += NNODE;
  float* r123  = p; p += 3*NREL*32;
  float* WT1   = p; p += 96*576;
  float* bcat  = p; p += 576;
  float* XI    = p; p += NREL*96;
  float* ghid0 = p; p += BB*96;
  float* goutb = p; p += BB*96;
  float* headb = p; p += BB*96;
  float* tailb = p; p += BB*96;
  float* lastb = p; p += (size_t)BB*64*32;

  hipMemsetAsync(deg, 0, NNODE*sizeof(int), stream);
  k_relchain<<<1, 256, 0, stream>>>(rel_emb, W_rel, r123);
  k_wt1<<<(96*576+255)/256, 256, 0, stream>>>(Wih_f, Wih_b, bih_f, bih_b, WT1, bcat);
  k_xi<<<NREL, 96, 0, stream>>>(r123 + 2*NREL*32, pWih, pbih, XI);
  k_deg<<<NEDGE/256, 256, 0, stream>>>(dst, deg);
  k_sem<<<NNODE/256, 256, 0, stream>>>(feat, out_rels, in_rels, r_label_nd,
                                       rel_emb, w2e_W, w2e_b, hin);
  for (int l = 0; l < 3; ++l) {
    const float* hsrc = (l == 0) ? hin : (repr + (l-1)*32);
    int hstride = (l == 0) ? 32 : 96;
    const float* r_l = (l == 0) ? rel_emb : (r123 + (l-1)*NREL*32);
    k_gnn<<<BB, 512, 0, stream>>>(hsrc, hstride, r_l, src, dst, etype, deg,
                                  W_msg + l*1024, W_self + l*1024, b_gnn + l*32,
                                  repr, l*32);
  }
  k_prep1<<<BB, 256, 0, stream>>>(repr, gru_bias, AT, ghid0);
  k_gemm1<<<dim3(9, 512), 256, 0, stream>>>(AT, WT1, bcat, GI);
  k_gru<<<512, 576, 0, stream>>>(Whh_f, bhh_f, Whh_b, bhh_b, GI, ghid0, gruo);
  k_prep2<<<dim3(BB, 2), 256, 0, stream>>>(gruo, AT2);
  k_gemm2<<<1024, 384, 0, stream>>>(AT2, Wo_W, Wo_b, nh);
  k_pool2<<<BB, 128, 0, stream>>>(nh, goutb, headb, tailb);
  k_path<<<256, 128, 0, stream>>>(XI, in_rels, rel_labels, pWhh, pbhh, lastb);
  k_final<<<BB, 64, 0, stream>>>(lastb, r123 + 2*NREL*32, rel_labels,
                                 goutb, headb, tailb, fcW, fcb, out);
}

// Round 7
// 1123.106 us; speedup vs baseline: 2.3750x; 1.0486x over previous
//
#include <hip/hip_runtime.h>
#include <math.h>

#define BB 512
#define NT 128
#define NREL 201
#define NNODE (BB*NT)
#define NEDGE (NNODE*16)

typedef float f32x4 __attribute__((ext_vector_type(4)));

__device__ __forceinline__ float sigm(float x) { return 1.f/(1.f + __expf(-x)); }

// ---------------------------------------------------------------- k_relchain : r123 (serial 3-layer chain, 1 block)
__global__ void k_relchain(const float* __restrict__ rel_emb, const float* __restrict__ W_rel,
                           float* __restrict__ r123) {
  __shared__ float rcur[NREL*32];
  __shared__ float rnext[NREL*32];
  int tid = threadIdx.x;
  for (int i = tid; i < NREL*32; i += 256) rcur[i] = rel_emb[i];
  __syncthreads();
  for (int l = 0; l < 3; ++l) {
    const float* w = W_rel + l*1024;
    for (int i = tid; i < NREL*32; i += 256) {
      int row = i >> 5, col = i & 31;
      float s = 0.f;
      #pragma unroll
      for (int d = 0; d < 32; ++d) s += rcur[row*32 + d] * w[d*32 + col];
      rnext[i] = s;
    }
    __syncthreads();
    for (int i = tid; i < NREL*32; i += 256) { float v = rnext[i]; rcur[i] = v; r123[l*NREL*32 + i] = v; }
    __syncthreads();
  }
}

// ---------------------------------------------------------------- k_wt1 : WT1[96][576] = [Wih_f;Wih_b]^T ; bcat
__global__ __launch_bounds__(256) void k_wt1(const float* __restrict__ Wih_f,
                                             const float* __restrict__ Wih_b,
                                             const float* __restrict__ bih_f,
                                             const float* __restrict__ bih_b,
                                             float* __restrict__ WT1,
                                             float* __restrict__ bcat) {
  int i = blockIdx.x*256 + threadIdx.x;
  if (i < 96*576) {
    int k = i / 576, j = i - k*576;
    WT1[i] = (j < 288) ? Wih_f[j*96 + k] : Wih_b[(j-288)*96 + k];
  }
  if (i < 576) bcat[i] = (i < 288) ? bih_f[i] : bih_b[i-288];
}

// ---------------------------------------------------------------- k_xi : XI[201][96] = r3 @ pWih^T + pbih
__global__ __launch_bounds__(96) void k_xi(const float* __restrict__ r3,
                                           const float* __restrict__ pWih,
                                           const float* __restrict__ pbih,
                                           float* __restrict__ XI) {
  __shared__ float rrow[32];
  int r = blockIdx.x, j = threadIdx.x;
  if (j < 32) rrow[j] = r3[r*32 + j];
  __syncthreads();
  float s = pbih[j];
  const float4* w4 = (const float4*)(pWih + j*32);
  #pragma unroll
  for (int q = 0; q < 8; ++q) {
    float4 w = w4[q];
    s += rrow[4*q+0]*w.x + rrow[4*q+1]*w.y + rrow[4*q+2]*w.z + rrow[4*q+3]*w.w;
  }
  XI[r*96 + j] = s;
}

// ---------------------------------------------------------------- k_deg
__global__ void k_deg(const int* __restrict__ dst, int* __restrict__ deg) {
  int e = blockIdx.x*256 + threadIdx.x;
  if (e < NEDGE) atomicAdd(&deg[dst[e]], 1);
}

// ---------------------------------------------------------------- k_sem
__device__ __forceinline__ void sem_att(const float* __restrict__ rel_emb,
                                        const int rels[8], const float tgt[32],
                                        float out[32]) {
  float dots[8]; float mx = -1e30f;
  #pragma unroll
  for (int k = 0; k < 8; ++k) {
    const float4* er = (const float4*)(rel_emb + rels[k]*32);
    float s = 0.f;
    #pragma unroll
    for (int q = 0; q < 8; ++q) {
      float4 v = er[q];
      s += v.x*tgt[4*q+0] + v.y*tgt[4*q+1] + v.z*tgt[4*q+2] + v.w*tgt[4*q+3];
    }
    dots[k] = s; mx = fmaxf(mx, s);
  }
  float den = 0.f;
  #pragma unroll
  for (int k = 0; k < 8; ++k) { float e = __expf(dots[k]-mx); dots[k] = e; den += e; }
  float inv = 1.f/den;
  #pragma unroll
  for (int d = 0; d < 32; ++d) out[d] = 0.f;
  #pragma unroll
  for (int k = 0; k < 8; ++k) {
    const float4* er = (const float4*)(rel_emb + rels[k]*32);
    float a = dots[k]*inv;
    #pragma unroll
    for (int q = 0; q < 8; ++q) {
      float4 v = er[q];
      out[4*q+0] += a*v.x; out[4*q+1] += a*v.y; out[4*q+2] += a*v.z; out[4*q+3] += a*v.w;
    }
  }
}

__global__ __launch_bounds__(256) void k_sem(
    const float* __restrict__ feat, const int* __restrict__ out_rels,
    const int* __restrict__ in_rels, const int* __restrict__ r_label_node,
    const float* __restrict__ rel_emb, const float* __restrict__ W,
    const float* __restrict__ bias, float* __restrict__ hin) {
  int n = blockIdx.x*256 + threadIdx.x;
  float tgt[32];
  {
    const float4* tr = (const float4*)(rel_emb + r_label_node[n]*32);
    #pragma unroll
    for (int q = 0; q < 8; ++q) {
      float4 v = tr[q];
      tgt[4*q+0]=v.x; tgt[4*q+1]=v.y; tgt[4*q+2]=v.z; tgt[4*q+3]=v.w;
    }
  }
  int ro[8], ri[8];
  #pragma unroll
  for (int k = 0; k < 8; ++k) { ro[k] = out_rels[n*8+k]; ri[k] = in_rels[n*8+k]; }
  float osem[32], isem[32];
  sem_att(rel_emb, ro, tgt, osem);
  sem_att(rel_emb, ri, tgt, isem);
  const float4* fr = (const float4*)(feat + (size_t)n*16);
  float4* ho = (float4*)(hin + (size_t)n*32);
  #pragma unroll
  for (int q = 0; q < 4; ++q) ho[q] = fr[q];
  #pragma unroll
  for (int j = 0; j < 16; ++j) {
    float s = bias[j];
    #pragma unroll
    for (int d = 0; d < 32; ++d) s += osem[d]*W[d*16+j] + isem[d]*W[(32+d)*16+j];
    hin[(size_t)n*32 + 16 + j] = sigm(s);
  }
}

// ---------------------------------------------------------------- k_gnn
__global__ __launch_bounds__(512) void k_gnn(
    const float* __restrict__ hsrc, int hstride, const float* __restrict__ r_l,
    const int* __restrict__ src, const int* __restrict__ dst, const int* __restrict__ etype,
    const int* __restrict__ deg, const float* __restrict__ Wm, const float* __restrict__ Ws,
    const float* __restrict__ bl, float* __restrict__ repr_out, int ofs) {
  __shared__ __align__(16) float hl[NT*32];
  __shared__ __align__(16) float agg[NT*32];
  __shared__ float rl[NREL*32];
  int g = blockIdx.x;
  int tid = threadIdx.x;
  for (int i = tid; i < NT*32; i += 512) {
    int row = i >> 5, col = i & 31;
    hl[i] = hsrc[(size_t)(g*NT + row)*hstride + col];
    agg[i] = 0.f;
  }
  for (int i = tid; i < NREL*32; i += 512) rl[i] = r_l[i];
  __syncthreads();
  {
    int d = tid & 31, grp = tid >> 5;
    int ebase = g*2048;
    for (int i = grp; i < 2048; i += 16) {
      int e = ebase + i;
      int sl = src[e] - g*NT;
      int dl = dst[e] - g*NT;
      float m = hl[sl*32 + d] * rl[etype[e]*32 + d];
      atomicAdd(&agg[dl*32 + d], m);
    }
  }
  __syncthreads();
  int j = tid & 31;
  float wm[32], ws[32];
  #pragma unroll
  for (int dd = 0; dd < 32; ++dd) { wm[dd] = Wm[dd*32+j]; ws[dd] = Ws[dd*32+j]; }
  float bj = bl[j];
  int nbase = tid >> 5;
  for (int k2 = 0; k2 < 8; ++k2) {
    int n = nbase + k2*16;
    int dv = deg[g*NT + n];
    float invd = 1.f / (float)(dv > 0 ? dv : 1);
    const float4* a4 = (const float4*)&agg[n*32];
    const float4* h4 = (const float4*)&hl[n*32];
    float sa = 0.f, sh = 0.f;
    #pragma unroll
    for (int q = 0; q < 8; ++q) {
      float4 av = a4[q], hv = h4[q];
      sa += av.x*wm[4*q+0] + av.y*wm[4*q+1] + av.z*wm[4*q+2] + av.w*wm[4*q+3];
      sh += hv.x*ws[4*q+0] + hv.y*ws[4*q+1] + hv.z*ws[4*q+2] + hv.w*ws[4*q+3];
    }
    float res = bj + invd*sa + sh;
    repr_out[(size_t)(g*NT + n)*96 + ofs + j] = fmaxf(res, 0.f);
  }
}

// ---------------------------------------------------------------- k_prep1 : AT = relu(repr+gbias)^T ; ghid0 = colmax(repr)
__global__ __launch_bounds__(256) void k_prep1(
    const float* __restrict__ repr, const float* __restrict__ gbias,
    float* __restrict__ AT, float* __restrict__ ghid0) {
  __shared__ float t[NT*97];
  int g = blockIdx.x, tid = threadIdx.x;
  const float* rb = repr + (size_t)g*NT*96;
  for (int i = tid; i < NT*96; i += 256) {
    int row = i / 96, col = i - row*96;
    t[row*97 + col] = rb[i];
  }
  __syncthreads();
  for (int i = tid; i < 96*NT; i += 256) {
    int k = i >> 7, n = i & 127;
    AT[(size_t)k*NNODE + g*NT + n] = fmaxf(t[n*97 + k] + gbias[k], 0.f);
  }
  if (tid < 96) {
    float m = -1e30f;
    for (int n = 0; n < NT; ++n) m = fmaxf(m, t[n*97 + tid]);
    ghid0[g*96 + tid] = m;
  }
}

// ---------------------------------------------------------------- k_gemm1 : GI[65536][576] = A(T) @ WT1 + bcat  (BM=128,BN=64,K=96)
__global__ __launch_bounds__(256) void k_gemm1(
    const float* __restrict__ AT, const float* __restrict__ WT1,
    const float* __restrict__ bcat, float* __restrict__ GI) {
  __shared__ __align__(16) float As[96*128];
  __shared__ __align__(16) float Bs[96*64];
  int nb = blockIdx.x;
  int mb = blockIdx.y;
  int m0 = mb*128, n0 = nb*64;
  int tid = threadIdx.x;
  for (int i = tid; i < 3072; i += 256) {
    int r = i >> 5, c4 = i & 31;
    *(float4*)&As[r*128 + c4*4] = *(const float4*)&AT[(size_t)r*NNODE + m0 + c4*4];
  }
  for (int i = tid; i < 1536; i += 256) {
    int r = i >> 4, c4 = i & 15;
    *(float4*)&Bs[r*64 + c4*4] = *(const float4*)&WT1[r*576 + n0 + c4*4];
  }
  __syncthreads();
  int tc = tid & 15, tr = tid >> 4;
  int r0 = tr*8, c0 = tc*4;
  float acc[8][4] = {};
  #pragma unroll 4
  for (int k = 0; k < 96; ++k) {
    float4 a0 = *(float4*)&As[k*128 + r0];
    float4 a1 = *(float4*)&As[k*128 + r0 + 4];
    float4 b  = *(float4*)&Bs[k*64 + c0];
    acc[0][0]+=a0.x*b.x; acc[0][1]+=a0.x*b.y; acc[0][2]+=a0.x*b.z; acc[0][3]+=a0.x*b.w;
    acc[1][0]+=a0.y*b.x; acc[1][1]+=a0.y*b.y; acc[1][2]+=a0.y*b.z; acc[1][3]+=a0.y*b.w;
    acc[2][0]+=a0.z*b.x; acc[2][1]+=a0.z*b.y; acc[2][2]+=a0.z*b.z; acc[2][3]+=a0.z*b.w;
    acc[3][0]+=a0.w*b.x; acc[3][1]+=a0.w*b.y; acc[3][2]+=a0.w*b.z; acc[3][3]+=a0.w*b.w;
    acc[4][0]+=a1.x*b.x; acc[4][1]+=a1.x*b.y; acc[4][2]+=a1.x*b.z; acc[4][3]+=a1.x*b.w;
    acc[5][0]+=a1.y*b.x; acc[5][1]+=a1.y*b.y; acc[5][2]+=a1.y*b.z; acc[5][3]+=a1.y*b.w;
    acc[6][0]+=a1.z*b.x; acc[6][1]+=a1.z*b.y; acc[6][2]+=a1.z*b.z; acc[6][3]+=a1.z*b.w;
    acc[7][0]+=a1.w*b.x; acc[7][1]+=a1.w*b.y; acc[7][2]+=a1.w*b.z; acc[7][3]+=a1.w*b.w;
  }
  float4 bia = *(const float4*)&bcat[n0 + c0];
  #pragma unroll
  for (int r = 0; r < 8; ++r) {
    f32x4 o = { acc[r][0]+bia.x, acc[r][1]+bia.y, acc[r][2]+bia.z, acc[r][3]+bia.w };
    __builtin_nontemporal_store(o, (f32x4*)&GI[(size_t)(m0 + r0 + r)*576 + n0 + c0]);
  }
}

// ---------------------------------------------------------------- k_gru : S=4 seqs/block, 256 blocks = 1/CU, K-split-6
#define PIN4(v) asm volatile("" : "+v"(v.x), "+v"(v.y), "+v"(v.z), "+v"(v.w))
#define DOT16(acc, W0,W1,W2,W3, X0,X1,X2,X3) \
  acc += W0.x*X0.x + W0.y*X0.y + W0.z*X0.z + W0.w*X0.w \
       + W1.x*X1.x + W1.y*X1.y + W1.z*X1.z + W1.w*X1.w \
       + W2.x*X2.x + W2.y*X2.y + W2.z*X2.z + W2.w*X2.w \
       + W3.x*X3.x + W3.y*X3.y + W3.z*X3.z + W3.w*X3.w

__global__ __launch_bounds__(576, 1) void k_gru(
    const float* __restrict__ Whh_f, const float* __restrict__ bhh_f,
    const float* __restrict__ Whh_b, const float* __restrict__ bhh_b,
    const float* __restrict__ GI, const float* __restrict__ ghid0,
    float* __restrict__ gruout) {
  __shared__ __align__(16) float h_lds[4][96];
  __shared__ float part[4][288][9];     // pad 9 -> bank stride 9, <=2-way (free)
  int bx = blockIdx.x;                  // 256 blocks
  int dir = bx >> 7;
  int gbase = (bx & 127) * 4;           // 4 same-dir graphs per block
  int tid = threadIdx.x;                // 0..575
  int c = tid % 96;
  int p = tid / 96;                     // K chunk 0..5 (16 wide)
  bool fin = (tid < 384);
  int s = p;                            // fin threads: p in 0..3 == seq

  const float* Whh = dir ? Whh_b : Whh_f;
  const float4* wr0 = (const float4*)(Whh + (size_t)c*96 + p*16);
  const float4* wr1 = (const float4*)(Whh + (size_t)(96+c)*96 + p*16);
  const float4* wr2 = (const float4*)(Whh + (size_t)(192+c)*96 + p*16);
  float4 wa0=wr0[0], wa1=wr0[1], wa2=wr0[2], wa3=wr0[3];
  float4 wb0=wr1[0], wb1=wr1[1], wb2=wr1[2], wb3=wr1[3];
  float4 wc0=wr2[0], wc1=wr2[1], wc2=wr2[2], wc3=wr2[3];

  float bh0=0.f, bh1=0.f, bh2=0.f;
  float gi0=0.f, gi1=0.f, gi2=0.f;
  if (fin) {
    const float* bhh = dir ? bhh_b : bhh_f;
    bh0 = bhh[c]; bh1 = bhh[96+c]; bh2 = bhh[192+c];
    h_lds[s][c] = ghid0[(gbase+s)*96 + c];
    int pos0 = dir ? 127 : 0;
    const float* g = GI + (size_t)((gbase+s)*128 + pos0)*576 + dir*288;
    gi0 = g[c]; gi1 = g[96+c]; gi2 = g[192+c];
  }
  __syncthreads();
  for (int t = 0; t < 128; ++t) {
    PIN4(wa0); PIN4(wa1); PIN4(wa2); PIN4(wa3);
    PIN4(wb0); PIN4(wb1); PIN4(wb2); PIN4(wb3);
    PIN4(wc0); PIN4(wc1); PIN4(wc2); PIN4(wc3);
    int pos = dir ? (127-t) : t;
    float gn0=0.f, gn1=0.f, gn2=0.f;
    if (fin && t < 127) {               // prefetch next step's GI
      int posn = dir ? (126-t) : (t+1);
      const float* g = GI + (size_t)((gbase+s)*128 + posn)*576 + dir*288;
      gn0 = g[c]; gn1 = g[96+c]; gn2 = g[192+c];
    }
    #pragma unroll
    for (int s4 = 0; s4 < 4; ++s4) {
      const float4* hh = (const float4*)&h_lds[s4][p*16];
      float4 x0=hh[0], x1=hh[1], x2=hh[2], x3=hh[3];
      float q0=0.f, q1=0.f, q2=0.f;
      DOT16(q0, wa0,wa1,wa2,wa3, x0,x1,x2,x3);
      DOT16(q1, wb0,wb1,wb2,wb3, x0,x1,x2,x3);
      DOT16(q2, wc0,wc1,wc2,wc3, x0,x1,x2,x3);
      part[s4][c][p]     = q0;
      part[s4][96+c][p]  = q1;
      part[s4][192+c][p] = q2;
    }
    __syncthreads();
    if (fin) {
      const float* pr = part[s][c];
      const float* pz = part[s][96+c];
      const float* pn = part[s][192+c];
      float ghr = pr[0]+pr[1]+pr[2]+pr[3]+pr[4]+pr[5] + bh0;
      float ghz = pz[0]+pz[1]+pz[2]+pz[3]+pz[4]+pz[5] + bh1;
      float ghn = pn[0]+pn[1]+pn[2]+pn[3]+pn[4]+pn[5] + bh2;
      float r  = sigm(gi0 + ghr);
      float z  = sigm(gi1 + ghz);
      float nn = tanhf(gi2 + r*ghn);
      float hv = (1.f - z)*nn + z*h_lds[s][c];
      h_lds[s][c] = hv;
      gruout[(size_t)((gbase+s)*128 + pos)*192 + dir*96 + c] = hv;
      gi0 = gn0; gi1 = gn1; gi2 = gn2;
    }
    __syncthreads();
  }
}

// ---------------------------------------------------------------- k_prep2 : AT2 = relu(gruout)^T
__global__ __launch_bounds__(256) void k_prep2(const float* __restrict__ gruo,
                                               float* __restrict__ AT2) {
  __shared__ float t[NT*97];
  int g = blockIdx.x, half = blockIdx.y, tid = threadIdx.x;
  const float* rb = gruo + (size_t)g*NT*192 + half*96;
  for (int i = tid; i < NT*96; i += 256) {
    int row = i / 96, col = i - row*96;
    t[row*97 + col] = rb[(size_t)row*192 + col];
  }
  __syncthreads();
  for (int i = tid; i < 96*NT; i += 256) {
    int k = i >> 7, n = i & 127;
    AT2[(size_t)(half*96 + k)*NNODE + g*NT + n] = fmaxf(t[n*97 + k], 0.f);
  }
}

// ---------------------------------------------------------------- k_gemm2 : nh = relu(A2 @ Wo + b)
__global__ __launch_bounds__(384) void k_gemm2(
    const float* __restrict__ AT2, const float* __restrict__ WoW,
    const float* __restrict__ Wob, float* __restrict__ nh) {
  __shared__ __align__(16) float As[96*64];
  __shared__ __align__(16) float Bs[96*96];
  int m0 = blockIdx.x*64;
  int tid = threadIdx.x;
  int tc = tid % 24, tr = tid / 24;
  int r0 = tr*4, c0 = tc*4;
  float acc[4][4] = {};
  for (int kc = 0; kc < 2; ++kc) {
    for (int i = tid; i < 1536; i += 384) {
      int r = i >> 4, c4 = i & 15;
      *(float4*)&As[r*64 + c4*4] = *(const float4*)&AT2[(size_t)(kc*96 + r)*NNODE + m0 + c4*4];
    }
    for (int i = tid; i < 2304; i += 384) {
      int r = i / 24, c4 = i % 24;
      *(float4*)&Bs[r*96 + c4*4] = *(const float4*)&WoW[(size_t)(kc*96 + r)*96 + c4*4];
    }
    __syncthreads();
    #pragma unroll 8
    for (int k = 0; k < 96; ++k) {
      float4 a = *(float4*)&As[k*64 + r0];
      float4 b = *(float4*)&Bs[k*96 + c0];
      acc[0][0] += a.x*b.x; acc[0][1] += a.x*b.y; acc[0][2] += a.x*b.z; acc[0][3] += a.x*b.w;
      acc[1][0] += a.y*b.x; acc[1][1] += a.y*b.y; acc[1][2] += a.y*b.z; acc[1][3] += a.y*b.w;
      acc[2][0] += a.z*b.x; acc[2][1] += a.z*b.y; acc[2][2] += a.z*b.z; acc[2][3] += a.z*b.w;
      acc[3][0] += a.w*b.x; acc[3][1] += a.w*b.y; acc[3][2] += a.w*b.z; acc[3][3] += a.w*b.w;
    }
    __syncthreads();
  }
  float4 bia = *(const float4*)&Wob[c0];
  #pragma unroll
  for (int r = 0; r < 4; ++r) {
    float4 o = make_float4(fmaxf(acc[r][0]+bia.x, 0.f), fmaxf(acc[r][1]+bia.y, 0.f),
                           fmaxf(acc[r][2]+bia.z, 0.f), fmaxf(acc[r][3]+bia.w, 0.f));
    *(float4*)&nh[(size_t)(m0 + r0 + r)*96 + c0] = o;
  }
}

// ---------------------------------------------------------------- k_pool2
__global__ __launch_bounds__(128) void k_pool2(const float* __restrict__ nh,
                                               float* __restrict__ goutb,
                                               float* __restrict__ headb,
                                               float* __restrict__ tailb) {
  int g = blockIdx.x, j = threadIdx.x;
  if (j >= 96) return;
  const float* base = nh + (size_t)g*NT*96;
  float s = 0.f;
  for (int n = 0; n < NT; ++n) s += base[(size_t)n*96 + j];
  goutb[g*96 + j] = s * (1.f/128.f);
  headb[g*96 + j] = base[j];
  tailb[g*96 + j] = base[96 + j];
}

// ---------------------------------------------------------------- k_path : XI-precomputed 3-step GRU
__global__ __launch_bounds__(128) void k_path(
    const float* __restrict__ XI, const int* __restrict__ in_rels,
    const int* __restrict__ labels, const float* __restrict__ pWhh,
    const float* __restrict__ pbhh, float* __restrict__ last) {
  __shared__ __align__(16) float wsh[96*32];
  __shared__ float bsh[96];
  __shared__ float hbuf[128*33];
  int tid = threadIdx.x;
  for (int i = tid; i < 96*32; i += 128) wsh[i] = pWhh[i];
  if (tid < 96) bsh[tid] = pbhh[tid];
  int p = blockIdx.x*128 + tid;
  int b = p >> 6, pp = p & 63;
  int rid0 = in_rels[b*1024 + (pp >> 3)];
  int rid1 = labels[b];
  int rid2 = in_rels[b*1024 + 8 + (pp & 7)];
  __syncthreads();
  float* hs = &hbuf[tid*33];
  {
    const float* xi = XI + rid0*96;
    #pragma unroll
    for (int gg = 0; gg < 32; ++gg) {
      float r = sigm(xi[gg] + bsh[gg]);
      float z = sigm(xi[32+gg] + bsh[32+gg]);
      float nn = tanhf(xi[64+gg] + r*bsh[64+gg]);
      hs[gg] = (1.f - z)*nn;
    }
  }
  float4 h4[8];
  #pragma unroll
  for (int q = 0; q < 8; ++q) h4[q] = make_float4(hs[4*q], hs[4*q+1], hs[4*q+2], hs[4*q+3]);
  for (int s = 0; s < 2; ++s) {
    const float* xi = XI + (s == 0 ? rid1 : rid2)*96;
    for (int gg = 0; gg < 32; ++gg) {
      float ar = bsh[gg], az = bsh[32+gg], an = bsh[64+gg];
      const float4* wr = (const float4*)&wsh[gg*32];
      const float4* wz = (const float4*)&wsh[(32+gg)*32];
      const float4* wn = (const float4*)&wsh[(64+gg)*32];
      #pragma unroll
      for (int q = 0; q < 8; ++q) {
        float4 hv = h4[q]; float4 w;
        w = wr[q]; ar += hv.x*w.x + hv.y*w.y + hv.z*w.z + hv.w*w.w;
        w = wz[q]; az += hv.x*w.x + hv.y*w.y + hv.z*w.z + hv.w*w.w;
        w = wn[q]; an += hv.x*w.x + hv.y*w.y + hv.z*w.z + hv.w*w.w;
      }
      float r = sigm(xi[gg] + ar);
      float z = sigm(xi[32+gg] + az);
      float nn = tanhf(xi[64+gg] + r*an);
      hs[gg] = (1.f - z)*nn + z*hs[gg];
    }
    #pragma unroll
    for (int q = 0; q < 8; ++q) h4[q] = make_float4(hs[4*q], hs[4*q+1], hs[4*q+2], hs[4*q+3]);
  }
  float* lp = last + (size_t)p*32;
  #pragma unroll
  for (int d = 0; d < 32; ++d) lp[d] = hs[d];
}

// ---------------------------------------------------------------- k_final
__global__ __launch_bounds__(64) void k_final(
    const float* __restrict__ last, const float* __restrict__ r3,
    const int* __restrict__ labels, const float* __restrict__ goutb,
    const float* __restrict__ headb, const float* __restrict__ tailb,
    const float* __restrict__ fcW, const float* __restrict__ fcb,
    float* __restrict__ out) {
  __shared__ float red[64*33];
  __shared__ float gpl[32];
  int b = blockIdx.x, lane = threadIdx.x;
  const float* rl = r3 + labels[b]*32;
  float l32[32];
  {
    const float4* lr = (const float4*)(last + (size_t)(b*64 + lane)*32);
    #pragma unroll
    for (int q = 0; q < 8; ++q) {
      float4 v = lr[q];
      l32[4*q+0]=v.x; l32[4*q+1]=v.y; l32[4*q+2]=v.z; l32[4*q+3]=v.w;
    }
  }
  float s = 0.f;
  #pragma unroll
  for (int d = 0; d < 32; ++d) s += l32[d]*rl[d];
  float mx = s;
  #pragma unroll
  for (int off = 32; off > 0; off >>= 1) mx = fmaxf(mx, __shfl_xor(mx, off));
  float e = __expf(s - mx);
  float den = e;
  #pragma unroll
  for (int off = 32; off > 0; off >>= 1) den += __shfl_xor(den, off);
  float att = e / den;
  #pragma unroll
  for (int d = 0; d < 32; ++d) red[lane*33 + d] = att*l32[d];
  __syncthreads();
  if (lane < 32) {
    float gp = 0.f;
    for (int p2 = 0; p2 < 64; ++p2) gp += red[p2*33 + lane];
    gpl[lane] = gp;
  }
  __syncthreads();
  float acc = 0.f;
  for (int i = lane; i < 352; i += 64) {
    float v;
    if (i < 96)       v = goutb[b*96 + i];
    else if (i < 192) v = headb[b*96 + (i-96)];
    else if (i < 288) v = tailb[b*96 + (i-192)];
    else if (i < 320) v = rl[i-288];
    else              v = gpl[i-320];
    acc += v*fcW[i];
  }
  #pragma unroll
  for (int off = 32; off > 0; off >>= 1) acc += __shfl_xor(acc, off);
  if (lane == 0) out[b] = acc + fcb[0];
}

// ---------------------------------------------------------------- launch
extern "C" void kernel_launch(void* const* d_in, const int* in_sizes, int n_in,
                              void* d_out, int out_size, void* d_ws, size_t ws_size,
                              hipStream_t stream) {
  const float* feat       = (const float*)d_in[0];
  const int*   out_rels   = (const int*)d_in[1];
  const int*   in_rels    = (const int*)d_in[2];
  const int*   r_label_nd = (const int*)d_in[3];
  const int*   src        = (const int*)d_in[4];
  const int*   dst        = (const int*)d_in[5];
  const int*   etype      = (const int*)d_in[6];
  const int*   rel_labels = (const int*)d_in[7];
  const float* rel_emb    = (const float*)d_in[8];
  const float* w2e_W      = (const float*)d_in[9];
  const float* w2e_b      = (const float*)d_in[10];
  const float* W_msg      = (const float*)d_in[11];
  const float* W_self     = (const float*)d_in[12];
  const float* b_gnn      = (const float*)d_in[13];
  const float* W_rel      = (const float*)d_in[14];
  const float* gru_bias   = (const float*)d_in[15];
  const float* Wih_f      = (const float*)d_in[16];
  const float* Whh_f      = (const float*)d_in[17];
  const float* bih_f      = (const float*)d_in[18];
  const float* bhh_f      = (const float*)d_in[19];
  const float* Wih_b      = (const float*)d_in[20];
  const float* Whh_b      = (const float*)d_in[21];
  const float* bih_b      = (const float*)d_in[22];
  const float* bhh_b      = (const float*)d_in[23];
  const float* Wo_W       = (const float*)d_in[24];
  const float* Wo_b       = (const float*)d_in[25];
  const float* pWih       = (const float*)d_in[26];
  const float* pWhh       = (const float*)d_in[27];
  const float* pbih       = (const float*)d_in[28];
  const float* pbhh       = (const float*)d_in[29];
  const float* fcW        = (const float*)d_in[30];
  const float* fcb        = (const float*)d_in[31];
  float* out = (float*)d_out;

  float* p = (float*)d_ws;
  float* hin   = p; p += (size_t)NNODE*32;
  float* R1    = p; p += (size_t)NNODE*192;
  float* repr  = R1;
  float* AT    = R1 + (size_t)NNODE*96;
  float* gruo  = R1;
  float* R2    = p; p += (size_t)NNODE*576;
  float* GI    = R2;
  float* AT2   = R2;
  float* nh    = R2 + (size_t)192*NNODE;
  int*   deg   = (int*)p; p += NNODE;
  float* r123  = p; p += 3*NREL*32;
  float* WT1   = p; p += 96*576;
  float* bcat  = p; p += 576;
  float* XI    = p; p += NREL*96;
  float* ghid0 = p; p += BB*96;
  float* goutb = p; p += BB*96;
  float* headb = p; p += BB*96;
  float* tailb = p; p += BB*96;
  float* lastb = p; p += (size_t)BB*64*32;

  hipMemsetAsync(deg, 0, NNODE*sizeof(int), stream);
  k_relchain<<<1, 256, 0, stream>>>(rel_emb, W_rel, r123);
  k_wt1<<<(96*576+255)/256, 256, 0, stream>>>(Wih_f, Wih_b, bih_f, bih_b, WT1, bcat);
  k_xi<<<NREL, 96, 0, stream>>>(r123 + 2*NREL*32, pWih, pbih, XI);
  k_deg<<<NEDGE/256, 256, 0, stream>>>(dst, deg);
  k_sem<<<NNODE/256, 256, 0, stream>>>(feat, out_rels, in_rels, r_label_nd,
                                       rel_emb, w2e_W, w2e_b, hin);
  for (int l = 0; l < 3; ++l) {
    const float* hsrc = (l == 0) ? hin : (repr + (l-1)*32);
    int hstride = (l == 0) ? 32 : 96;
    const float* r_l = (l == 0) ? rel_emb : (r123 + (l-1)*NREL*32);
    k_gnn<<<BB, 512, 0, stream>>>(hsrc, hstride, r_l, src, dst, etype, deg,
                                  W_msg + l*1024, W_self + l*1024, b_gnn + l*32,
                                  repr, l*32);
  }
  k_prep1<<<BB, 256, 0, stream>>>(repr, gru_bias, AT, ghid0);
  k_gemm1<<<dim3(9, 512), 256, 0, stream>>>(AT, WT1, bcat, GI);
  k_gru<<<256, 576, 0, stream>>>(Whh_f, bhh_f, Whh_b, bhh_b, GI, ghid0, gruo);
  k_prep2<<<dim3(BB, 2), 256, 0, stream>>>(gruo, AT2);
  k_gemm2<<<1024, 384, 0, stream>>>(AT2, Wo_W, Wo_b, nh);
  k_pool2<<<BB, 128, 0, stream>>>(nh, goutb, headb, tailb);
  k_path<<<256, 128, 0, stream>>>(XI, in_rels, rel_labels, pWhh, pbhh, lastb);
  k_final<<<BB, 64, 0, stream>>>(lastb, r123 + 2*NREL*32, rel_labels,
                                 goutb, headb, tailb, fcW, fcb, out);
}

// Round 8
// 1062.170 us; speedup vs baseline: 2.5113x; 1.0574x over previous
//
#include <hip/hip_runtime.h>
#include <math.h>

#define BB 512
#define NT 128
#define NREL 201
#define NNODE (BB*NT)
#define NEDGE (NNODE*16)

typedef float f32x4 __attribute__((ext_vector_type(4)));

__device__ __forceinline__ float sigm(float x) { return 1.f/(1.f + __expf(-x)); }

// ---------------------------------------------------------------- k_rel2 : per-row rel chain + XI (201 blocks x 96)
__global__ __launch_bounds__(96) void k_rel2(const float* __restrict__ rel_emb,
                                             const float* __restrict__ W_rel,
                                             const float* __restrict__ pWih,
                                             const float* __restrict__ pbih,
                                             float* __restrict__ r123,
                                             float* __restrict__ XI) {
  __shared__ float ra[32], rb[32];
  int r = blockIdx.x, tid = threadIdx.x;
  if (tid < 32) ra[tid] = rel_emb[r*32 + tid];
  __syncthreads();
  if (tid < 32) {
    float s = 0.f;
    #pragma unroll
    for (int d = 0; d < 32; ++d) s += ra[d]*W_rel[d*32 + tid];
    rb[tid] = s; r123[0*NREL*32 + r*32 + tid] = s;
  }
  __syncthreads();
  if (tid < 32) {
    float s = 0.f;
    #pragma unroll
    for (int d = 0; d < 32; ++d) s += rb[d]*W_rel[1024 + d*32 + tid];
    ra[tid] = s; r123[1*NREL*32 + r*32 + tid] = s;
  }
  __syncthreads();
  if (tid < 32) {
    float s = 0.f;
    #pragma unroll
    for (int d = 0; d < 32; ++d) s += ra[d]*W_rel[2048 + d*32 + tid];
    rb[tid] = s; r123[2*NREL*32 + r*32 + tid] = s;
  }
  __syncthreads();
  float s = pbih[tid];
  #pragma unroll
  for (int d = 0; d < 32; ++d) s += rb[d]*pWih[tid*32 + d];
  XI[r*96 + tid] = s;
}

// ---------------------------------------------------------------- k_wt1 : WT1[96][576] = [Wih_f;Wih_b]^T ; bcat
__global__ __launch_bounds__(256) void k_wt1(const float* __restrict__ Wih_f,
                                             const float* __restrict__ Wih_b,
                                             const float* __restrict__ bih_f,
                                             const float* __restrict__ bih_b,
                                             float* __restrict__ WT1,
                                             float* __restrict__ bcat) {
  int i = blockIdx.x*256 + threadIdx.x;
  if (i < 96*576) {
    int k = i / 576, j = i - k*576;
    WT1[i] = (j < 288) ? Wih_f[j*96 + k] : Wih_b[(j-288)*96 + k];
  }
  if (i < 576) bcat[i] = (i < 288) ? bih_f[i] : bih_b[i-288];
}

// ---------------------------------------------------------------- k_deg
__global__ void k_deg(const int* __restrict__ dst, int* __restrict__ deg) {
  int e = blockIdx.x*256 + threadIdx.x;
  if (e < NEDGE) atomicAdd(&deg[dst[e]], 1);
}

// ---------------------------------------------------------------- k_sem
__device__ __forceinline__ void sem_att(const float* __restrict__ rel_emb,
                                        const int rels[8], const float tgt[32],
                                        float out[32]) {
  float dots[8]; float mx = -1e30f;
  #pragma unroll
  for (int k = 0; k < 8; ++k) {
    const float4* er = (const float4*)(rel_emb + rels[k]*32);
    float s = 0.f;
    #pragma unroll
    for (int q = 0; q < 8; ++q) {
      float4 v = er[q];
      s += v.x*tgt[4*q+0] + v.y*tgt[4*q+1] + v.z*tgt[4*q+2] + v.w*tgt[4*q+3];
    }
    dots[k] = s; mx = fmaxf(mx, s);
  }
  float den = 0.f;
  #pragma unroll
  for (int k = 0; k < 8; ++k) { float e = __expf(dots[k]-mx); dots[k] = e; den += e; }
  float inv = 1.f/den;
  #pragma unroll
  for (int d = 0; d < 32; ++d) out[d] = 0.f;
  #pragma unroll
  for (int k = 0; k < 8; ++k) {
    const float4* er = (const float4*)(rel_emb + rels[k]*32);
    float a = dots[k]*inv;
    #pragma unroll
    for (int q = 0; q < 8; ++q) {
      float4 v = er[q];
      out[4*q+0] += a*v.x; out[4*q+1] += a*v.y; out[4*q+2] += a*v.z; out[4*q+3] += a*v.w;
    }
  }
}

__global__ __launch_bounds__(256) void k_sem(
    const float* __restrict__ feat, const int* __restrict__ out_rels,
    const int* __restrict__ in_rels, const int* __restrict__ r_label_node,
    const float* __restrict__ rel_emb, const float* __restrict__ W,
    const float* __restrict__ bias, float* __restrict__ hin) {
  int n = blockIdx.x*256 + threadIdx.x;
  float tgt[32];
  {
    const float4* tr = (const float4*)(rel_emb + r_label_node[n]*32);
    #pragma unroll
    for (int q = 0; q < 8; ++q) {
      float4 v = tr[q];
      tgt[4*q+0]=v.x; tgt[4*q+1]=v.y; tgt[4*q+2]=v.z; tgt[4*q+3]=v.w;
    }
  }
  int ro[8], ri[8];
  #pragma unroll
  for (int k = 0; k < 8; ++k) { ro[k] = out_rels[n*8+k]; ri[k] = in_rels[n*8+k]; }
  float osem[32], isem[32];
  sem_att(rel_emb, ro, tgt, osem);
  sem_att(rel_emb, ri, tgt, isem);
  const float4* fr = (const float4*)(feat + (size_t)n*16);
  float4* ho = (float4*)(hin + (size_t)n*32);
  #pragma unroll
  for (int q = 0; q < 4; ++q) ho[q] = fr[q];
  #pragma unroll
  for (int j = 0; j < 16; ++j) {
    float s = bias[j];
    #pragma unroll
    for (int d = 0; d < 32; ++d) s += osem[d]*W[d*16+j] + isem[d]*W[(32+d)*16+j];
    hin[(size_t)n*32 + 16 + j] = sigm(s);
  }
}

// ---------------------------------------------------------------- k_gnn : atomic-agg, AT col-major output (in-LDS transpose)
__global__ __launch_bounds__(512) void k_gnn(
    const float* __restrict__ ATin, const float* __restrict__ hin, int layer,
    const float* __restrict__ r_l,
    const int* __restrict__ src, const int* __restrict__ dst, const int* __restrict__ etype,
    const int* __restrict__ deg, const float* __restrict__ Wm, const float* __restrict__ Ws,
    const float* __restrict__ bl, float* __restrict__ AT, int ofs) {
  __shared__ __align__(16) float hl[NT*36];   // padded stride 36 (16B aligned, conflict-free reads)
  __shared__ __align__(16) float agg[NT*32];
  __shared__ float rl[NREL*32];
  __shared__ int epk[2048];
  int g = blockIdx.x;
  int tid = threadIdx.x;
  if (layer == 0) {
    for (int i = tid; i < NT*32; i += 512) {
      int row = i >> 5, col = i & 31;
      hl[row*36 + col] = hin[(size_t)(g*NT + row)*32 + col];
    }
  } else {
    for (int i = tid; i < NT*32; i += 512) {
      int col = i >> 7, row = i & 127;
      hl[row*36 + col] = ATin[(size_t)((layer-1)*32 + col)*NNODE + g*NT + row];
    }
  }
  for (int i = tid; i < NT*32; i += 512) agg[i] = 0.f;
  for (int i = tid; i < NREL*32; i += 512) rl[i] = r_l[i];
  for (int i = tid; i < 2048; i += 512) {
    int e = g*2048 + i;
    epk[i] = ((src[e] - g*NT) << 15) | ((dst[e] - g*NT) << 8) | etype[e];
  }
  __syncthreads();
  {
    int d = tid & 31, grp = tid >> 5;   // 16 groups of 32 lanes, one edge per group-iter
    for (int i = grp; i < 2048; i += 16) {
      int pk = epk[i];
      int et = pk & 255, dl = (pk >> 8) & 127, sl = pk >> 15;
      atomicAdd(&agg[dl*32 + d], hl[sl*36 + d] * rl[et*32 + d]);
    }
  }
  __syncthreads();
  int j = tid & 31;
  float wm[32], ws[32];
  #pragma unroll
  for (int dd = 0; dd < 32; ++dd) { wm[dd] = Wm[dd*32+j]; ws[dd] = Ws[dd*32+j]; }
  float bj = bl[j];
  int nbase = tid >> 5;
  float res[8];
  for (int k2 = 0; k2 < 8; ++k2) {
    int n = nbase + k2*16;
    int dv = deg[g*NT + n];
    float invd = 1.f / (float)(dv > 0 ? dv : 1);
    const float4* a4 = (const float4*)&agg[n*32];
    const float4* h4 = (const float4*)&hl[n*36];
    float sa = 0.f, sh = 0.f;
    #pragma unroll
    for (int q = 0; q < 8; ++q) {
      float4 av = a4[q], hv = h4[q];
      sa += av.x*wm[4*q+0] + av.y*wm[4*q+1] + av.z*wm[4*q+2] + av.w*wm[4*q+3];
      sh += hv.x*ws[4*q+0] + hv.y*ws[4*q+1] + hv.z*ws[4*q+2] + hv.w*ws[4*q+3];
    }
    res[k2] = fmaxf(bj + invd*sa + sh, 0.f);
  }
  __syncthreads();                  // all hl/agg reads done
  float* t = hl;                    // reuse as transpose buffer, stride 33
  for (int k2 = 0; k2 < 8; ++k2)
    t[(nbase + k2*16)*33 + j] = res[k2];
  __syncthreads();
  for (int pass = 0; pass < 8; ++pass) {
    int col = (pass << 2) + (tid >> 7);
    int row = tid & 127;
    AT[(size_t)(ofs + col)*NNODE + g*NT + row] = t[row*33 + col];
  }
}

// ---------------------------------------------------------------- k_h0 : ghid0 = colmax over nodes (AT col-major)
__global__ __launch_bounds__(96) void k_h0(const float* __restrict__ AT,
                                           float* __restrict__ ghid0) {
  int g = blockIdx.x, j = threadIdx.x;
  const float4* col = (const float4*)(AT + (size_t)j*NNODE + g*NT);
  float4 m4 = col[0];
  for (int q = 1; q < 32; ++q) {
    float4 v = col[q];
    m4.x = fmaxf(m4.x, v.x); m4.y = fmaxf(m4.y, v.y);
    m4.z = fmaxf(m4.z, v.z); m4.w = fmaxf(m4.w, v.w);
  }
  ghid0[g*96 + j] = fmaxf(fmaxf(m4.x, m4.y), fmaxf(m4.z, m4.w));
}

// ---------------------------------------------------------------- k_gemm1 : GI = relu(AT^T + gbias) @ WT1 + bcat
__global__ __launch_bounds__(256) void k_gemm1(
    const float* __restrict__ AT, const float* __restrict__ gbias,
    const float* __restrict__ WT1, const float* __restrict__ bcat,
    float* __restrict__ GI) {
  __shared__ __align__(16) float As[96*128];
  __shared__ __align__(16) float Bs[96*64];
  int nb = blockIdx.x;
  int mb = blockIdx.y;
  int m0 = mb*128, n0 = nb*64;
  int tid = threadIdx.x;
  for (int i = tid; i < 3072; i += 256) {
    int r = i >> 5, c4 = i & 31;
    float4 v = *(const float4*)&AT[(size_t)r*NNODE + m0 + c4*4];
    float b = gbias[r];
    float4 o = make_float4(fmaxf(v.x+b,0.f), fmaxf(v.y+b,0.f), fmaxf(v.z+b,0.f), fmaxf(v.w+b,0.f));
    *(float4*)&As[r*128 + c4*4] = o;
  }
  for (int i = tid; i < 1536; i += 256) {
    int r = i >> 4, c4 = i & 15;
    *(float4*)&Bs[r*64 + c4*4] = *(const float4*)&WT1[r*576 + n0 + c4*4];
  }
  __syncthreads();
  int tc = tid & 15, tr = tid >> 4;
  int r0 = tr*8, c0 = tc*4;
  float acc[8][4] = {};
  #pragma unroll 4
  for (int k = 0; k < 96; ++k) {
    float4 a0 = *(float4*)&As[k*128 + r0];
    float4 a1 = *(float4*)&As[k*128 + r0 + 4];
    float4 b  = *(float4*)&Bs[k*64 + c0];
    acc[0][0]+=a0.x*b.x; acc[0][1]+=a0.x*b.y; acc[0][2]+=a0.x*b.z; acc[0][3]+=a0.x*b.w;
    acc[1][0]+=a0.y*b.x; acc[1][1]+=a0.y*b.y; acc[1][2]+=a0.y*b.z; acc[1][3]+=a0.y*b.w;
    acc[2][0]+=a0.z*b.x; acc[2][1]+=a0.z*b.y; acc[2][2]+=a0.z*b.z; acc[2][3]+=a0.z*b.w;
    acc[3][0]+=a0.w*b.x; acc[3][1]+=a0.w*b.y; acc[3][2]+=a0.w*b.z; acc[3][3]+=a0.w*b.w;
    acc[4][0]+=a1.x*b.x; acc[4][1]+=a1.x*b.y; acc[4][2]+=a1.x*b.z; acc[4][3]+=a1.x*b.w;
    acc[5][0]+=a1.y*b.x; acc[5][1]+=a1.y*b.y; acc[5][2]+=a1.y*b.z; acc[5][3]+=a1.y*b.w;
    acc[6][0]+=a1.z*b.x; acc[6][1]+=a1.z*b.y; acc[6][2]+=a1.z*b.z; acc[6][3]+=a1.z*b.w;
    acc[7][0]+=a1.w*b.x; acc[7][1]+=a1.w*b.y; acc[7][2]+=a1.w*b.z; acc[7][3]+=a1.w*b.w;
  }
  float4 bia = *(const float4*)&bcat[n0 + c0];
  #pragma unroll
  for (int r = 0; r < 8; ++r) {
    f32x4 o = { acc[r][0]+bia.x, acc[r][1]+bia.y, acc[r][2]+bia.z, acc[r][3]+bia.w };
    __builtin_nontemporal_store(o, (f32x4*)&GI[(size_t)(m0 + r0 + r)*576 + n0 + c0]);
  }
}

// ---------------------------------------------------------------- k_gru : S=4, writes relu'd AT2 (col-major) directly
#define PIN4(v) asm volatile("" : "+v"(v.x), "+v"(v.y), "+v"(v.z), "+v"(v.w))
#define DOT16(acc, W0,W1,W2,W3, X0,X1,X2,X3) \
  acc += W0.x*X0.x + W0.y*X0.y + W0.z*X0.z + W0.w*X0.w \
       + W1.x*X1.x + W1.y*X1.y + W1.z*X1.z + W1.w*X1.w \
       + W2.x*X2.x + W2.y*X2.y + W2.z*X2.z + W2.w*X2.w \
       + W3.x*X3.x + W3.y*X3.y + W3.z*X3.z + W3.w*X3.w

__global__ __launch_bounds__(576, 1) void k_gru(
    const float* __restrict__ Whh_f, const float* __restrict__ bhh_f,
    const float* __restrict__ Whh_b, const float* __restrict__ bhh_b,
    const float* __restrict__ GI, const float* __restrict__ ghid0,
    float* __restrict__ AT2) {
  __shared__ __align__(16) float h_lds[4][96];
  __shared__ float part[4][288][9];
  int bx = blockIdx.x;                  // 256 blocks
  int dir = bx >> 7;
  int gbase = (bx & 127) * 4;
  int tid = threadIdx.x;
  int c = tid % 96;
  int p = tid / 96;
  bool fin = (tid < 384);
  int s = p;

  const float* Whh = dir ? Whh_b : Whh_f;
  const float4* wr0 = (const float4*)(Whh + (size_t)c*96 + p*16);
  const float4* wr1 = (const float4*)(Whh + (size_t)(96+c)*96 + p*16);
  const float4* wr2 = (const float4*)(Whh + (size_t)(192+c)*96 + p*16);
  float4 wa0=wr0[0], wa1=wr0[1], wa2=wr0[2], wa3=wr0[3];
  float4 wb0=wr1[0], wb1=wr1[1], wb2=wr1[2], wb3=wr1[3];
  float4 wc0=wr2[0], wc1=wr2[1], wc2=wr2[2], wc3=wr2[3];

  float bh0=0.f, bh1=0.f, bh2=0.f;
  float gi0=0.f, gi1=0.f, gi2=0.f;
  if (fin) {
    const float* bhh = dir ? bhh_b : bhh_f;
    bh0 = bhh[c]; bh1 = bhh[96+c]; bh2 = bhh[192+c];
    h_lds[s][c] = ghid0[(gbase+s)*96 + c];
    int pos0 = dir ? 127 : 0;
    const float* g = GI + (size_t)((gbase+s)*128 + pos0)*576 + dir*288;
    gi0 = g[c]; gi1 = g[96+c]; gi2 = g[192+c];
  }
  __syncthreads();
  for (int t = 0; t < 128; ++t) {
    PIN4(wa0); PIN4(wa1); PIN4(wa2); PIN4(wa3);
    PIN4(wb0); PIN4(wb1); PIN4(wb2); PIN4(wb3);
    PIN4(wc0); PIN4(wc1); PIN4(wc2); PIN4(wc3);
    int pos = dir ? (127-t) : t;
    float gn0=0.f, gn1=0.f, gn2=0.f;
    if (fin && t < 127) {
      int posn = dir ? (126-t) : (t+1);
      const float* g = GI + (size_t)((gbase+s)*128 + posn)*576 + dir*288;
      gn0 = g[c]; gn1 = g[96+c]; gn2 = g[192+c];
    }
    #pragma unroll
    for (int s4 = 0; s4 < 4; ++s4) {
      const float4* hh = (const float4*)&h_lds[s4][p*16];
      float4 x0=hh[0], x1=hh[1], x2=hh[2], x3=hh[3];
      float q0=0.f, q1=0.f, q2=0.f;
      DOT16(q0, wa0,wa1,wa2,wa3, x0,x1,x2,x3);
      DOT16(q1, wb0,wb1,wb2,wb3, x0,x1,x2,x3);
      DOT16(q2, wc0,wc1,wc2,wc3, x0,x1,x2,x3);
      part[s4][c][p]     = q0;
      part[s4][96+c][p]  = q1;
      part[s4][192+c][p] = q2;
    }
    __syncthreads();
    if (fin) {
      const float* pr = part[s][c];
      const float* pz = part[s][96+c];
      const float* pn = part[s][192+c];
      float ghr = pr[0]+pr[1]+pr[2]+pr[3]+pr[4]+pr[5] + bh0;
      float ghz = pz[0]+pz[1]+pz[2]+pz[3]+pz[4]+pz[5] + bh1;
      float ghn = pn[0]+pn[1]+pn[2]+pn[3]+pn[4]+pn[5] + bh2;
      float r  = sigm(gi0 + ghr);
      float z  = sigm(gi1 + ghz);
      float nn = tanhf(gi2 + r*ghn);
      float hv = (1.f - z)*nn + z*h_lds[s][c];
      h_lds[s][c] = hv;
      AT2[(size_t)(dir*96 + c)*NNODE + (gbase+s)*128 + pos] = fmaxf(hv, 0.f);
      gi0 = gn0; gi1 = gn1; gi2 = gn2;
    }
    __syncthreads();
  }
}

// ---------------------------------------------------------------- k_gemm2p : fused Wo-GEMM + pooling (no nh materialization)
__global__ __launch_bounds__(384) void k_gemm2p(
    const float* __restrict__ AT2, const float* __restrict__ WoW,
    const float* __restrict__ Wob, float* __restrict__ goutb,
    float* __restrict__ headb, float* __restrict__ tailb) {
  __shared__ __align__(16) float As[96*64];
  __shared__ __align__(16) float Bs[96*96];
  __shared__ float red[16][100];
  int m0 = blockIdx.x*64;
  int g = m0 >> 7;
  int tid = threadIdx.x;
  int tc = tid % 24, tr = tid / 24;
  int r0 = tr*4, c0 = tc*4;
  float acc[4][4] = {};
  for (int kc = 0; kc < 2; ++kc) {
    for (int i = tid; i < 1536; i += 384) {
      int r = i >> 4, c4 = i & 15;
      *(float4*)&As[r*64 + c4*4] = *(const float4*)&AT2[(size_t)(kc*96 + r)*NNODE + m0 + c4*4];
    }
    for (int i = tid; i < 2304; i += 384) {
      int r = i / 24, c4 = i % 24;
      *(float4*)&Bs[r*96 + c4*4] = *(const float4*)&WoW[(size_t)(kc*96 + r)*96 + c4*4];
    }
    __syncthreads();
    #pragma unroll 8
    for (int k = 0; k < 96; ++k) {
      float4 a = *(float4*)&As[k*64 + r0];
      float4 b = *(float4*)&Bs[k*96 + c0];
      acc[0][0] += a.x*b.x; acc[0][1] += a.x*b.y; acc[0][2] += a.x*b.z; acc[0][3] += a.x*b.w;
      acc[1][0] += a.y*b.x; acc[1][1] += a.y*b.y; acc[1][2] += a.y*b.z; acc[1][3] += a.y*b.w;
      acc[2][0] += a.z*b.x; acc[2][1] += a.z*b.y; acc[2][2] += a.z*b.z; acc[2][3] += a.z*b.w;
      acc[3][0] += a.w*b.x; acc[3][1] += a.w*b.y; acc[3][2] += a.w*b.z; acc[3][3] += a.w*b.w;
    }
    __syncthreads();
  }
  float4 bia = *(const float4*)&Wob[c0];
  float nv[4][4];
  #pragma unroll
  for (int r = 0; r < 4; ++r) {
    nv[r][0] = fmaxf(acc[r][0]+bia.x, 0.f);
    nv[r][1] = fmaxf(acc[r][1]+bia.y, 0.f);
    nv[r][2] = fmaxf(acc[r][2]+bia.z, 0.f);
    nv[r][3] = fmaxf(acc[r][3]+bia.w, 0.f);
  }
  #pragma unroll
  for (int cj = 0; cj < 4; ++cj)
    red[tr][c0+cj] = nv[0][cj] + nv[1][cj] + nv[2][cj] + nv[3][cj];
  if ((m0 & 127) == 0 && tr == 0) {
    #pragma unroll
    for (int cj = 0; cj < 4; ++cj) {
      headb[g*96 + c0 + cj] = nv[0][cj];
      tailb[g*96 + c0 + cj] = nv[1][cj];
    }
  }
  __syncthreads();
  if (tid < 96) {
    float s = 0.f;
    #pragma unroll
    for (int t2 = 0; t2 < 16; ++t2) s += red[t2][tid];
    atomicAdd(&goutb[g*96 + tid], s);
  }
}

// ---------------------------------------------------------------- k_path : XI-precomputed 3-step GRU
__global__ __launch_bounds__(128) void k_path(
    const float* __restrict__ XI, const int* __restrict__ in_rels,
    const int* __restrict__ labels, const float* __restrict__ pWhh,
    const float* __restrict__ pbhh, float* __restrict__ last) {
  __shared__ __align__(16) float wsh[96*32];
  __shared__ float bsh[96];
  __shared__ float hbuf[128*33];
  int tid = threadIdx.x;
  for (int i = tid; i < 96*32; i += 128) wsh[i] = pWhh[i];
  if (tid < 96) bsh[tid] = pbhh[tid];
  int p = blockIdx.x*128 + tid;
  int b = p >> 6, pp = p & 63;
  int rid0 = in_rels[b*1024 + (pp >> 3)];
  int rid1 = labels[b];
  int rid2 = in_rels[b*1024 + 8 + (pp & 7)];
  __syncthreads();
  float* hs = &hbuf[tid*33];
  {
    const float* xi = XI + rid0*96;
    #pragma unroll
    for (int gg = 0; gg < 32; ++gg) {
      float r = sigm(xi[gg] + bsh[gg]);
      float z = sigm(xi[32+gg] + bsh[32+gg]);
      float nn = tanhf(xi[64+gg] + r*bsh[64+gg]);
      hs[gg] = (1.f - z)*nn;
    }
  }
  float4 h4[8];
  #pragma unroll
  for (int q = 0; q < 8; ++q) h4[q] = make_float4(hs[4*q], hs[4*q+1], hs[4*q+2], hs[4*q+3]);
  for (int s = 0; s < 2; ++s) {
    const float* xi = XI + (s == 0 ? rid1 : rid2)*96;
    for (int gg = 0; gg < 32; ++gg) {
      float ar = bsh[gg], az = bsh[32+gg], an = bsh[64+gg];
      const float4* wr = (const float4*)&wsh[gg*32];
      const float4* wz = (const float4*)&wsh[(32+gg)*32];
      const float4* wn = (const float4*)&wsh[(64+gg)*32];
      #pragma unroll
      for (int q = 0; q < 8; ++q) {
        float4 hv = h4[q]; float4 w;
        w = wr[q]; ar += hv.x*w.x + hv.y*w.y + hv.z*w.z + hv.w*w.w;
        w = wz[q]; az += hv.x*w.x + hv.y*w.y + hv.z*w.z + hv.w*w.w;
        w = wn[q]; an += hv.x*w.x + hv.y*w.y + hv.z*w.z + hv.w*w.w;
      }
      float r = sigm(xi[gg] + ar);
      float z = sigm(xi[32+gg] + az);
      float nn = tanhf(xi[64+gg] + r*an);
      hs[gg] = (1.f - z)*nn + z*hs[gg];
    }
    #pragma unroll
    for (int q = 0; q < 8; ++q) h4[q] = make_float4(hs[4*q], hs[4*q+1], hs[4*q+2], hs[4*q+3]);
  }
  float* lp = last + (size_t)p*32;
  #pragma unroll
  for (int d = 0; d < 32; ++d) lp[d] = hs[d];
}

// ---------------------------------------------------------------- k_final
__global__ __launch_bounds__(64) void k_final(
    const float* __restrict__ last, const float* __restrict__ r3,
    const int* __restrict__ labels, const float* __restrict__ goutb,
    const float* __restrict__ headb, const float* __restrict__ tailb,
    const float* __restrict__ fcW, const float* __restrict__ fcb,
    float* __restrict__ out) {
  __shared__ float red[64*33];
  __shared__ float gpl[32];
  int b = blockIdx.x, lane = threadIdx.x;
  const float* rl = r3 + labels[b]*32;
  float l32[32];
  {
    const float4* lr = (const float4*)(last + (size_t)(b*64 + lane)*32);
    #pragma unroll
    for (int q = 0; q < 8; ++q) {
      float4 v = lr[q];
      l32[4*q+0]=v.x; l32[4*q+1]=v.y; l32[4*q+2]=v.z; l32[4*q+3]=v.w;
    }
  }
  float s = 0.f;
  #pragma unroll
  for (int d = 0; d < 32; ++d) s += l32[d]*rl[d];
  float mx = s;
  #pragma unroll
  for (int off = 32; off > 0; off >>= 1) mx = fmaxf(mx, __shfl_xor(mx, off));
  float e = __expf(s - mx);
  float den = e;
  #pragma unroll
  for (int off = 32; off > 0; off >>= 1) den += __shfl_xor(den, off);
  float att = e / den;
  #pragma unroll
  for (int d = 0; d < 32; ++d) red[lane*33 + d] = att*l32[d];
  __syncthreads();
  if (lane < 32) {
    float gp = 0.f;
    for (int p2 = 0; p2 < 64; ++p2) gp += red[p2*33 + lane];
    gpl[lane] = gp;
  }
  __syncthreads();
  float acc = 0.f;
  for (int i = lane; i < 352; i += 64) {
    float v;
    if (i < 96)       v = goutb[b*96 + i] * 0.0078125f;   // /128
    else if (i < 192) v = headb[b*96 + (i-96)];
    else if (i < 288) v = tailb[b*96 + (i-192)];
    else if (i < 320) v = rl[i-288];
    else              v = gpl[i-320];
    acc += v*fcW[i];
  }
  #pragma unroll
  for (int off = 32; off > 0; off >>= 1) acc += __shfl_xor(acc, off);
  if (lane == 0) out[b] = acc + fcb[0];
}

// ---------------------------------------------------------------- launch
extern "C" void kernel_launch(void* const* d_in, const int* in_sizes, int n_in,
                              void* d_out, int out_size, void* d_ws, size_t ws_size,
                              hipStream_t stream) {
  const float* feat       = (const float*)d_in[0];
  const int*   out_rels   = (const int*)d_in[1];
  const int*   in_rels    = (const int*)d_in[2];
  const int*   r_label_nd = (const int*)d_in[3];
  const int*   src        = (const int*)d_in[4];
  const int*   dst        = (const int*)d_in[5];
  const int*   etype      = (const int*)d_in[6];
  const int*   rel_labels = (const int*)d_in[7];
  const float* rel_emb    = (const float*)d_in[8];
  const float* w2e_W      = (const float*)d_in[9];
  const float* w2e_b      = (const float*)d_in[10];
  const float* W_msg      = (const float*)d_in[11];
  const float* W_self     = (const float*)d_in[12];
  const float* b_gnn      = (const float*)d_in[13];
  const float* W_rel      = (const float*)d_in[14];
  const float* gru_bias   = (const float*)d_in[15];
  const float* Wih_f      = (const float*)d_in[16];
  const float* Whh_f      = (const float*)d_in[17];
  const float* bih_f      = (const float*)d_in[18];
  const float* bhh_f      = (const float*)d_in[19];
  const float* Wih_b      = (const float*)d_in[20];
  const float* Whh_b      = (const float*)d_in[21];
  const float* bih_b      = (const float*)d_in[22];
  const float* bhh_b      = (const float*)d_in[23];
  const float* Wo_W       = (const float*)d_in[24];
  const float* Wo_b       = (const float*)d_in[25];
  const float* pWih       = (const float*)d_in[26];
  const float* pWhh       = (const float*)d_in[27];
  const float* pbih       = (const float*)d_in[28];
  const float* pbhh       = (const float*)d_in[29];
  const float* fcW        = (const float*)d_in[30];
  const float* fcb        = (const float*)d_in[31];
  float* out = (float*)d_out;

  float* p = (float*)d_ws;
  float* hin   = p; p += (size_t)NNODE*32;
  float* R1    = p; p += (size_t)NNODE*192;   // AT (96xN) during GNN/gemm1; AT2 (192xN) after
  float* AT    = R1;
  float* AT2   = R1;
  float* R2    = p; p += (size_t)NNODE*576;   // GI
  float* GI    = R2;
  int*   deg   = (int*)p; p += NNODE;
  float* r123  = p; p += 3*NREL*32;
  float* WT1   = p; p += 96*576;
  float* bcat  = p; p += 576;
  float* XI    = p; p += NREL*96;
  float* ghid0 = p; p += BB*96;
  float* goutb = p; p += BB*96;
  float* headb = p; p += BB*96;
  float* tailb = p; p += BB*96;
  float* lastb = p; p += (size_t)BB*64*32;

  hipMemsetAsync(deg, 0, NNODE*sizeof(int), stream);
  hipMemsetAsync(goutb, 0, BB*96*sizeof(float), stream);
  k_rel2<<<NREL, 96, 0, stream>>>(rel_emb, W_rel, pWih, pbih, r123, XI);
  k_wt1<<<(96*576+255)/256, 256, 0, stream>>>(Wih_f, Wih_b, bih_f, bih_b, WT1, bcat);
  k_deg<<<NEDGE/256, 256, 0, stream>>>(dst, deg);
  k_sem<<<NNODE/256, 256, 0, stream>>>(feat, out_rels, in_rels, r_label_nd,
                                       rel_emb, w2e_W, w2e_b, hin);
  for (int l = 0; l < 3; ++l) {
    const float* r_l = (l == 0) ? rel_emb : (r123 + (l-1)*NREL*32);
    k_gnn<<<BB, 512, 0, stream>>>(AT, hin, l, r_l, src, dst, etype, deg,
                                  W_msg + l*1024, W_self + l*1024, b_gnn + l*32,
                                  AT, l*32);
  }
  k_h0<<<BB, 96, 0, stream>>>(AT, ghid0);
  k_gemm1<<<dim3(9, 512), 256, 0, stream>>>(AT, gru_bias, WT1, bcat, GI);
  k_gru<<<256, 576, 0, stream>>>(Whh_f, bhh_f, Whh_b, bhh_b, GI, ghid0, AT2);
  k_gemm2p<<<1024, 384, 0, stream>>>(AT2, Wo_W, Wo_b, goutb, headb, tailb);
  k_path<<<256, 128, 0, stream>>>(XI, in_rels, rel_labels, pWhh, pbhh, lastb);
  k_final<<<BB, 64, 0, stream>>>(lastb, r123 + 2*NREL*32, rel_labels,
                                 goutb, headb, tailb, fcW, fcb, out);
}

// Round 9
// 533.908 us; speedup vs baseline: 4.9959x; 1.9894x over previous
//
#include <hip/hip_runtime.h>
#include <math.h>

#define BB 512
#define NT 128
#define NREL 201
#define NNODE (BB*NT)
#define NEDGE (NNODE*16)

typedef float f32x4 __attribute__((ext_vector_type(4)));

__device__ __forceinline__ float sigm(float x) { return 1.f/(1.f + __expf(-x)); }

// ---------------------------------------------------------------- k_rel2 : per-row rel chain + XI (201 blocks x 96)
__global__ __launch_bounds__(96) void k_rel2(const float* __restrict__ rel_emb,
                                             const float* __restrict__ W_rel,
                                             const float* __restrict__ pWih,
                                             const float* __restrict__ pbih,
                                             float* __restrict__ r123,
                                             float* __restrict__ XI) {
  __shared__ float ra[32], rb[32];
  int r = blockIdx.x, tid = threadIdx.x;
  if (tid < 32) ra[tid] = rel_emb[r*32 + tid];
  __syncthreads();
  if (tid < 32) {
    float s = 0.f;
    #pragma unroll
    for (int d = 0; d < 32; ++d) s += ra[d]*W_rel[d*32 + tid];
    rb[tid] = s; r123[0*NREL*32 + r*32 + tid] = s;
  }
  __syncthreads();
  if (tid < 32) {
    float s = 0.f;
    #pragma unroll
    for (int d = 0; d < 32; ++d) s += rb[d]*W_rel[1024 + d*32 + tid];
    ra[tid] = s; r123[1*NREL*32 + r*32 + tid] = s;
  }
  __syncthreads();
  if (tid < 32) {
    float s = 0.f;
    #pragma unroll
    for (int d = 0; d < 32; ++d) s += ra[d]*W_rel[2048 + d*32 + tid];
    rb[tid] = s; r123[2*NREL*32 + r*32 + tid] = s;
  }
  __syncthreads();
  float s = pbih[tid];
  #pragma unroll
  for (int d = 0; d < 32; ++d) s += rb[d]*pWih[tid*32 + d];
  XI[r*96 + tid] = s;
}

// ---------------------------------------------------------------- k_wt1 : WT1[96][576] = [Wih_f;Wih_b]^T ; bcat
__global__ __launch_bounds__(256) void k_wt1(const float* __restrict__ Wih_f,
                                             const float* __restrict__ Wih_b,
                                             const float* __restrict__ bih_f,
                                             const float* __restrict__ bih_b,
                                             float* __restrict__ WT1,
                                             float* __restrict__ bcat) {
  int i = blockIdx.x*256 + threadIdx.x;
  if (i < 96*576) {
    int k = i / 576, j = i - k*576;
    WT1[i] = (j < 288) ? Wih_f[j*96 + k] : Wih_b[(j-288)*96 + k];
  }
  if (i < 576) bcat[i] = (i < 288) ? bih_f[i] : bih_b[i-288];
}

// ---------------------------------------------------------------- k_sem
__device__ __forceinline__ void sem_att(const float* __restrict__ rel_emb,
                                        const int rels[8], const float tgt[32],
                                        float out[32]) {
  float dots[8]; float mx = -1e30f;
  #pragma unroll
  for (int k = 0; k < 8; ++k) {
    const float4* er = (const float4*)(rel_emb + rels[k]*32);
    float s = 0.f;
    #pragma unroll
    for (int q = 0; q < 8; ++q) {
      float4 v = er[q];
      s += v.x*tgt[4*q+0] + v.y*tgt[4*q+1] + v.z*tgt[4*q+2] + v.w*tgt[4*q+3];
    }
    dots[k] = s; mx = fmaxf(mx, s);
  }
  float den = 0.f;
  #pragma unroll
  for (int k = 0; k < 8; ++k) { float e = __expf(dots[k]-mx); dots[k] = e; den += e; }
  float inv = 1.f/den;
  #pragma unroll
  for (int d = 0; d < 32; ++d) out[d] = 0.f;
  #pragma unroll
  for (int k = 0; k < 8; ++k) {
    const float4* er = (const float4*)(rel_emb + rels[k]*32);
    float a = dots[k]*inv;
    #pragma unroll
    for (int q = 0; q < 8; ++q) {
      float4 v = er[q];
      out[4*q+0] += a*v.x; out[4*q+1] += a*v.y; out[4*q+2] += a*v.z; out[4*q+3] += a*v.w;
    }
  }
}

__global__ __launch_bounds__(256) void k_sem(
    const float* __restrict__ feat, const int* __restrict__ out_rels,
    const int* __restrict__ in_rels, const int* __restrict__ r_label_node,
    const float* __restrict__ rel_emb, const float* __restrict__ W,
    const float* __restrict__ bias, float* __restrict__ hin) {
  int n = blockIdx.x*256 + threadIdx.x;
  float tgt[32];
  {
    const float4* tr = (const float4*)(rel_emb + r_label_node[n]*32);
    #pragma unroll
    for (int q = 0; q < 8; ++q) {
      float4 v = tr[q];
      tgt[4*q+0]=v.x; tgt[4*q+1]=v.y; tgt[4*q+2]=v.z; tgt[4*q+3]=v.w;
    }
  }
  int ro[8], ri[8];
  #pragma unroll
  for (int k = 0; k < 8; ++k) { ro[k] = out_rels[n*8+k]; ri[k] = in_rels[n*8+k]; }
  float osem[32], isem[32];
  sem_att(rel_emb, ro, tgt, osem);
  sem_att(rel_emb, ri, tgt, isem);
  const float4* fr = (const float4*)(feat + (size_t)n*16);
  float4* ho = (float4*)(hin + (size_t)n*32);
  #pragma unroll
  for (int q = 0; q < 4; ++q) ho[q] = fr[q];
  #pragma unroll
  for (int j = 0; j < 16; ++j) {
    float s = bias[j];
    #pragma unroll
    for (int d = 0; d < 32; ++d) s += osem[d]*W[d*16+j] + isem[d]*W[(32+d)*16+j];
    hin[(size_t)n*32 + 16 + j] = sigm(s);
  }
}

// ---------------------------------------------------------------- k_gnn3 : all 3 layers fused, CSR gather (no float atomics)
__global__ __launch_bounds__(512) void k_gnn3(
    const float* __restrict__ hin, const float* __restrict__ rel_emb,
    const float* __restrict__ r123,
    const int* __restrict__ src, const int* __restrict__ dst, const int* __restrict__ etype,
    const float* __restrict__ W_msg, const float* __restrict__ W_self,
    const float* __restrict__ b_gnn,
    float* __restrict__ AT, float* __restrict__ ghid0) {
  __shared__ __align__(16) float hl[NT*36];
  __shared__ __align__(16) float hnew[NT*33];
  __shared__ float rl[NREL*32];
  __shared__ unsigned short eidx[2048];
  __shared__ float scratch[16][32];
  __shared__ int cnt[128], fill[128], scanv[128], rowstart[129];
  int g = blockIdx.x;
  int tid = threadIdx.x;
  int d = tid & 31, grp = tid >> 5;

  // ---- stage h0 (row-major hin -> stride-36)
  for (int i = tid; i < NT*32; i += 512) {
    int row = i >> 5, col = i & 31;
    hl[row*36 + col] = hin[(size_t)(g*NT + row)*32 + col];
  }
  // ---- CSR build (dst invariant across layers)
  if (tid < 128) { cnt[tid] = 0; fill[tid] = 0; }
  __syncthreads();
  for (int i = tid; i < 2048; i += 512)
    atomicAdd(&cnt[dst[g*2048 + i] - g*NT], 1);
  __syncthreads();
  if (tid < 128) scanv[tid] = cnt[tid];
  __syncthreads();
  #pragma unroll
  for (int off = 1; off < 128; off <<= 1) {
    int v = 0;
    if (tid < 128 && tid >= off) v = scanv[tid - off];
    __syncthreads();
    if (tid < 128) scanv[tid] += v;
    __syncthreads();
  }
  if (tid < 128) { rowstart[tid+1] = scanv[tid]; if (tid == 0) rowstart[0] = 0; }
  __syncthreads();
  for (int i = tid; i < 2048; i += 512) {
    int e = g*2048 + i;
    int dl = dst[e] - g*NT;
    int slot = rowstart[dl] + atomicAdd(&fill[dl], 1);
    eidx[slot] = (unsigned short)(((src[e] - g*NT) << 8) | etype[e]);
  }
  // note: no sync needed here; the layer-loop's first sync covers it

  for (int l = 0; l < 3; ++l) {
    const float* rsrc = (l == 0) ? rel_emb : (r123 + (size_t)(l-1)*NREL*32);
    for (int i = tid; i < NREL*32; i += 512) rl[i] = rsrc[i];
    float wm[32], ws[32];
    #pragma unroll
    for (int dd = 0; dd < 32; ++dd) {
      wm[dd] = W_msg[l*1024 + dd*32 + d];
      ws[dd] = W_self[l*1024 + dd*32 + d];
    }
    float bj = b_gnn[l*32 + d];
    __syncthreads();                       // rl + hl + eidx ready
    for (int k2 = 0; k2 < 8; ++k2) {
      int n = grp + k2*16;
      int e0 = rowstart[n], e1 = rowstart[n+1];
      float acc = 0.f;
      for (int e = e0; e < e1; ++e) {
        int pk = eidx[e];
        acc += hl[(pk >> 8)*36 + d] * rl[(pk & 255)*32 + d];
      }
      scratch[grp][d] = acc;               // half-wave lockstep: safe
      float invd = 1.f / (float)((e1 - e0) > 0 ? (e1 - e0) : 1);
      float sa = 0.f, sh = 0.f;
      #pragma unroll
      for (int dd = 0; dd < 32; ++dd) {
        sa += scratch[grp][dd]*wm[dd];
        sh += hl[n*36 + dd]*ws[dd];
      }
      hnew[n*33 + d] = fmaxf(bj + invd*sa + sh, 0.f);
    }
    __syncthreads();                       // hnew complete, hl reads done
    // hl <- hnew ; AT slice ; ghid0 partial max
    for (int i = tid; i < NT*32; i += 512) {
      int row = i >> 5, col = i & 31;
      hl[row*36 + col] = hnew[row*33 + col];
    }
    #pragma unroll
    for (int pass = 0; pass < 8; ++pass) {
      int col = (pass << 2) + (tid >> 7);
      int row = tid & 127;
      AT[(size_t)(l*32 + col)*NNODE + g*NT + row] = hnew[row*33 + col];
    }
    {
      float m = -1e30f;
      #pragma unroll
      for (int k2 = 0; k2 < 8; ++k2) m = fmaxf(m, hnew[(grp + k2*16)*33 + d]);
      scratch[grp][d] = m;
    }
    __syncthreads();
    if (tid < 32) {
      float m = -1e30f;
      #pragma unroll
      for (int p2 = 0; p2 < 16; ++p2) m = fmaxf(m, scratch[p2][tid]);
      ghid0[g*96 + l*32 + tid] = m;
    }
    __syncthreads();                       // scratch/hl stable before next layer
  }
}

// ---------------------------------------------------------------- k_gemm1 : persistent-A, loops 9 N-tiles
__global__ __launch_bounds__(256) void k_gemm1(
    const float* __restrict__ AT, const float* __restrict__ gbias,
    const float* __restrict__ WT1, const float* __restrict__ bcat,
    float* __restrict__ GI) {
  __shared__ __align__(16) float As[96*128];
  __shared__ __align__(16) float Bs[96*64];
  int mb = blockIdx.x;
  int m0 = mb*128;
  int tid = threadIdx.x;
  for (int i = tid; i < 3072; i += 256) {
    int r = i >> 5, c4 = i & 31;
    float4 v = *(const float4*)&AT[(size_t)r*NNODE + m0 + c4*4];
    float b = gbias[r];
    float4 o = make_float4(fmaxf(v.x+b,0.f), fmaxf(v.y+b,0.f), fmaxf(v.z+b,0.f), fmaxf(v.w+b,0.f));
    *(float4*)&As[r*128 + c4*4] = o;
  }
  int tc = tid & 15, tr = tid >> 4;
  int r0 = tr*8, c0 = tc*4;
  for (int nb = 0; nb < 9; ++nb) {
    int n0 = nb*64;
    for (int i = tid; i < 1536; i += 256) {
      int r = i >> 4, c4 = i & 15;
      *(float4*)&Bs[r*64 + c4*4] = *(const float4*)&WT1[r*576 + n0 + c4*4];
    }
    __syncthreads();
    float acc[8][4] = {};
    #pragma unroll 4
    for (int k = 0; k < 96; ++k) {
      float4 a0 = *(float4*)&As[k*128 + r0];
      float4 a1 = *(float4*)&As[k*128 + r0 + 4];
      float4 b  = *(float4*)&Bs[k*64 + c0];
      acc[0][0]+=a0.x*b.x; acc[0][1]+=a0.x*b.y; acc[0][2]+=a0.x*b.z; acc[0][3]+=a0.x*b.w;
      acc[1][0]+=a0.y*b.x; acc[1][1]+=a0.y*b.y; acc[1][2]+=a0.y*b.z; acc[1][3]+=a0.y*b.w;
      acc[2][0]+=a0.z*b.x; acc[2][1]+=a0.z*b.y; acc[2][2]+=a0.z*b.z; acc[2][3]+=a0.z*b.w;
      acc[3][0]+=a0.w*b.x; acc[3][1]+=a0.w*b.y; acc[3][2]+=a0.w*b.z; acc[3][3]+=a0.w*b.w;
      acc[4][0]+=a1.x*b.x; acc[4][1]+=a1.x*b.y; acc[4][2]+=a1.x*b.z; acc[4][3]+=a1.x*b.w;
      acc[5][0]+=a1.y*b.x; acc[5][1]+=a1.y*b.y; acc[5][2]+=a1.y*b.z; acc[5][3]+=a1.y*b.w;
      acc[6][0]+=a1.z*b.x; acc[6][1]+=a1.z*b.y; acc[6][2]+=a1.z*b.z; acc[6][3]+=a1.z*b.w;
      acc[7][0]+=a1.w*b.x; acc[7][1]+=a1.w*b.y; acc[7][2]+=a1.w*b.z; acc[7][3]+=a1.w*b.w;
    }
    float4 bia = *(const float4*)&bcat[n0 + c0];
    #pragma unroll
    for (int r = 0; r < 8; ++r) {
      f32x4 o = { acc[r][0]+bia.x, acc[r][1]+bia.y, acc[r][2]+bia.z, acc[r][3]+bia.w };
      __builtin_nontemporal_store(o, (f32x4*)&GI[(size_t)(m0 + r0 + r)*576 + n0 + c0]);
    }
    __syncthreads();
  }
}

// ---------------------------------------------------------------- k_gru : S=4, writes relu'd AT2 (col-major) directly
#define PIN4(v) asm volatile("" : "+v"(v.x), "+v"(v.y), "+v"(v.z), "+v"(v.w))
#define DOT16(acc, W0,W1,W2,W3, X0,X1,X2,X3) \
  acc += W0.x*X0.x + W0.y*X0.y + W0.z*X0.z + W0.w*X0.w \
       + W1.x*X1.x + W1.y*X1.y + W1.z*X1.z + W1.w*X1.w \
       + W2.x*X2.x + W2.y*X2.y + W2.z*X2.z + W2.w*X2.w \
       + W3.x*X3.x + W3.y*X3.y + W3.z*X3.z + W3.w*X3.w

__global__ __launch_bounds__(576, 1) void k_gru(
    const float* __restrict__ Whh_f, const float* __restrict__ bhh_f,
    const float* __restrict__ Whh_b, const float* __restrict__ bhh_b,
    const float* __restrict__ GI, const float* __restrict__ ghid0,
    float* __restrict__ AT2) {
  __shared__ __align__(16) float h_lds[4][96];
  __shared__ float part[4][288][9];
  int bx = blockIdx.x;                  // 256 blocks
  int dir = bx >> 7;
  int gbase = (bx & 127) * 4;
  int tid = threadIdx.x;
  int c = tid % 96;
  int p = tid / 96;
  bool fin = (tid < 384);
  int s = p;

  const float* Whh = dir ? Whh_b : Whh_f;
  const float4* wr0 = (const float4*)(Whh + (size_t)c*96 + p*16);
  const float4* wr1 = (const float4*)(Whh + (size_t)(96+c)*96 + p*16);
  const float4* wr2 = (const float4*)(Whh + (size_t)(192+c)*96 + p*16);
  float4 wa0=wr0[0], wa1=wr0[1], wa2=wr0[2], wa3=wr0[3];
  float4 wb0=wr1[0], wb1=wr1[1], wb2=wr1[2], wb3=wr1[3];
  float4 wc0=wr2[0], wc1=wr2[1], wc2=wr2[2], wc3=wr2[3];

  float bh0=0.f, bh1=0.f, bh2=0.f;
  float gi0=0.f, gi1=0.f, gi2=0.f;
  if (fin) {
    const float* bhh = dir ? bhh_b : bhh_f;
    bh0 = bhh[c]; bh1 = bhh[96+c]; bh2 = bhh[192+c];
    h_lds[s][c] = ghid0[(gbase+s)*96 + c];
    int pos0 = dir ? 127 : 0;
    const float* g = GI + (size_t)((gbase+s)*128 + pos0)*576 + dir*288;
    gi0 = g[c]; gi1 = g[96+c]; gi2 = g[192+c];
  }
  __syncthreads();
  for (int t = 0; t < 128; ++t) {
    PIN4(wa0); PIN4(wa1); PIN4(wa2); PIN4(wa3);
    PIN4(wb0); PIN4(wb1); PIN4(wb2); PIN4(wb3);
    PIN4(wc0); PIN4(wc1); PIN4(wc2); PIN4(wc3);
    int pos = dir ? (127-t) : t;
    float gn0=0.f, gn1=0.f, gn2=0.f;
    if (fin && t < 127) {
      int posn = dir ? (126-t) : (t+1);
      const float* g = GI + (size_t)((gbase+s)*128 + posn)*576 + dir*288;
      gn0 = g[c]; gn1 = g[96+c]; gn2 = g[192+c];
    }
    #pragma unroll
    for (int s4 = 0; s4 < 4; ++s4) {
      const float4* hh = (const float4*)&h_lds[s4][p*16];
      float4 x0=hh[0], x1=hh[1], x2=hh[2], x3=hh[3];
      float q0=0.f, q1=0.f, q2=0.f;
      DOT16(q0, wa0,wa1,wa2,wa3, x0,x1,x2,x3);
      DOT16(q1, wb0,wb1,wb2,wb3, x0,x1,x2,x3);
      DOT16(q2, wc0,wc1,wc2,wc3, x0,x1,x2,x3);
      part[s4][c][p]     = q0;
      part[s4][96+c][p]  = q1;
      part[s4][192+c][p] = q2;
    }
    __syncthreads();
    if (fin) {
      const float* pr = part[s][c];
      const float* pz = part[s][96+c];
      const float* pn = part[s][192+c];
      float ghr = pr[0]+pr[1]+pr[2]+pr[3]+pr[4]+pr[5] + bh0;
      float ghz = pz[0]+pz[1]+pz[2]+pz[3]+pz[4]+pz[5] + bh1;
      float ghn = pn[0]+pn[1]+pn[2]+pn[3]+pn[4]+pn[5] + bh2;
      float r  = sigm(gi0 + ghr);
      float z  = sigm(gi1 + ghz);
      float nn = tanhf(gi2 + r*ghn);
      float hv = (1.f - z)*nn + z*h_lds[s][c];
      h_lds[s][c] = hv;
      AT2[(size_t)(dir*96 + c)*NNODE + (gbase+s)*128 + pos] = fmaxf(hv, 0.f);
      gi0 = gn0; gi1 = gn1; gi2 = gn2;
    }
    __syncthreads();
  }
}

// ---------------------------------------------------------------- k_gemm2p : fused Wo-GEMM + pooling
__global__ __launch_bounds__(384) void k_gemm2p(
    const float* __restrict__ AT2, const float* __restrict__ WoW,
    const float* __restrict__ Wob, float* __restrict__ goutb,
    float* __restrict__ headb, float* __restrict__ tailb) {
  __shared__ __align__(16) float As[96*64];
  __shared__ __align__(16) float Bs[96*96];
  __shared__ float red[16][100];
  int m0 = blockIdx.x*64;
  int g = m0 >> 7;
  int tid = threadIdx.x;
  int tc = tid % 24, tr = tid / 24;
  int r0 = tr*4, c0 = tc*4;
  float acc[4][4] = {};
  for (int kc = 0; kc < 2; ++kc) {
    for (int i = tid; i < 1536; i += 384) {
      int r = i >> 4, c4 = i & 15;
      *(float4*)&As[r*64 + c4*4] = *(const float4*)&AT2[(size_t)(kc*96 + r)*NNODE + m0 + c4*4];
    }
    for (int i = tid; i < 2304; i += 384) {
      int r = i / 24, c4 = i % 24;
      *(float4*)&Bs[r*96 + c4*4] = *(const float4*)&WoW[(size_t)(kc*96 + r)*96 + c4*4];
    }
    __syncthreads();
    #pragma unroll 8
    for (int k = 0; k < 96; ++k) {
      float4 a = *(float4*)&As[k*64 + r0];
      float4 b = *(float4*)&Bs[k*96 + c0];
      acc[0][0] += a.x*b.x; acc[0][1] += a.x*b.y; acc[0][2] += a.x*b.z; acc[0][3] += a.x*b.w;
      acc[1][0] += a.y*b.x; acc[1][1] += a.y*b.y; acc[1][2] += a.y*b.z; acc[1][3] += a.y*b.w;
      acc[2][0] += a.z*b.x; acc[2][1] += a.z*b.y; acc[2][2] += a.z*b.z; acc[2][3] += a.z*b.w;
      acc[3][0] += a.w*b.x; acc[3][1] += a.w*b.y; acc[3][2] += a.w*b.z; acc[3][3] += a.w*b.w;
    }
    __syncthreads();
  }
  float4 bia = *(const float4*)&Wob[c0];
  float nv[4][4];
  #pragma unroll
  for (int r = 0; r < 4; ++r) {
    nv[r][0] = fmaxf(acc[r][0]+bia.x, 0.f);
    nv[r][1] = fmaxf(acc[r][1]+bia.y, 0.f);
    nv[r][2] = fmaxf(acc[r][2]+bia.z, 0.f);
    nv[r][3] = fmaxf(acc[r][3]+bia.w, 0.f);
  }
  #pragma unroll
  for (int cj = 0; cj < 4; ++cj)
    red[tr][c0+cj] = nv[0][cj] + nv[1][cj] + nv[2][cj] + nv[3][cj];
  if ((m0 & 127) == 0 && tr == 0) {
    #pragma unroll
    for (int cj = 0; cj < 4; ++cj) {
      headb[g*96 + c0 + cj] = nv[0][cj];
      tailb[g*96 + c0 + cj] = nv[1][cj];
    }
  }
  __syncthreads();
  if (tid < 96) {
    float s = 0.f;
    #pragma unroll
    for (int t2 = 0; t2 < 16; ++t2) s += red[t2][tid];
    atomicAdd(&goutb[g*96 + tid], s);
  }
}

// ---------------------------------------------------------------- k_path
__global__ __launch_bounds__(128) void k_path(
    const float* __restrict__ XI, const int* __restrict__ in_rels,
    const int* __restrict__ labels, const float* __restrict__ pWhh,
    const float* __restrict__ pbhh, float* __restrict__ last) {
  __shared__ __align__(16) float wsh[96*32];
  __shared__ float bsh[96];
  __shared__ float hbuf[128*33];
  int tid = threadIdx.x;
  for (int i = tid; i < 96*32; i += 128) wsh[i] = pWhh[i];
  if (tid < 96) bsh[tid] = pbhh[tid];
  int p = blockIdx.x*128 + tid;
  int b = p >> 6, pp = p & 63;
  int rid0 = in_rels[b*1024 + (pp >> 3)];
  int rid1 = labels[b];
  int rid2 = in_rels[b*1024 + 8 + (pp & 7)];
  __syncthreads();
  float* hs = &hbuf[tid*33];
  {
    const float* xi = XI + rid0*96;
    #pragma unroll
    for (int gg = 0; gg < 32; ++gg) {
      float r = sigm(xi[gg] + bsh[gg]);
      float z = sigm(xi[32+gg] + bsh[32+gg]);
      float nn = tanhf(xi[64+gg] + r*bsh[64+gg]);
      hs[gg] = (1.f - z)*nn;
    }
  }
  float4 h4[8];
  #pragma unroll
  for (int q = 0; q < 8; ++q) h4[q] = make_float4(hs[4*q], hs[4*q+1], hs[4*q+2], hs[4*q+3]);
  for (int s = 0; s < 2; ++s) {
    const float* xi = XI + (s == 0 ? rid1 : rid2)*96;
    for (int gg = 0; gg < 32; ++gg) {
      float ar = bsh[gg], az = bsh[32+gg], an = bsh[64+gg];
      const float4* wr = (const float4*)&wsh[gg*32];
      const float4* wz = (const float4*)&wsh[(32+gg)*32];
      const float4* wn = (const float4*)&wsh[(64+gg)*32];
      #pragma unroll
      for (int q = 0; q < 8; ++q) {
        float4 hv = h4[q]; float4 w;
        w = wr[q]; ar += hv.x*w.x + hv.y*w.y + hv.z*w.z + hv.w*w.w;
        w = wz[q]; az += hv.x*w.x + hv.y*w.y + hv.z*w.z + hv.w*w.w;
        w = wn[q]; an += hv.x*w.x + hv.y*w.y + hv.z*w.z + hv.w*w.w;
      }
      float r = sigm(xi[gg] + ar);
      float z = sigm(xi[32+gg] + az);
      float nn = tanhf(xi[64+gg] + r*an);
      hs[gg] = (1.f - z)*nn + z*hs[gg];
    }
    #pragma unroll
    for (int q = 0; q < 8; ++q) h4[q] = make_float4(hs[4*q], hs[4*q+1], hs[4*q+2], hs[4*q+3]);
  }
  float* lp = last + (size_t)p*32;
  #pragma unroll
  for (int d = 0; d < 32; ++d) lp[d] = hs[d];
}

// ---------------------------------------------------------------- k_final
__global__ __launch_bounds__(64) void k_final(
    const float* __restrict__ last, const float* __restrict__ r3,
    const int* __restrict__ labels, const float* __restrict__ goutb,
    const float* __restrict__ headb, const float* __restrict__ tailb,
    const float* __restrict__ fcW, const float* __restrict__ fcb,
    float* __restrict__ out) {
  __shared__ float red[64*33];
  __shared__ float gpl[32];
  int b = blockIdx.x, lane = threadIdx.x;
  const float* rl = r3 + labels[b]*32;
  float l32[32];
  {
    const float4* lr = (const float4*)(last + (size_t)(b*64 + lane)*32);
    #pragma unroll
    for (int q = 0; q < 8; ++q) {
      float4 v = lr[q];
      l32[4*q+0]=v.x; l32[4*q+1]=v.y; l32[4*q+2]=v.z; l32[4*q+3]=v.w;
    }
  }
  float s = 0.f;
  #pragma unroll
  for (int d = 0; d < 32; ++d) s += l32[d]*rl[d];
  float mx = s;
  #pragma unroll
  for (int off = 32; off > 0; off >>= 1) mx = fmaxf(mx, __shfl_xor(mx, off));
  float e = __expf(s - mx);
  float den = e;
  #pragma unroll
  for (int off = 32; off > 0; off >>= 1) den += __shfl_xor(den, off);
  float att = e / den;
  #pragma unroll
  for (int d = 0; d < 32; ++d) red[lane*33 + d] = att*l32[d];
  __syncthreads();
  if (lane < 32) {
    float gp = 0.f;
    for (int p2 = 0; p2 < 64; ++p2) gp += red[p2*33 + lane];
    gpl[lane] = gp;
  }
  __syncthreads();
  float acc = 0.f;
  for (int i = lane; i < 352; i += 64) {
    float v;
    if (i < 96)       v = goutb[b*96 + i] * 0.0078125f;   // /128
    else if (i < 192) v = headb[b*96 + (i-96)];
    else if (i < 288) v = tailb[b*96 + (i-192)];
    else if (i < 320) v = rl[i-288];
    else              v = gpl[i-320];
    acc += v*fcW[i];
  }
  #pragma unroll
  for (int off = 32; off > 0; off >>= 1) acc += __shfl_xor(acc, off);
  if (lane == 0) out[b] = acc + fcb[0];
}

// ---------------------------------------------------------------- launch
extern "C" void kernel_launch(void* const* d_in, const int* in_sizes, int n_in,
                              void* d_out, int out_size, void* d_ws, size_t ws_size,
                              hipStream_t stream) {
  const float* feat       = (const float*)d_in[0];
  const int*   out_rels   = (const int*)d_in[1];
  const int*   in_rels    = (const int*)d_in[2];
  const int*   r_label_nd = (const int*)d_in[3];
  const int*   src        = (const int*)d_in[4];
  const int*   dst        = (const int*)d_in[5];
  const int*   etype      = (const int*)d_in[6];
  const int*   rel_labels = (const int*)d_in[7];
  const float* rel_emb    = (const float*)d_in[8];
  const float* w2e_W      = (const float*)d_in[9];
  const float* w2e_b      = (const float*)d_in[10];
  const float* W_msg      = (const float*)d_in[11];
  const float* W_self     = (const float*)d_in[12];
  const float* b_gnn      = (const float*)d_in[13];
  const float* W_rel      = (const float*)d_in[14];
  const float* gru_bias   = (const float*)d_in[15];
  const float* Wih_f      = (const float*)d_in[16];
  const float* Whh_f      = (const float*)d_in[17];
  const float* bih_f      = (const float*)d_in[18];
  const float* bhh_f      = (const float*)d_in[19];
  const float* Wih_b      = (const float*)d_in[20];
  const float* Whh_b      = (const float*)d_in[21];
  const float* bih_b      = (const float*)d_in[22];
  const float* bhh_b      = (const float*)d_in[23];
  const float* Wo_W       = (const float*)d_in[24];
  const float* Wo_b       = (const float*)d_in[25];
  const float* pWih       = (const float*)d_in[26];
  const float* pWhh       = (const float*)d_in[27];
  const float* pbih       = (const float*)d_in[28];
  const float* pbhh       = (const float*)d_in[29];
  const float* fcW        = (const float*)d_in[30];
  const float* fcb        = (const float*)d_in[31];
  float* out = (float*)d_out;

  float* p = (float*)d_ws;
  float* hin   = p; p += (size_t)NNODE*32;
  float* R1    = p; p += (size_t)NNODE*192;   // AT (96xN) then AT2 (192xN)
  float* AT    = R1;
  float* AT2   = R1;
  float* R2    = p; p += (size_t)NNODE*576;   // GI
  float* GI    = R2;
  float* r123  = p; p += 3*NREL*32;
  float* WT1   = p; p += 96*576;
  float* bcat  = p; p += 576;
  float* XI    = p; p += NREL*96;
  float* ghid0 = p; p += BB*96;
  float* goutb = p; p += BB*96;
  float* headb = p; p += BB*96;
  float* tailb = p; p += BB*96;
  float* lastb = p; p += (size_t)BB*64*32;

  hipMemsetAsync(goutb, 0, BB*96*sizeof(float), stream);
  k_rel2<<<NREL, 96, 0, stream>>>(rel_emb, W_rel, pWih, pbih, r123, XI);
  k_wt1<<<(96*576+255)/256, 256, 0, stream>>>(Wih_f, Wih_b, bih_f, bih_b, WT1, bcat);
  k_sem<<<NNODE/256, 256, 0, stream>>>(feat, out_rels, in_rels, r_label_nd,
                                       rel_emb, w2e_W, w2e_b, hin);
  k_gnn3<<<BB, 512, 0, stream>>>(hin, rel_emb, r123, src, dst, etype,
                                 W_msg, W_self, b_gnn, AT, ghid0);
  k_gemm1<<<512, 256, 0, stream>>>(AT, gru_bias, WT1, bcat, GI);
  k_gru<<<256, 576, 0, stream>>>(Whh_f, bhh_f, Whh_b, bhh_b, GI, ghid0, AT2);
  k_gemm2p<<<1024, 384, 0, stream>>>(AT2, Wo_W, Wo_b, goutb, headb, tailb);
  k_path<<<256, 128, 0, stream>>>(XI, in_rels, rel_labels, pWhh, pbhh, lastb);
  k_final<<<BB, 64, 0, stream>>>(lastb, r123 + 2*NREL*32, rel_labels,
                                 goutb, headb, tailb, fcW, fcb, out);
}